// Round 10
// baseline (319.017 us; speedup 1.0000x reference)
//
#include <hip/hip_runtime.h>
#include <hip/hip_bf16.h>
#include <math.h>

#define NB 2        // batch
#define NC 64       // channels
#define ND 8        // head dim (C/8)
#define NN 4096     // tokens (T*W*H)
#define NM 256      // landmarks
#define NL 16       // N/M
#define SCALE 0.35355339059327373f  // 1/sqrt(8)
// p(z) = 13-15z+7z^2-z^3 = (A_ROOT - z)(z^2 + B_COEF z + C_COEF)  [validated R7-R9]
#define A_ROOT 4.1303956f
#define B_COEF (-2.8696044f)
#define C_COEF 3.1474086f

typedef __attribute__((ext_vector_type(4))) float f32x4;
typedef __attribute__((ext_vector_type(8))) short bf16x8;

__device__ inline ushort f2bf(float f) {
  __hip_bfloat16 h = __float2bfloat16(f);
  return *reinterpret_cast<ushort*>(&h);
}
__device__ inline float bf2f(ushort u) {
  return __uint_as_float(((unsigned int)u) << 16);
}

// async global->LDS, 16B per lane; LDS dest must be wave-linear (base + lane*16)
__device__ inline void gl_lds16(const void* g, void* l) {
  __builtin_amdgcn_global_load_lds(
      (const __attribute__((address_space(1))) unsigned int*)g,
      (__attribute__((address_space(3))) unsigned int*)l, 16, 0, 0);
}

// ---------------- qkv projection, output-row parallel (R5) ----------------
__global__ __launch_bounds__(256) void qkv2_kernel(
    const float* __restrict__ x,
    const float* __restrict__ wq, const float* __restrict__ bq,
    const float* __restrict__ wk, const float* __restrict__ bk,
    const float* __restrict__ wv, const float* __restrict__ bv,
    float* __restrict__ q, float* __restrict__ k, float* __restrict__ v) {
  __shared__ float ws[NC];
  int o = blockIdx.x;            // 0..79: 0-7 q, 8-15 k, 16-79 v
  int b = blockIdx.z;
  int n0 = blockIdx.y * 1024;
  int t = threadIdx.x;
  const float* wrow;
  float bias;
  if (o < ND)            { wrow = wq + (size_t)o * NC;            bias = bq[o]; }
  else if (o < 2 * ND)   { wrow = wk + (size_t)(o - ND) * NC;     bias = bk[o - ND]; }
  else                   { wrow = wv + (size_t)(o - 2 * ND) * NC; bias = bv[o - 2 * ND]; }
  if (t < NC) ws[t] = wrow[t];
  __syncthreads();
  int n = n0 + t * 4;
  float4 acc = {bias, bias, bias, bias};
  #pragma unroll
  for (int c = 0; c < NC; ++c) {
    float wc = ws[c];
    float4 xv = *(const float4*)(x + ((size_t)b * NC + c) * NN + n);
    acc.x += wc * xv.x; acc.y += wc * xv.y; acc.z += wc * xv.z; acc.w += wc * xv.w;
  }
  if (o < ND) {
    float* qp = q + ((size_t)b * NN + n) * ND + o;
    qp[0] = acc.x; qp[8] = acc.y; qp[16] = acc.z; qp[24] = acc.w;
  } else if (o < 2 * ND) {
    float* kp = k + ((size_t)b * NN + n) * ND + (o - ND);
    kp[0] = acc.x; kp[8] = acc.y; kp[16] = acc.z; kp[24] = acc.w;
  } else {
    *(float4*)(v + ((size_t)b * NC + (o - 2 * ND)) * NN + n) = acc;
  }
}

// ---------------- landmarks (R5) ----------------
__global__ void landmark_kernel(const float* __restrict__ q, const float* __restrict__ k,
                                float* __restrict__ ql, float* __restrict__ kl) {
  int idx = blockIdx.x * 256 + threadIdx.x;
  int b = idx / (NM * ND), r = idx % (NM * ND), i = r / ND, o = r % ND;
  float sq = 0.f, sk = 0.f;
  for (int l = 0; l < NL; ++l) {
    size_t base = ((size_t)b * NN + i * NL + l) * ND + o;
    sq += q[base]; sk += k[base];
  }
  ql[idx] = sq * (1.0f / NL);
  kl[idx] = sk * (1.0f / NL);
}

// ---------------- softmax rows vs landmarks: bf16 output (k1) ----------------
__global__ __launch_bounds__(256) void scores_softmax_m_bf16(
    const float* __restrict__ Q, int R, const float* __restrict__ KL,
    ushort* __restrict__ out) {
  __shared__ float skl[NM][9];
  int b = blockIdx.y;
  int t = threadIdx.x;
  for (int i = t; i < NM * ND; i += 256) skl[i >> 3][i & 7] = KL[(size_t)b * NM * ND + i];
  __syncthreads();
  int wave = t >> 6, lane = t & 63;
  int r = blockIdx.x * 4 + wave;
  const float* qrow = Q + ((size_t)b * R + r) * ND;
  float qr[ND];
  #pragma unroll
  for (int dd = 0; dd < ND; ++dd) qr[dd] = qrow[dd];
  float sc[4];
  float lmax = -1e30f;
  #pragma unroll
  for (int s = 0; s < 4; ++s) {
    int j = lane + 64 * s;
    float a = 0.f;
    #pragma unroll
    for (int dd = 0; dd < ND; ++dd) a += qr[dd] * skl[j][dd];
    sc[s] = a * SCALE;
    lmax = fmaxf(lmax, sc[s]);
  }
  for (int off = 32; off; off >>= 1) lmax = fmaxf(lmax, __shfl_xor(lmax, off));
  float lsum = 0.f;
  #pragma unroll
  for (int s = 0; s < 4; ++s) { sc[s] = expf(sc[s] - lmax); lsum += sc[s]; }
  for (int off = 32; off; off >>= 1) lsum += __shfl_xor(lsum, off);
  float inv = 1.0f / lsum;
  #pragma unroll
  for (int s = 0; s < 4; ++s)
    out[((size_t)b * R + r) * NM + lane + 64 * s] = f2bf(sc[s] * inv);
}

// ---------------- softmax rows vs landmarks: fp32 output (k2) ----------------
__global__ __launch_bounds__(256) void scores_softmax_m_f32(
    const float* __restrict__ Q, int R, const float* __restrict__ KL,
    float* __restrict__ out) {
  __shared__ float skl[NM][9];
  int b = blockIdx.y;
  int t = threadIdx.x;
  for (int i = t; i < NM * ND; i += 256) skl[i >> 3][i & 7] = KL[(size_t)b * NM * ND + i];
  __syncthreads();
  int wave = t >> 6, lane = t & 63;
  int r = blockIdx.x * 4 + wave;
  const float* qrow = Q + ((size_t)b * R + r) * ND;
  float qr[ND];
  #pragma unroll
  for (int dd = 0; dd < ND; ++dd) qr[dd] = qrow[dd];
  float sc[4];
  float lmax = -1e30f;
  #pragma unroll
  for (int s = 0; s < 4; ++s) {
    int j = lane + 64 * s;
    float a = 0.f;
    #pragma unroll
    for (int dd = 0; dd < ND; ++dd) a += qr[dd] * skl[j][dd];
    sc[s] = a * SCALE;
    lmax = fmaxf(lmax, sc[s]);
  }
  for (int off = 32; off; off >>= 1) lmax = fmaxf(lmax, __shfl_xor(lmax, off));
  float lsum = 0.f;
  #pragma unroll
  for (int s = 0; s < 4; ++s) { sc[s] = expf(sc[s] - lmax); lsum += sc[s]; }
  for (int off = 32; off; off >>= 1) lsum += __shfl_xor(lsum, off);
  float inv = 1.0f / lsum;
  #pragma unroll
  for (int s = 0; s < 4; ++s) out[((size_t)b * R + r) * NM + lane + 64 * s] = sc[s] * inv;
}

// ---------------- k3 softmax (fp32 out, R5) ----------------
__global__ __launch_bounds__(256) void scores_softmax_n(
    const float* __restrict__ QL, const float* __restrict__ Kt,
    float* __restrict__ out) {
  __shared__ float wred[4], wsum[4];
  int b = blockIdx.y, i = blockIdx.x;
  int t = threadIdx.x;
  float qr[ND];
  #pragma unroll
  for (int dd = 0; dd < ND; ++dd) qr[dd] = QL[((size_t)b * NM + i) * ND + dd];
  float sc[16];
  float lmax = -1e30f;
  #pragma unroll
  for (int s = 0; s < 16; ++s) {
    int n = t + 256 * s;
    const float* kp = Kt + ((size_t)b * NN + n) * ND;
    float a = 0.f;
    #pragma unroll
    for (int dd = 0; dd < ND; ++dd) a += qr[dd] * kp[dd];
    sc[s] = a * SCALE;
    lmax = fmaxf(lmax, sc[s]);
  }
  for (int off = 32; off; off >>= 1) lmax = fmaxf(lmax, __shfl_xor(lmax, off));
  if ((t & 63) == 0) wred[t >> 6] = lmax;
  __syncthreads();
  lmax = fmaxf(fmaxf(wred[0], wred[1]), fmaxf(wred[2], wred[3]));
  float lsum = 0.f;
  #pragma unroll
  for (int s = 0; s < 16; ++s) { sc[s] = expf(sc[s] - lmax); lsum += sc[s]; }
  for (int off = 32; off; off >>= 1) lsum += __shfl_xor(lsum, off);
  if ((t & 63) == 0) wsum[t >> 6] = lsum;
  __syncthreads();
  lsum = wsum[0] + wsum[1] + wsum[2] + wsum[3];
  float inv = 1.0f / lsum;
  #pragma unroll
  for (int s = 0; s < 16; ++s) out[((size_t)b * NM + i) * NN + t + 256 * s] = sc[s] * inv;
}

// ---------------- denom: max column-sum per batch (R5) ----------------
__global__ __launch_bounds__(256) void denom_kernel(const float* __restrict__ k2,
                                                    float* __restrict__ denw) {
  __shared__ float red[256];
  int b = blockIdx.x;
  int t = threadIdx.x;
  float cs = 0.f;
  for (int i = 0; i < NM; ++i) cs += k2[((size_t)b * NM + i) * NM + t];
  red[t] = cs;
  __syncthreads();
  for (int off = 128; off; off >>= 1) {
    if (t < off) red[t] = fmaxf(red[t], red[t + off]);
    __syncthreads();
  }
  if (t == 0) denw[b] = red[0];
}

// ---------------- V0 = k2^T * invdenom (R5) ----------------
__global__ void vinit_kernel(const float* __restrict__ k2, const float* __restrict__ denw,
                             float* __restrict__ V) {
  int idx = blockIdx.x * 256 + threadIdx.x;
  int b = idx / (NM * NM), r = idx % (NM * NM), i = r / NM, j = r % NM;
  float dval = 1.0f / fmaxf(denw[0], denw[1]);
  V[idx] = k2[((size_t)b * NM + j) * NM + i] * dval;
}

// ================= NS: factored cubic, 3 homogeneous launches / iter ==========
#define NS_SMEM 70144   // As 32x260x4 (33280) + Bs 256x36x4 (36864)

// 32x32 output tile, full K=256, single barrier (R5 gemm_rk32 structure).
// B2 == nullptr: B plain.  B2 != nullptr: B_eff = B + B_COEF*B2 + C_COEF*I.
// O = s_ab * (A @ B_eff) + s_a * A
__device__ __forceinline__ void ns_tile(
    const float* __restrict__ A, const float* __restrict__ B,
    const float* __restrict__ B2, float* __restrict__ O,
    float s_a, float s_ab, size_t bo, int bi, int bj, char* smem, int t) {
  typedef float ARow[260];
  typedef float BRow[36];
  ARow* As = (ARow*)smem;
  BRow* Bs = (BRow*)(smem + 33280);
  #pragma unroll
  for (int q = 0; q < 8; ++q) {
    int s = q * 256 + t;
    int ar = s >> 6, ac = (s & 63) * 4;
    *(float4*)&As[ar][ac] = *(const float4*)(A + bo + (size_t)(bi + ar) * NM + ac);
    int bk = s >> 3, bc = (s & 7) * 4;
    if (B2 == nullptr) {
      *(float4*)&Bs[bk][bc] = *(const float4*)(B + bo + (size_t)bk * NM + bj + bc);
    } else {
      float4 v = *(const float4*)(B + bo + (size_t)bk * NM + bj + bc);
      float4 z = *(const float4*)(B2 + bo + (size_t)bk * NM + bj + bc);
      float4 rr;
      rr.x = v.x + B_COEF * z.x; rr.y = v.y + B_COEF * z.y;
      rr.z = v.z + B_COEF * z.z; rr.w = v.w + B_COEF * z.w;
      int d = bk - bj - bc;
      if (d >= 0 && d < 4) ((float*)&rr)[d] += C_COEF;
      *(float4*)&Bs[bk][bc] = rr;
    }
  }
  __syncthreads();
  int tx = t & 15, ty = t >> 4;
  float acc[2][2] = {};
  #pragma unroll 8
  for (int kk = 0; kk < NM; ++kk) {
    float a0 = As[ty * 2][kk], a1 = As[ty * 2 + 1][kk];
    float b0 = Bs[kk][tx * 2], b1 = Bs[kk][tx * 2 + 1];
    acc[0][0] += a0 * b0; acc[0][1] += a0 * b1;
    acc[1][0] += a1 * b0; acc[1][1] += a1 * b1;
  }
  #pragma unroll
  for (int i = 0; i < 2; ++i)
    #pragma unroll
    for (int j = 0; j < 2; ++j) {
      size_t o = bo + (size_t)(bi + ty * 2 + i) * NM + bj + tx * 2 + j;
      float r = s_ab * acc[i][j];
      if (s_a != 0.0f) r += s_a * A[o];
      O[o] = r;
    }
}

// Z = k2 @ V
__global__ __launch_bounds__(256) void ns_z_kernel(
    const float* __restrict__ k2, const float* __restrict__ V, float* __restrict__ Z) {
  __shared__ char smem[NS_SMEM];
  int blk = blockIdx.x, t = threadIdx.x;
  int b = blk >> 6, tile = blk & 63;
  int bi = (tile >> 3) * 32, bj = (tile & 7) * 32;
  ns_tile(k2, V, nullptr, Z, 0.f, 1.f, (size_t)b * NM * NM, bi, bj, smem, t);
}

// dual: blk<128 -> U = V@Z - a*V ; else -> Z2 = Z@Z
__global__ __launch_bounds__(256) void ns_uz2_kernel(
    const float* __restrict__ V, const float* __restrict__ Z,
    float* __restrict__ U, float* __restrict__ Z2) {
  __shared__ char smem[NS_SMEM];
  int blk = blockIdx.x, t = threadIdx.x;
  if (blk < NB * 64) {
    int b = blk >> 6, tile = blk & 63;
    int bi = (tile >> 3) * 32, bj = (tile & 7) * 32;
    ns_tile(V, Z, nullptr, U, -A_ROOT, 1.f, (size_t)b * NM * NM, bi, bj, smem, t);
  } else {
    int r = blk - NB * 64;
    int b = r >> 6, tile = r & 63;
    int bi = (tile >> 3) * 32, bj = (tile & 7) * 32;
    ns_tile(Z, Z, nullptr, Z2, 0.f, 1.f, (size_t)b * NM * NM, bi, bj, smem, t);
  }
}

// V' = -0.25 * U @ (Z2 + B_COEF*Z + C_COEF*I)
__global__ __launch_bounds__(256) void ns_v_kernel(
    const float* __restrict__ U, const float* __restrict__ Z2,
    const float* __restrict__ Z, float* __restrict__ Vout) {
  __shared__ char smem[NS_SMEM];
  int blk = blockIdx.x, t = threadIdx.x;
  int b = blk >> 6, tile = blk & 63;
  int bi = (tile >> 3) * 32, bj = (tile & 7) * 32;
  ns_tile(U, Z2, Z, Vout, 0.f, -0.25f, (size_t)b * NM * NM, bi, bj, smem, t);
}

// ---------------- Vinv fp32 -> bf16 transposed (R5) ----------------
__global__ __launch_bounds__(256) void cvt_vinv_kernel(const float* __restrict__ Va,
                                                       ushort* __restrict__ Vt) {
  int b = blockIdx.z;
  int n0 = blockIdx.x * 32, m0 = blockIdx.y * 32;
  __shared__ float tile[32][33];
  int t = threadIdx.x;
  int r = t >> 3, c4 = (t & 7) * 4;
  float4 v = *(const float4*)(Va + ((size_t)b * NM + m0 + r) * NM + n0 + c4);
  tile[c4][r] = v.x; tile[c4 + 1][r] = v.y; tile[c4 + 2][r] = v.z; tile[c4 + 3][r] = v.w;
  __syncthreads();
  ushort4 u;
  u.x = f2bf(tile[r][c4]);     u.y = f2bf(tile[r][c4 + 1]);
  u.z = f2bf(tile[r][c4 + 2]); u.w = f2bf(tile[r][c4 + 3]);
  *(ushort4*)(Vt + ((size_t)b * NM + n0 + r) * NM + m0 + c4) = u;
}

// ---------------- k3: [B][NM][NN] fp32 -> k3t: [B][NN][NM] bf16 (R5) ----------------
__global__ __launch_bounds__(256) void cvt_t_kernel(const float* __restrict__ k3,
                                                    ushort* __restrict__ k3t) {
  int b = blockIdx.z;
  int n0 = blockIdx.x * 32, m0 = blockIdx.y * 32;
  __shared__ float tile[32][33];
  int t = threadIdx.x;
  int r = t >> 3, c4 = (t & 7) * 4;
  float4 v = *(const float4*)(k3 + ((size_t)b * NM + m0 + r) * NN + n0 + c4);
  tile[c4][r] = v.x; tile[c4 + 1][r] = v.y; tile[c4 + 2][r] = v.z; tile[c4 + 3][r] = v.w;
  __syncthreads();
  ushort4 u;
  u.x = f2bf(tile[r][c4]);     u.y = f2bf(tile[r][c4 + 1]);
  u.z = f2bf(tile[r][c4 + 2]); u.w = f2bf(tile[r][c4 + 3]);
  *(ushort4*)(k3t + ((size_t)b * NN + n0 + r) * NM + m0 + c4) = u;
}

// ---------------- A = k1 @ Vinv via bf16 MFMA (R5) ----------------
__global__ __launch_bounds__(256) void gemm_a_mfma(
    const ushort* __restrict__ k1bf, const ushort* __restrict__ Vt,
    ushort* __restrict__ Abf) {
  int b = blockIdx.z;
  int bi = blockIdx.y * 128, bj = blockIdx.x * 128;
  __shared__ ushort As[128 * 64];
  __shared__ ushort Bs[128 * 64];
  int t = threadIdx.x;
  int wave = t >> 6, lane = t & 63;
  int wr = wave >> 1, wc = wave & 1;
  const ushort* Ab = k1bf + (size_t)b * NN * NM;
  const ushort* Bb = Vt + (size_t)b * NM * NM;
  f32x4 acc[4][4] = {};
  for (int k0 = 0; k0 < NM; k0 += 64) {
    #pragma unroll
    for (int q = 0; q < 4; ++q) {
      int s = q * 256 + t;
      int r = s >> 3, c = s & 7;
      int cs = (c ^ (r & 7)) << 3;
      gl_lds16(Ab + (size_t)(bi + r) * NM + k0 + cs, As + (size_t)s * 8);
      gl_lds16(Bb + (size_t)(bj + r) * NM + k0 + cs, Bs + (size_t)s * 8);
    }
    __syncthreads();
    #pragma unroll
    for (int kk = 0; kk < 2; ++kk) {
      int koff = kk * 64 + (lane >> 4) * 16;
      bf16x8 af[4], bfv[4];
      #pragma unroll
      for (int mi = 0; mi < 4; ++mi) {
        int row = wr * 64 + mi * 16 + (lane & 15);
        af[mi] = *(const bf16x8*)((const char*)As + row * 128 + (koff ^ ((row & 7) << 4)));
      }
      #pragma unroll
      for (int nj = 0; nj < 4; ++nj) {
        int row = wc * 64 + nj * 16 + (lane & 15);
        bfv[nj] = *(const bf16x8*)((const char*)Bs + row * 128 + (koff ^ ((row & 7) << 4)));
      }
      #pragma unroll
      for (int mi = 0; mi < 4; ++mi)
        #pragma unroll
        for (int nj = 0; nj < 4; ++nj)
          acc[mi][nj] = __builtin_amdgcn_mfma_f32_16x16x32_bf16(af[mi], bfv[nj], acc[mi][nj], 0, 0, 0);
    }
    __syncthreads();
  }
  int col = lane & 15, rbase = (lane >> 4) * 4;
  #pragma unroll
  for (int mi = 0; mi < 4; ++mi)
    #pragma unroll
    for (int nj = 0; nj < 4; ++nj)
      #pragma unroll
      for (int r = 0; r < 4; ++r)
        Abf[((size_t)b * NN + bi + wr * 64 + mi * 16 + rbase + r) * NM
            + bj + wc * 64 + nj * 16 + col] = f2bf(acc[mi][nj][r]);
}

// ---------------- attn = A @ k3 via bf16 MFMA, 128x128 tile, XCD swizzle (R5) ----------------
__global__ __launch_bounds__(256) void gemm_attn_mfma(
    const ushort* __restrict__ Abf, const ushort* __restrict__ K3T,
    float* __restrict__ attn) {
  int lin = blockIdx.z * 1024 + blockIdx.y * 32 + blockIdx.x;
  int swz = (lin & 7) * 256 + (lin >> 3);
  int b = swz >> 10;
  int rem = swz & 1023;
  int bi = (rem >> 5) * 128, bj = (rem & 31) * 128;
  __shared__ ushort As[128 * 64];
  __shared__ ushort Bs[128 * 64];
  int t = threadIdx.x;
  int wave = t >> 6, lane = t & 63;
  int wr = wave >> 1, wc = wave & 1;
  const ushort* Ab = Abf + (size_t)b * NN * NM;
  const ushort* Bb = K3T + (size_t)b * NN * NM;
  f32x4 acc[4][4] = {};
  for (int k0 = 0; k0 < NM; k0 += 64) {
    #pragma unroll
    for (int q = 0; q < 4; ++q) {
      int s = q * 256 + t;
      int r = s >> 3, c = s & 7;
      int cs = (c ^ (r & 7)) << 3;
      gl_lds16(Ab + (size_t)(bi + r) * NM + k0 + cs, As + (size_t)s * 8);
      gl_lds16(Bb + (size_t)(bj + r) * NM + k0 + cs, Bs + (size_t)s * 8);
    }
    __syncthreads();
    #pragma unroll
    for (int kk = 0; kk < 2; ++kk) {
      int koff = kk * 64 + (lane >> 4) * 16;
      bf16x8 af[4], bfv[4];
      #pragma unroll
      for (int mi = 0; mi < 4; ++mi) {
        int row = wr * 64 + mi * 16 + (lane & 15);
        af[mi] = *(const bf16x8*)((const char*)As + row * 128 + (koff ^ ((row & 7) << 4)));
      }
      #pragma unroll
      for (int nj = 0; nj < 4; ++nj) {
        int row = wc * 64 + nj * 16 + (lane & 15);
        bfv[nj] = *(const bf16x8*)((const char*)Bs + row * 128 + (koff ^ ((row & 7) << 4)));
      }
      #pragma unroll
      for (int mi = 0; mi < 4; ++mi)
        #pragma unroll
        for (int nj = 0; nj < 4; ++nj)
          acc[mi][nj] = __builtin_amdgcn_mfma_f32_16x16x32_bf16(af[mi], bfv[nj], acc[mi][nj], 0, 0, 0);
    }
    __syncthreads();
  }
  int col = lane & 15, rbase = (lane >> 4) * 4;
  #pragma unroll
  for (int mi = 0; mi < 4; ++mi)
    #pragma unroll
    for (int nj = 0; nj < 4; ++nj)
      #pragma unroll
      for (int r = 0; r < 4; ++r)
        attn[((size_t)b * NN + bi + wr * 64 + mi * 16 + rbase + r) * NN
             + bj + wc * 64 + nj * 16 + col] = acc[mi][nj][r];
}

// ---------------- split-K kv (atomicAdd into zeroed buffer, R5) ----------------
__global__ __launch_bounds__(256) void kv_kernel(
    const float* __restrict__ K3, const float* __restrict__ Vv,
    float* __restrict__ kvout) {
  int b = blockIdx.z, bp = blockIdx.x * 64;
  int j0base = blockIdx.y * (NN / 32);
  __shared__ float Ks[64][33], Vs[64][33];
  int t = threadIdx.x, tx = t & 15, ty = t >> 4;
  int lrow = t >> 2, ljc = (t & 3) * 8;
  float acc[4][4] = {};
  for (int j0 = j0base; j0 < j0base + NN / 32; j0 += 32) {
    float4 a0 = *(const float4*)(K3 + ((size_t)b * NM + bp + lrow) * NN + j0 + ljc);
    float4 a1 = *(const float4*)(K3 + ((size_t)b * NM + bp + lrow) * NN + j0 + ljc + 4);
    float4 v0 = *(const float4*)(Vv + ((size_t)b * NC + lrow) * NN + j0 + ljc);
    float4 v1 = *(const float4*)(Vv + ((size_t)b * NC + lrow) * NN + j0 + ljc + 4);
    Ks[lrow][ljc + 0] = a0.x; Ks[lrow][ljc + 1] = a0.y; Ks[lrow][ljc + 2] = a0.z; Ks[lrow][ljc + 3] = a0.w;
    Ks[lrow][ljc + 4] = a1.x; Ks[lrow][ljc + 5] = a1.y; Ks[lrow][ljc + 6] = a1.z; Ks[lrow][ljc + 7] = a1.w;
    Vs[lrow][ljc + 0] = v0.x; Vs[lrow][ljc + 1] = v0.y; Vs[lrow][ljc + 2] = v0.z; Vs[lrow][ljc + 3] = v0.w;
    Vs[lrow][ljc + 4] = v1.x; Vs[lrow][ljc + 5] = v1.y; Vs[lrow][ljc + 6] = v1.z; Vs[lrow][ljc + 7] = v1.w;
    __syncthreads();
    #pragma unroll
    for (int kk = 0; kk < 32; ++kk) {
      float av_[4], bv_[4];
      #pragma unroll
      for (int i = 0; i < 4; ++i) av_[i] = Ks[(ty << 2) + i][kk];
      #pragma unroll
      for (int j = 0; j < 4; ++j) bv_[j] = Vs[(tx << 2) + j][kk];
      #pragma unroll
      for (int i = 0; i < 4; ++i)
        #pragma unroll
        for (int j = 0; j < 4; ++j) acc[i][j] += av_[i] * bv_[j];
    }
    __syncthreads();
  }
  #pragma unroll
  for (int i = 0; i < 4; ++i)
    #pragma unroll
    for (int j = 0; j < 4; ++j)
      atomicAdd(&kvout[((size_t)b * NM + bp + (ty << 2) + i) * NC + (tx << 2) + j], acc[i][j]);
}

// ---------------- out = gamma*(A@kv) + x  (A in bf16, R5) ----------------
__global__ __launch_bounds__(256) void out_kernel(
    const ushort* __restrict__ Abf, const float* __restrict__ kvm,
    const float* __restrict__ x, const float* __restrict__ gamma,
    float* __restrict__ outp) {
  __shared__ float As[32 * 256];
  int blk = blockIdx.x;
  int b = blk / (NN / 32), n0 = (blk % (NN / 32)) * 32;
  int t = threadIdx.x;
  for (int it = 0; it < 32; ++it)
    As[it * 256 + (t ^ (it & 31))] = bf2f(Abf[((size_t)b * NN + n0 + it) * NM + t]);
  __syncthreads();
  int tn = t & 31, cg0 = (t >> 5) * 8;
  float g = gamma[0];
  float acc[8] = {};
  for (int p = 0; p < NM; ++p) {
    float a = As[tn * 256 + (p ^ (tn & 31))];
    float4 kv0 = *(const float4*)(kvm + ((size_t)b * NM + p) * NC + cg0);
    float4 kv1 = *(const float4*)(kvm + ((size_t)b * NM + p) * NC + cg0 + 4);
    acc[0] += a * kv0.x; acc[1] += a * kv0.y; acc[2] += a * kv0.z; acc[3] += a * kv0.w;
    acc[4] += a * kv1.x; acc[5] += a * kv1.y; acc[6] += a * kv1.z; acc[7] += a * kv1.w;
  }
  #pragma unroll
  for (int qd = 0; qd < 8; ++qd) {
    int c = cg0 + qd;
    size_t idx = ((size_t)b * NC + c) * NN + n0 + tn;
    outp[idx] = g * acc[qd] + x[idx];
  }
}

extern "C" void kernel_launch(void* const* d_in, const int* in_sizes, int n_in,
                              void* d_out, int out_size, void* d_ws, size_t ws_size,
                              hipStream_t stream) {
  const float* x     = (const float*)d_in[0];
  const float* wq    = (const float*)d_in[1];
  const float* bq    = (const float*)d_in[2];
  const float* wk    = (const float*)d_in[3];
  const float* bk    = (const float*)d_in[4];
  const float* wv    = (const float*)d_in[5];
  const float* bv    = (const float*)d_in[6];
  const float* gamma = (const float*)d_in[7];
  float* outp = (float*)d_out;                       // [B][C][N]
  float* attn = outp + (size_t)NB * NC * NN;         // [B][N][N]
  float* w = (float*)d_ws;

  float* qw   = w;                 // [B][N][D]    65536
  float* kw   = qw + 65536;        // [B][N][D]    65536
  float* vw   = kw + 65536;        // [B][C][N]    524288
  float* qlw  = vw + 524288;       // [B][M][D]    4096
  float* klw  = qlw + 4096;        // [B][M][D]    4096
  float* k1w  = klw + 4096;        // 8 MB region: k1bf (4MB) + k3T (4MB)
  float* k2w  = k1w + 2097152;     // [B][M][M]    131072
  float* k3w  = k2w + 131072;      // [B][M][N]    2097152
  float* Abuf = k3w + 2097152;     // 4 MB region: Abf bf16
  float* Zb   = Abuf + 1048576;    // [B][M][M]    131072
  float* Z2b  = Zb + 131072;       // [B][M][M]    131072
  float* Ub   = Z2b + 131072;      // [B][M][M]    131072
  float* Va   = Ub + 131072;       // [B][M][M]    131072
  float* Vtw  = Va + 131072;       // Vinvt bf16   65536 floats
  float* kvw  = Vtw + 65536;       // [B][M][C]    32768
  float* denw = kvw + 32768;       // [2]
  ushort* k1bf  = (ushort*)k1w;                 // [B][N][M] bf16
  ushort* k3T   = (ushort*)k1w + 2097152;       // [B][N][M] bf16 (k3^T)
  ushort* Abf   = (ushort*)Abuf;                // [B][N][M] bf16
  ushort* Vinvt = (ushort*)Vtw;                 // [B][M][M] bf16 (Vinv^T)

  hipMemsetAsync(kvw, 0, (size_t)NB * NM * NC * sizeof(float), stream);
  qkv2_kernel<<<dim3(80, NN / 1024, NB), dim3(256), 0, stream>>>(
      x, wq, bq, wk, bk, wv, bv, qw, kw, vw);
  landmark_kernel<<<dim3(NB * NM * ND / 256), dim3(256), 0, stream>>>(qw, kw, qlw, klw);
  scores_softmax_m_bf16<<<dim3(NN / 4, NB), dim3(256), 0, stream>>>(qw, NN, klw, k1bf);
  scores_softmax_m_f32<<<dim3(NM / 4, NB), dim3(256), 0, stream>>>(qlw, NM, klw, k2w);
  scores_softmax_n<<<dim3(NM, NB), dim3(256), 0, stream>>>(qlw, kw, k3w);
  denom_kernel<<<dim3(NB), dim3(256), 0, stream>>>(k2w, denw);
  vinit_kernel<<<dim3(NB * NM * NM / 256), dim3(256), 0, stream>>>(k2w, denw, Va);

  // Newton-Schulz via factored cubic (validated numerics): 18 homogeneous launches.
  for (int it = 0; it < 6; ++it) {
    ns_z_kernel<<<dim3(NB * 64), dim3(256), 0, stream>>>(k2w, Va, Zb);
    ns_uz2_kernel<<<dim3(2 * NB * 64), dim3(256), 0, stream>>>(Va, Zb, Ub, Z2b);
    ns_v_kernel<<<dim3(NB * 64), dim3(256), 0, stream>>>(Ub, Z2b, Zb, Va);
  }

  cvt_vinv_kernel<<<dim3(NM / 32, NM / 32, NB), dim3(256), 0, stream>>>(Va, Vinvt);
  cvt_t_kernel<<<dim3(NN / 32, NM / 32, NB), dim3(256), 0, stream>>>(k3w, k3T);
  gemm_a_mfma<<<dim3(NM / 128, NN / 128, NB), dim3(256), 0, stream>>>(k1bf, Vinvt, Abf);
  gemm_attn_mfma<<<dim3(NN / 128, NN / 128, NB), dim3(256), 0, stream>>>(Abf, k3T, attn);
  kv_kernel<<<dim3(NM / 64, 32, NB), dim3(256), 0, stream>>>(k3w, vw, kvw);
  out_kernel<<<dim3(NB * NN / 32), dim3(256), 0, stream>>>(Abf, kvw, x, gamma, outp);
}

// Round 11
// 301.990 us; speedup vs baseline: 1.0564x; 1.0564x over previous
//
#include <hip/hip_runtime.h>
#include <hip/hip_bf16.h>
#include <math.h>

#define NB 2        // batch
#define NC 64       // channels
#define ND 8        // head dim (C/8)
#define NN 4096     // tokens (T*W*H)
#define NM 256      // landmarks
#define NL 16       // N/M
#define SCALE 0.35355339059327373f  // 1/sqrt(8)

typedef __attribute__((ext_vector_type(4))) float f32x4;
typedef __attribute__((ext_vector_type(8))) short bf16x8;

__device__ inline ushort f2bf(float f) {
  __hip_bfloat16 h = __float2bfloat16(f);
  return *reinterpret_cast<ushort*>(&h);
}
__device__ inline float bf2f(ushort u) {
  return __uint_as_float(((unsigned int)u) << 16);
}

// async global->LDS, 16B per lane; LDS dest must be wave-linear (base + lane*16)
__device__ inline void gl_lds16(const void* g, void* l) {
  __builtin_amdgcn_global_load_lds(
      (const __attribute__((address_space(1))) unsigned int*)g,
      (__attribute__((address_space(3))) unsigned int*)l, 16, 0, 0);
}

// ---------------- qkv projection + fused landmark means (R6-validated) ----------------
__global__ __launch_bounds__(256) void qkv2l_kernel(
    const float* __restrict__ x,
    const float* __restrict__ wq, const float* __restrict__ bq,
    const float* __restrict__ wk, const float* __restrict__ bk,
    const float* __restrict__ wv, const float* __restrict__ bv,
    float* __restrict__ q, float* __restrict__ k, float* __restrict__ v,
    float* __restrict__ ql, float* __restrict__ kl) {
  __shared__ float ws[NC];
  int o = blockIdx.x;            // 0..79: 0-7 q, 8-15 k, 16-79 v
  int b = blockIdx.z;
  int n0 = blockIdx.y * 1024;
  int t = threadIdx.x;
  const float* wrow;
  float bias;
  if (o < ND)            { wrow = wq + (size_t)o * NC;            bias = bq[o]; }
  else if (o < 2 * ND)   { wrow = wk + (size_t)(o - ND) * NC;     bias = bk[o - ND]; }
  else                   { wrow = wv + (size_t)(o - 2 * ND) * NC; bias = bv[o - 2 * ND]; }
  if (t < NC) ws[t] = wrow[t];
  __syncthreads();
  int n = n0 + t * 4;
  float4 acc = {bias, bias, bias, bias};
  #pragma unroll
  for (int c = 0; c < NC; ++c) {
    float wc = ws[c];
    float4 xv = *(const float4*)(x + ((size_t)b * NC + c) * NN + n);
    acc.x += wc * xv.x; acc.y += wc * xv.y; acc.z += wc * xv.z; acc.w += wc * xv.w;
  }
  if (o < ND) {
    float* qp = q + ((size_t)b * NN + n) * ND + o;
    qp[0] = acc.x; qp[8] = acc.y; qp[16] = acc.z; qp[24] = acc.w;
  } else if (o < 2 * ND) {
    float* kp = k + ((size_t)b * NN + n) * ND + (o - ND);
    kp[0] = acc.x; kp[8] = acc.y; kp[16] = acc.z; kp[24] = acc.w;
  } else {
    *(float4*)(v + ((size_t)b * NC + (o - 2 * ND)) * NN + n) = acc;
  }
  // fused landmark: group of 16 tokens = 4 consecutive threads (wave-aligned quads)
  if (o < 2 * ND) {
    float s4 = acc.x + acc.y + acc.z + acc.w;
    s4 += __shfl_xor(s4, 1);
    s4 += __shfl_xor(s4, 2);
    if ((t & 3) == 0) {
      int g = n0 / 16 + (t >> 2);
      float* dst = (o < ND) ? ql : kl;
      dst[((size_t)b * NM + g) * ND + (o & 7)] = s4 * (1.0f / 16.0f);
    }
  }
}

// ---------------- merged softmaxes: k1 bf16 / k2 f32 / k3 f32 (R6-validated) ----------------
__global__ __launch_bounds__(256) void scores_all_kernel(
    const float* __restrict__ q, const float* __restrict__ ql,
    const float* __restrict__ kw, const float* __restrict__ kl,
    ushort* __restrict__ k1bf, float* __restrict__ k2w,
    float* __restrict__ k3w) {
  __shared__ float skl[NM][9];
  __shared__ float wred[4], wsum[4];
  int blk = blockIdx.x;
  int t = threadIdx.x;
  if (blk < 2048 + 128) {
    const float* Q; int R, b, xrow;
    bool isbf;
    if (blk < 2048) { b = blk >> 10; xrow = blk & 1023; Q = q;  R = NN; isbf = true; }
    else { int r = blk - 2048; b = r >> 6; xrow = r & 63; Q = ql; R = NM; isbf = false; }
    for (int i = t; i < NM * ND; i += 256) skl[i >> 3][i & 7] = kl[(size_t)b * NM * ND + i];
    __syncthreads();
    int wave = t >> 6, lane = t & 63;
    int r = xrow * 4 + wave;
    const float* qrow = Q + ((size_t)b * R + r) * ND;
    float qr[ND];
    #pragma unroll
    for (int dd = 0; dd < ND; ++dd) qr[dd] = qrow[dd];
    float sc[4];
    float lmax = -1e30f;
    #pragma unroll
    for (int s = 0; s < 4; ++s) {
      int j = lane + 64 * s;
      float a = 0.f;
      #pragma unroll
      for (int dd = 0; dd < ND; ++dd) a += qr[dd] * skl[j][dd];
      sc[s] = a * SCALE;
      lmax = fmaxf(lmax, sc[s]);
    }
    for (int off = 32; off; off >>= 1) lmax = fmaxf(lmax, __shfl_xor(lmax, off));
    float lsum = 0.f;
    #pragma unroll
    for (int s = 0; s < 4; ++s) { sc[s] = expf(sc[s] - lmax); lsum += sc[s]; }
    for (int off = 32; off; off >>= 1) lsum += __shfl_xor(lsum, off);
    float inv = 1.0f / lsum;
    if (isbf) {
      #pragma unroll
      for (int s = 0; s < 4; ++s)
        k1bf[((size_t)b * R + r) * NM + lane + 64 * s] = f2bf(sc[s] * inv);
    } else {
      #pragma unroll
      for (int s = 0; s < 4; ++s)
        k2w[((size_t)b * R + r) * NM + lane + 64 * s] = sc[s] * inv;
    }
  } else {
    // k3 softmax: landmark queries vs all keys
    int r = blk - 2176;
    int b = r >> 8, i = r & 255;
    float qr[ND];
    #pragma unroll
    for (int dd = 0; dd < ND; ++dd) qr[dd] = ql[((size_t)b * NM + i) * ND + dd];
    float sc[16];
    float lmax = -1e30f;
    #pragma unroll
    for (int s = 0; s < 16; ++s) {
      int n = t + 256 * s;
      const float* kp = kw + ((size_t)b * NN + n) * ND;
      float a = 0.f;
      #pragma unroll
      for (int dd = 0; dd < ND; ++dd) a += qr[dd] * kp[dd];
      sc[s] = a * SCALE;
      lmax = fmaxf(lmax, sc[s]);
    }
    for (int off = 32; off; off >>= 1) lmax = fmaxf(lmax, __shfl_xor(lmax, off));
    if ((t & 63) == 0) wred[t >> 6] = lmax;
    __syncthreads();
    lmax = fmaxf(fmaxf(wred[0], wred[1]), fmaxf(wred[2], wred[3]));
    float lsum = 0.f;
    #pragma unroll
    for (int s = 0; s < 16; ++s) { sc[s] = expf(sc[s] - lmax); lsum += sc[s]; }
    for (int off = 32; off; off >>= 1) lsum += __shfl_xor(lsum, off);
    if ((t & 63) == 0) wsum[t >> 6] = lsum;
    __syncthreads();
    lsum = wsum[0] + wsum[1] + wsum[2] + wsum[3];
    float inv = 1.0f / lsum;
    #pragma unroll
    for (int s = 0; s < 16; ++s) k3w[((size_t)b * NM + i) * NN + t + 256 * s] = sc[s] * inv;
  }
}

// ---------------- denom: max column-sum per batch (R5) ----------------
__global__ __launch_bounds__(256) void denom_kernel(const float* __restrict__ k2,
                                                    float* __restrict__ denw) {
  __shared__ float red[256];
  int b = blockIdx.x;
  int t = threadIdx.x;
  float cs = 0.f;
  for (int i = 0; i < NM; ++i) cs += k2[((size_t)b * NM + i) * NM + t];
  red[t] = cs;
  __syncthreads();
  for (int off = 128; off; off >>= 1) {
    if (t < off) red[t] = fmaxf(red[t], red[t + off]);
    __syncthreads();
  }
  if (t == 0) denw[b] = red[0];
}

// ---------------- V0 = k2^T * invdenom (R5) ----------------
__global__ void vinit_kernel(const float* __restrict__ k2, const float* __restrict__ denw,
                             float* __restrict__ V) {
  int idx = blockIdx.x * 256 + threadIdx.x;
  int b = idx / (NM * NM), r = idx % (NM * NM), i = r / NM, j = r % NM;
  float dval = 1.0f / fmaxf(denw[0], denw[1]);
  V[idx] = k2[((size_t)b * NM + j) * NM + i] * dval;
}

// ---------------- 32x32-tile batched GEMM, full-panel single-barrier (R5, 303-verified) ----------------
// out = s_a*A + s_ab*(A @ Bm);  A,Bm,out: [B][256][256]; grid (8,8,B)
__global__ __launch_bounds__(256) void gemm_rk32(
    const float* __restrict__ A, const float* __restrict__ Bm,
    float* __restrict__ out, float s_a, float s_ab) {
  int b = blockIdx.z;
  int bi = blockIdx.y * 32, bj = blockIdx.x * 32;
  __shared__ float As[32][260];   // [row][k], pad 260 for conflict-free + 16B-aligned rows
  __shared__ float Bs[256][36];   // [k][col], pad 36
  int t = threadIdx.x;
  const float* Ab = A + (size_t)b * NM * NM;
  const float* Bb = Bm + (size_t)b * NM * NM;
  #pragma unroll
  for (int q = 0; q < 8; ++q) {
    int s = q * 256 + t;
    int ar = s >> 6, ac = (s & 63) * 4;
    *(float4*)&As[ar][ac] = *(const float4*)(Ab + (size_t)(bi + ar) * NM + ac);
    int br = s >> 3, bc = (s & 7) * 4;
    *(float4*)&Bs[br][bc] = *(const float4*)(Bb + (size_t)br * NM + bj + bc);
  }
  __syncthreads();
  int tx = t & 15, ty = t >> 4;
  float acc[2][2] = {};
  #pragma unroll 8
  for (int kk = 0; kk < NM; ++kk) {
    float a0 = As[ty * 2][kk], a1 = As[ty * 2 + 1][kk];
    float b0 = Bs[kk][tx * 2], b1 = Bs[kk][tx * 2 + 1];
    acc[0][0] += a0 * b0; acc[0][1] += a0 * b1;
    acc[1][0] += a1 * b0; acc[1][1] += a1 * b1;
  }
  #pragma unroll
  for (int i = 0; i < 2; ++i)
    #pragma unroll
    for (int j = 0; j < 2; ++j) {
      size_t o = ((size_t)b * NM + bi + ty * 2 + i) * NM + bj + tx * 2 + j;
      float r = s_ab * acc[i][j];
      if (s_a != 0.0f) r += s_a * A[o];
      out[o] = r;
    }
}

// ---------------- Vinv fp32 -> bf16 transposed (R5) ----------------
__global__ __launch_bounds__(256) void cvt_vinv_kernel(const float* __restrict__ Va,
                                                       ushort* __restrict__ Vt) {
  int b = blockIdx.z;
  int n0 = blockIdx.x * 32, m0 = blockIdx.y * 32;
  __shared__ float tile[32][33];
  int t = threadIdx.x;
  int r = t >> 3, c4 = (t & 7) * 4;
  float4 v = *(const float4*)(Va + ((size_t)b * NM + m0 + r) * NM + n0 + c4);
  tile[c4][r] = v.x; tile[c4 + 1][r] = v.y; tile[c4 + 2][r] = v.z; tile[c4 + 3][r] = v.w;
  __syncthreads();
  ushort4 u;
  u.x = f2bf(tile[r][c4]);     u.y = f2bf(tile[r][c4 + 1]);
  u.z = f2bf(tile[r][c4 + 2]); u.w = f2bf(tile[r][c4 + 3]);
  *(ushort4*)(Vt + ((size_t)b * NM + n0 + r) * NM + m0 + c4) = u;
}

// ---------------- k3: [B][NM][NN] fp32 -> k3t: [B][NN][NM] bf16 (R5) ----------------
__global__ __launch_bounds__(256) void cvt_t_kernel(const float* __restrict__ k3,
                                                    ushort* __restrict__ k3t) {
  int b = blockIdx.z;
  int n0 = blockIdx.x * 32, m0 = blockIdx.y * 32;
  __shared__ float tile[32][33];
  int t = threadIdx.x;
  int r = t >> 3, c4 = (t & 7) * 4;
  float4 v = *(const float4*)(k3 + ((size_t)b * NM + m0 + r) * NN + n0 + c4);
  tile[c4][r] = v.x; tile[c4 + 1][r] = v.y; tile[c4 + 2][r] = v.z; tile[c4 + 3][r] = v.w;
  __syncthreads();
  ushort4 u;
  u.x = f2bf(tile[r][c4]);     u.y = f2bf(tile[r][c4 + 1]);
  u.z = f2bf(tile[r][c4 + 2]); u.w = f2bf(tile[r][c4 + 3]);
  *(ushort4*)(k3t + ((size_t)b * NN + n0 + r) * NM + m0 + c4) = u;
}

// ---------------- A = k1 @ Vinv via bf16 MFMA (R5) ----------------
__global__ __launch_bounds__(256) void gemm_a_mfma(
    const ushort* __restrict__ k1bf, const ushort* __restrict__ Vt,
    ushort* __restrict__ Abf) {
  int b = blockIdx.z;
  int bi = blockIdx.y * 128, bj = blockIdx.x * 128;
  __shared__ ushort As[128 * 64];
  __shared__ ushort Bs[128 * 64];
  int t = threadIdx.x;
  int wave = t >> 6, lane = t & 63;
  int wr = wave >> 1, wc = wave & 1;
  const ushort* Ab = k1bf + (size_t)b * NN * NM;
  const ushort* Bb = Vt + (size_t)b * NM * NM;
  f32x4 acc[4][4] = {};
  for (int k0 = 0; k0 < NM; k0 += 64) {
    #pragma unroll
    for (int q = 0; q < 4; ++q) {
      int s = q * 256 + t;
      int r = s >> 3, c = s & 7;
      int cs = (c ^ (r & 7)) << 3;
      gl_lds16(Ab + (size_t)(bi + r) * NM + k0 + cs, As + (size_t)s * 8);
      gl_lds16(Bb + (size_t)(bj + r) * NM + k0 + cs, Bs + (size_t)s * 8);
    }
    __syncthreads();
    #pragma unroll
    for (int kk = 0; kk < 2; ++kk) {
      int koff = kk * 64 + (lane >> 4) * 16;
      bf16x8 af[4], bfv[4];
      #pragma unroll
      for (int mi = 0; mi < 4; ++mi) {
        int row = wr * 64 + mi * 16 + (lane & 15);
        af[mi] = *(const bf16x8*)((const char*)As + row * 128 + (koff ^ ((row & 7) << 4)));
      }
      #pragma unroll
      for (int nj = 0; nj < 4; ++nj) {
        int row = wc * 64 + nj * 16 + (lane & 15);
        bfv[nj] = *(const bf16x8*)((const char*)Bs + row * 128 + (koff ^ ((row & 7) << 4)));
      }
      #pragma unroll
      for (int mi = 0; mi < 4; ++mi)
        #pragma unroll
        for (int nj = 0; nj < 4; ++nj)
          acc[mi][nj] = __builtin_amdgcn_mfma_f32_16x16x32_bf16(af[mi], bfv[nj], acc[mi][nj], 0, 0, 0);
    }
    __syncthreads();
  }
  int col = lane & 15, rbase = (lane >> 4) * 4;
  #pragma unroll
  for (int mi = 0; mi < 4; ++mi)
    #pragma unroll
    for (int nj = 0; nj < 4; ++nj)
      #pragma unroll
      for (int r = 0; r < 4; ++r)
        Abf[((size_t)b * NN + bi + wr * 64 + mi * 16 + rbase + r) * NM
            + bj + wc * 64 + nj * 16 + col] = f2bf(acc[mi][nj][r]);
}

// ---------------- attn = A @ k3 via bf16 MFMA, 128x128 tile, XCD swizzle (R5 + nt stores) ----------------
__global__ __launch_bounds__(256) void gemm_attn_mfma(
    const ushort* __restrict__ Abf, const ushort* __restrict__ K3T,
    float* __restrict__ attn) {
  int lin = blockIdx.z * 1024 + blockIdx.y * 32 + blockIdx.x;
  int swz = (lin & 7) * 256 + (lin >> 3);
  int b = swz >> 10;
  int rem = swz & 1023;
  int bi = (rem >> 5) * 128, bj = (rem & 31) * 128;
  __shared__ ushort As[128 * 64];
  __shared__ ushort Bs[128 * 64];
  int t = threadIdx.x;
  int wave = t >> 6, lane = t & 63;
  int wr = wave >> 1, wc = wave & 1;
  const ushort* Ab = Abf + (size_t)b * NN * NM;
  const ushort* Bb = K3T + (size_t)b * NN * NM;
  f32x4 acc[4][4] = {};
  for (int k0 = 0; k0 < NM; k0 += 64) {
    #pragma unroll
    for (int q = 0; q < 4; ++q) {
      int s = q * 256 + t;
      int r = s >> 3, c = s & 7;
      int cs = (c ^ (r & 7)) << 3;
      gl_lds16(Ab + (size_t)(bi + r) * NM + k0 + cs, As + (size_t)s * 8);
      gl_lds16(Bb + (size_t)(bj + r) * NM + k0 + cs, Bs + (size_t)s * 8);
    }
    __syncthreads();
    #pragma unroll
    for (int kk = 0; kk < 2; ++kk) {
      int koff = kk * 64 + (lane >> 4) * 16;
      bf16x8 af[4], bfv[4];
      #pragma unroll
      for (int mi = 0; mi < 4; ++mi) {
        int row = wr * 64 + mi * 16 + (lane & 15);
        af[mi] = *(const bf16x8*)((const char*)As + row * 128 + (koff ^ ((row & 7) << 4)));
      }
      #pragma unroll
      for (int nj = 0; nj < 4; ++nj) {
        int row = wc * 64 + nj * 16 + (lane & 15);
        bfv[nj] = *(const bf16x8*)((const char*)Bs + row * 128 + (koff ^ ((row & 7) << 4)));
      }
      #pragma unroll
      for (int mi = 0; mi < 4; ++mi)
        #pragma unroll
        for (int nj = 0; nj < 4; ++nj)
          acc[mi][nj] = __builtin_amdgcn_mfma_f32_16x16x32_bf16(af[mi], bfv[nj], acc[mi][nj], 0, 0, 0);
    }
    __syncthreads();
  }
  // attn is write-once, never re-read in-pipeline -> nontemporal (skip L2 pollution)
  int col = lane & 15, rbase = (lane >> 4) * 4;
  #pragma unroll
  for (int mi = 0; mi < 4; ++mi)
    #pragma unroll
    for (int nj = 0; nj < 4; ++nj)
      #pragma unroll
      for (int r = 0; r < 4; ++r)
        __builtin_nontemporal_store(
            acc[mi][nj][r],
            &attn[((size_t)b * NN + bi + wr * 64 + mi * 16 + rbase + r) * NN
                  + bj + wc * 64 + nj * 16 + col]);
}

// ---------------- split-K kv (atomicAdd into zeroed buffer, R5) ----------------
__global__ __launch_bounds__(256) void kv_kernel(
    const float* __restrict__ K3, const float* __restrict__ Vv,
    float* __restrict__ kvout) {
  int b = blockIdx.z, bp = blockIdx.x * 64;
  int j0base = blockIdx.y * (NN / 32);
  __shared__ float Ks[64][33], Vs[64][33];
  int t = threadIdx.x, tx = t & 15, ty = t >> 4;
  int lrow = t >> 2, ljc = (t & 3) * 8;
  float acc[4][4] = {};
  for (int j0 = j0base; j0 < j0base + NN / 32; j0 += 32) {
    float4 a0 = *(const float4*)(K3 + ((size_t)b * NM + bp + lrow) * NN + j0 + ljc);
    float4 a1 = *(const float4*)(K3 + ((size_t)b * NM + bp + lrow) * NN + j0 + ljc + 4);
    float4 v0 = *(const float4*)(Vv + ((size_t)b * NC + lrow) * NN + j0 + ljc);
    float4 v1 = *(const float4*)(Vv + ((size_t)b * NC + lrow) * NN + j0 + ljc + 4);
    Ks[lrow][ljc + 0] = a0.x; Ks[lrow][ljc + 1] = a0.y; Ks[lrow][ljc + 2] = a0.z; Ks[lrow][ljc + 3] = a0.w;
    Ks[lrow][ljc + 4] = a1.x; Ks[lrow][ljc + 5] = a1.y; Ks[lrow][ljc + 6] = a1.z; Ks[lrow][ljc + 7] = a1.w;
    Vs[lrow][ljc + 0] = v0.x; Vs[lrow][ljc + 1] = v0.y; Vs[lrow][ljc + 2] = v0.z; Vs[lrow][ljc + 3] = v0.w;
    Vs[lrow][ljc + 4] = v1.x; Vs[lrow][ljc + 5] = v1.y; Vs[lrow][ljc + 6] = v1.z; Vs[lrow][ljc + 7] = v1.w;
    __syncthreads();
    #pragma unroll
    for (int kk = 0; kk < 32; ++kk) {
      float av_[4], bv_[4];
      #pragma unroll
      for (int i = 0; i < 4; ++i) av_[i] = Ks[(ty << 2) + i][kk];
      #pragma unroll
      for (int j = 0; j < 4; ++j) bv_[j] = Vs[(tx << 2) + j][kk];
      #pragma unroll
      for (int i = 0; i < 4; ++i)
        #pragma unroll
        for (int j = 0; j < 4; ++j) acc[i][j] += av_[i] * bv_[j];
    }
    __syncthreads();
  }
  #pragma unroll
  for (int i = 0; i < 4; ++i)
    #pragma unroll
    for (int j = 0; j < 4; ++j)
      atomicAdd(&kvout[((size_t)b * NM + bp + (ty << 2) + i) * NC + (tx << 2) + j], acc[i][j]);
}

// ---------------- out = gamma*(A@kv) + x  (A in bf16, R5 + nt stores) ----------------
__global__ __launch_bounds__(256) void out_kernel(
    const ushort* __restrict__ Abf, const float* __restrict__ kvm,
    const float* __restrict__ x, const float* __restrict__ gamma,
    float* __restrict__ outp) {
  __shared__ float As[32 * 256];
  int blk = blockIdx.x;
  int b = blk / (NN / 32), n0 = (blk % (NN / 32)) * 32;
  int t = threadIdx.x;
  for (int it = 0; it < 32; ++it)
    As[it * 256 + (t ^ (it & 31))] = bf2f(Abf[((size_t)b * NN + n0 + it) * NM + t]);
  __syncthreads();
  int tn = t & 31, cg0 = (t >> 5) * 8;
  float g = gamma[0];
  float acc[8] = {};
  for (int p = 0; p < NM; ++p) {
    float a = As[tn * 256 + (p ^ (tn & 31))];
    float4 kv0 = *(const float4*)(kvm + ((size_t)b * NM + p) * NC + cg0);
    float4 kv1 = *(const float4*)(kvm + ((size_t)b * NM + p) * NC + cg0 + 4);
    acc[0] += a * kv0.x; acc[1] += a * kv0.y; acc[2] += a * kv0.z; acc[3] += a * kv0.w;
    acc[4] += a * kv1.x; acc[5] += a * kv1.y; acc[6] += a * kv1.z; acc[7] += a * kv1.w;
  }
  #pragma unroll
  for (int qd = 0; qd < 8; ++qd) {
    int c = cg0 + qd;
    size_t idx = ((size_t)b * NC + c) * NN + n0 + tn;
    __builtin_nontemporal_store(g * acc[qd] + x[idx], &outp[idx]);
  }
}

extern "C" void kernel_launch(void* const* d_in, const int* in_sizes, int n_in,
                              void* d_out, int out_size, void* d_ws, size_t ws_size,
                              hipStream_t stream) {
  const float* x     = (const float*)d_in[0];
  const float* wq    = (const float*)d_in[1];
  const float* bq    = (const float*)d_in[2];
  const float* wk    = (const float*)d_in[3];
  const float* bk    = (const float*)d_in[4];
  const float* wv    = (const float*)d_in[5];
  const float* bv    = (const float*)d_in[6];
  const float* gamma = (const float*)d_in[7];
  float* outp = (float*)d_out;                       // [B][C][N]
  float* attn = outp + (size_t)NB * NC * NN;         // [B][N][N]
  float* w = (float*)d_ws;

  float* qw   = w;                 // [B][N][D]    65536
  float* kw   = qw + 65536;        // [B][N][D]    65536
  float* vw   = kw + 65536;        // [B][C][N]    524288
  float* qlw  = vw + 524288;       // [B][M][D]    4096
  float* klw  = qlw + 4096;        // [B][M][D]    4096
  float* k1w  = klw + 4096;        // 8 MB region: k1bf (4MB) + k3T (4MB)
  float* k2w  = k1w + 2097152;     // [B][M][M]    131072
  float* k3w  = k2w + 131072;      // [B][M][N]    2097152
  float* Abuf = k3w + 2097152;     // 4 MB region: Abf bf16
  float* Va   = Abuf + 1048576;    // [B][M][M]    131072
  float* Vb   = Va + 131072;       // [B][M][M]    131072
  float* Zb   = Vb + 131072;       // [B][M][M]    131072
  float* T1   = Zb + 131072;       // [B][M][M]    131072
  float* T2   = T1 + 131072;       // [B][M][M]    131072
  float* Vtw  = T2 + 131072;       // Vinvt bf16   65536 floats
  float* kvw  = Vtw + 65536;       // [B][M][C]    32768
  float* denw = kvw + 32768;       // [2]
  ushort* k1bf  = (ushort*)k1w;                 // [B][N][M] bf16
  ushort* k3T   = (ushort*)k1w + 2097152;       // [B][N][M] bf16 (k3^T)
  ushort* Abf   = (ushort*)Abuf;                // [B][N][M] bf16
  ushort* Vinvt = (ushort*)Vtw;                 // [B][M][M] bf16 (Vinv^T)

  hipMemsetAsync(kvw, 0, (size_t)NB * NM * NC * sizeof(float), stream);
  qkv2l_kernel<<<dim3(80, NN / 1024, NB), dim3(256), 0, stream>>>(
      x, wq, bq, wk, bk, wv, bv, qw, kw, vw, qlw, klw);
  scores_all_kernel<<<dim3(2048 + 128 + 512), dim3(256), 0, stream>>>(
      qw, qlw, kw, klw, k1bf, k2w, k3w);
  denom_kernel<<<dim3(NB), dim3(256), 0, stream>>>(k2w, denw);
  vinit_kernel<<<dim3(NB * NM * NM / 256), dim3(256), 0, stream>>>(k2w, denw, Va);

  // Newton-Schulz: R5's verified 24-launch plain chain (measured-best structure)
  float* Vc = Va; float* Vn = Vb;
  for (int it = 0; it < 6; ++it) {
    gemm_rk32<<<dim3(8, 8, NB), dim3(256), 0, stream>>>(k2w, Vc, Zb, 0.f, 1.f);     // Z = K@V
    gemm_rk32<<<dim3(8, 8, NB), dim3(256), 0, stream>>>(Zb, Zb, T1, 7.f, -1.f);     // T1 = 7Z - Z@Z
    gemm_rk32<<<dim3(8, 8, NB), dim3(256), 0, stream>>>(Zb, T1, T2, 15.f, -1.f);    // T2 = 15Z - Z@T1
    gemm_rk32<<<dim3(8, 8, NB), dim3(256), 0, stream>>>(Vc, T2, Vn, 3.25f, -0.25f); // V' = 3.25V - .25V@T2
    float* tmp = Vc; Vc = Vn; Vn = tmp;
  }
  // final Vinv in Vc (= Va after 6 swaps)

  cvt_vinv_kernel<<<dim3(NM / 32, NM / 32, NB), dim3(256), 0, stream>>>(Vc, Vinvt);
  cvt_t_kernel<<<dim3(NN / 32, NM / 32, NB), dim3(256), 0, stream>>>(k3w, k3T);
  gemm_a_mfma<<<dim3(NM / 128, NN / 128, NB), dim3(256), 0, stream>>>(k1bf, Vinvt, Abf);
  gemm_attn_mfma<<<dim3(NN / 128, NN / 128, NB), dim3(256), 0, stream>>>(Abf, k3T, attn);
  kv_kernel<<<dim3(NM / 64, 32, NB), dim3(256), 0, stream>>>(k3w, vw, kvw);
  out_kernel<<<dim3(NB * NN / 32), dim3(256), 0, stream>>>(Abf, kvw, x, gamma, outp);
}

// Round 12
// 299.107 us; speedup vs baseline: 1.0666x; 1.0096x over previous
//
#include <hip/hip_runtime.h>
#include <hip/hip_bf16.h>
#include <math.h>

#define NB 2        // batch
#define NC 64       // channels
#define ND 8        // head dim (C/8)
#define NN 4096     // tokens (T*W*H)
#define NM 256      // landmarks
#define NL 16       // N/M
#define SCALE 0.35355339059327373f  // 1/sqrt(8)

typedef __attribute__((ext_vector_type(4))) float f32x4;
typedef __attribute__((ext_vector_type(8))) short bf16x8;

__device__ inline ushort f2bf(float f) {
  __hip_bfloat16 h = __float2bfloat16(f);
  return *reinterpret_cast<ushort*>(&h);
}
__device__ inline float bf2f(ushort u) {
  return __uint_as_float(((unsigned int)u) << 16);
}

// async global->LDS, 16B per lane; LDS dest must be wave-linear (base + lane*16)
__device__ inline void gl_lds16(const void* g, void* l) {
  __builtin_amdgcn_global_load_lds(
      (const __attribute__((address_space(1))) unsigned int*)g,
      (__attribute__((address_space(3))) unsigned int*)l, 16, 0, 0);
}

// ---------------- qkv projection, 4 output rows per block + fused landmarks ----------------
// grid (20, NN/1024, NB); block 256; x read 20x instead of 80x
__global__ __launch_bounds__(256) void qkv4_kernel(
    const float* __restrict__ x,
    const float* __restrict__ wq, const float* __restrict__ bq,
    const float* __restrict__ wk, const float* __restrict__ bk,
    const float* __restrict__ wv, const float* __restrict__ bv,
    float* __restrict__ q, float* __restrict__ k, float* __restrict__ v,
    float* __restrict__ ql, float* __restrict__ kl) {
  __shared__ float ws[4][NC];
  int o0 = blockIdx.x * 4;       // 0..76; groups never straddle q/k/v boundaries
  int b = blockIdx.z;
  int n0 = blockIdx.y * 1024;
  int t = threadIdx.x;
  {
    int j = t >> 6, c = t & 63;
    int o = o0 + j;
    const float* wrow;
    if (o < ND)          wrow = wq + (size_t)o * NC;
    else if (o < 2 * ND) wrow = wk + (size_t)(o - ND) * NC;
    else                 wrow = wv + (size_t)(o - 2 * ND) * NC;
    ws[j][c] = wrow[c];
  }
  __syncthreads();
  int n = n0 + t * 4;
  float4 acc[4];
  #pragma unroll
  for (int j = 0; j < 4; ++j) {
    int o = o0 + j;
    float bias = (o < ND) ? bq[o] : (o < 2 * ND ? bk[o - ND] : bv[o - 2 * ND]);
    acc[j].x = bias; acc[j].y = bias; acc[j].z = bias; acc[j].w = bias;
  }
  for (int c = 0; c < NC; ++c) {
    float4 xv = *(const float4*)(x + ((size_t)b * NC + c) * NN + n);
    #pragma unroll
    for (int j = 0; j < 4; ++j) {
      float wc = ws[j][c];
      acc[j].x += wc * xv.x; acc[j].y += wc * xv.y;
      acc[j].z += wc * xv.z; acc[j].w += wc * xv.w;
    }
  }
  #pragma unroll
  for (int j = 0; j < 4; ++j) {
    int o = o0 + j;
    if (o < ND) {
      float* qp = q + ((size_t)b * NN + n) * ND + o;
      qp[0] = acc[j].x; qp[8] = acc[j].y; qp[16] = acc[j].z; qp[24] = acc[j].w;
    } else if (o < 2 * ND) {
      float* kp = k + ((size_t)b * NN + n) * ND + (o - ND);
      kp[0] = acc[j].x; kp[8] = acc[j].y; kp[16] = acc[j].z; kp[24] = acc[j].w;
    } else {
      *(float4*)(v + ((size_t)b * NC + (o - 2 * ND)) * NN + n) = acc[j];
    }
    // fused landmark means (quads of threads = 16 tokens), q/k rows only
    if (o < 2 * ND) {
      float s4 = acc[j].x + acc[j].y + acc[j].z + acc[j].w;
      s4 += __shfl_xor(s4, 1);
      s4 += __shfl_xor(s4, 2);
      if ((t & 3) == 0) {
        int g = n0 / 16 + (t >> 2);
        float* dst = (o < ND) ? ql : kl;
        dst[((size_t)b * NM + g) * ND + (o & 7)] = s4 * (1.0f / 16.0f);
      }
    }
  }
}

// ---------------- merged softmaxes: k1 bf16 / k2 f32 / k3 f32 (R6-validated) ----------------
__global__ __launch_bounds__(256) void scores_all_kernel(
    const float* __restrict__ q, const float* __restrict__ ql,
    const float* __restrict__ kw, const float* __restrict__ kl,
    ushort* __restrict__ k1bf, float* __restrict__ k2w,
    float* __restrict__ k3w) {
  __shared__ float skl[NM][9];
  __shared__ float wred[4], wsum[4];
  int blk = blockIdx.x;
  int t = threadIdx.x;
  if (blk < 2048 + 128) {
    const float* Q; int R, b, xrow;
    bool isbf;
    if (blk < 2048) { b = blk >> 10; xrow = blk & 1023; Q = q;  R = NN; isbf = true; }
    else { int r = blk - 2048; b = r >> 6; xrow = r & 63; Q = ql; R = NM; isbf = false; }
    for (int i = t; i < NM * ND; i += 256) skl[i >> 3][i & 7] = kl[(size_t)b * NM * ND + i];
    __syncthreads();
    int wave = t >> 6, lane = t & 63;
    int r = xrow * 4 + wave;
    const float* qrow = Q + ((size_t)b * R + r) * ND;
    float qr[ND];
    #pragma unroll
    for (int dd = 0; dd < ND; ++dd) qr[dd] = qrow[dd];
    float sc[4];
    float lmax = -1e30f;
    #pragma unroll
    for (int s = 0; s < 4; ++s) {
      int j = lane + 64 * s;
      float a = 0.f;
      #pragma unroll
      for (int dd = 0; dd < ND; ++dd) a += qr[dd] * skl[j][dd];
      sc[s] = a * SCALE;
      lmax = fmaxf(lmax, sc[s]);
    }
    for (int off = 32; off; off >>= 1) lmax = fmaxf(lmax, __shfl_xor(lmax, off));
    float lsum = 0.f;
    #pragma unroll
    for (int s = 0; s < 4; ++s) { sc[s] = expf(sc[s] - lmax); lsum += sc[s]; }
    for (int off = 32; off; off >>= 1) lsum += __shfl_xor(lsum, off);
    float inv = 1.0f / lsum;
    if (isbf) {
      #pragma unroll
      for (int s = 0; s < 4; ++s)
        k1bf[((size_t)b * R + r) * NM + lane + 64 * s] = f2bf(sc[s] * inv);
    } else {
      #pragma unroll
      for (int s = 0; s < 4; ++s)
        k2w[((size_t)b * R + r) * NM + lane + 64 * s] = sc[s] * inv;
    }
  } else {
    int r = blk - 2176;
    int b = r >> 8, i = r & 255;
    float qr[ND];
    #pragma unroll
    for (int dd = 0; dd < ND; ++dd) qr[dd] = ql[((size_t)b * NM + i) * ND + dd];
    float sc[16];
    float lmax = -1e30f;
    #pragma unroll
    for (int s = 0; s < 16; ++s) {
      int n = t + 256 * s;
      const float* kp = kw + ((size_t)b * NN + n) * ND;
      float a = 0.f;
      #pragma unroll
      for (int dd = 0; dd < ND; ++dd) a += qr[dd] * kp[dd];
      sc[s] = a * SCALE;
      lmax = fmaxf(lmax, sc[s]);
    }
    for (int off = 32; off; off >>= 1) lmax = fmaxf(lmax, __shfl_xor(lmax, off));
    if ((t & 63) == 0) wred[t >> 6] = lmax;
    __syncthreads();
    lmax = fmaxf(fmaxf(wred[0], wred[1]), fmaxf(wred[2], wred[3]));
    float lsum = 0.f;
    #pragma unroll
    for (int s = 0; s < 16; ++s) { sc[s] = expf(sc[s] - lmax); lsum += sc[s]; }
    for (int off = 32; off; off >>= 1) lsum += __shfl_xor(lsum, off);
    if ((t & 63) == 0) wsum[t >> 6] = lsum;
    __syncthreads();
    lsum = wsum[0] + wsum[1] + wsum[2] + wsum[3];
    float inv = 1.0f / lsum;
    #pragma unroll
    for (int s = 0; s < 16; ++s) k3w[((size_t)b * NM + i) * NN + t + 256 * s] = sc[s] * inv;
  }
}

// ---------------- denom: max column-sum per batch (R5) ----------------
__global__ __launch_bounds__(256) void denom_kernel(const float* __restrict__ k2,
                                                    float* __restrict__ denw) {
  __shared__ float red[256];
  int b = blockIdx.x;
  int t = threadIdx.x;
  float cs = 0.f;
  for (int i = 0; i < NM; ++i) cs += k2[((size_t)b * NM + i) * NM + t];
  red[t] = cs;
  __syncthreads();
  for (int off = 128; off; off >>= 1) {
    if (t < off) red[t] = fmaxf(red[t], red[t + off]);
    __syncthreads();
  }
  if (t == 0) denw[b] = red[0];
}

// ---------------- 32x32-tile batched GEMM (R5 core, 303-verified) ----------------
__global__ __launch_bounds__(256) void gemm_rk32(
    const float* __restrict__ A, const float* __restrict__ Bm,
    float* __restrict__ out, float s_a, float s_ab) {
  int b = blockIdx.z;
  int bi = blockIdx.y * 32, bj = blockIdx.x * 32;
  __shared__ float As[32][260];
  __shared__ float Bs[256][36];
  int t = threadIdx.x;
  const float* Ab = A + (size_t)b * NM * NM;
  const float* Bb = Bm + (size_t)b * NM * NM;
  #pragma unroll
  for (int q = 0; q < 8; ++q) {
    int s = q * 256 + t;
    int ar = s >> 6, ac = (s & 63) * 4;
    *(float4*)&As[ar][ac] = *(const float4*)(Ab + (size_t)(bi + ar) * NM + ac);
    int br = s >> 3, bc = (s & 7) * 4;
    *(float4*)&Bs[br][bc] = *(const float4*)(Bb + (size_t)br * NM + bj + bc);
  }
  __syncthreads();
  int tx = t & 15, ty = t >> 4;
  float acc[2][2] = {};
  #pragma unroll 8
  for (int kk = 0; kk < NM; ++kk) {
    float a0 = As[ty * 2][kk], a1 = As[ty * 2 + 1][kk];
    float b0 = Bs[kk][tx * 2], b1 = Bs[kk][tx * 2 + 1];
    acc[0][0] += a0 * b0; acc[0][1] += a0 * b1;
    acc[1][0] += a1 * b0; acc[1][1] += a1 * b1;
  }
  #pragma unroll
  for (int i = 0; i < 2; ++i)
    #pragma unroll
    for (int j = 0; j < 2; ++j) {
      size_t o = ((size_t)b * NM + bi + ty * 2 + i) * NM + bj + tx * 2 + j;
      float r = s_ab * acc[i][j];
      if (s_a != 0.0f) r += s_a * A[o];
      out[o] = r;
    }
}

// ---- NS launch 1 of iter 0: Z = k2 @ V0, V0[i][j] = k2[j][i]*dval (virtual, fold of vinit)
__global__ __launch_bounds__(256) void gemm_rk32_zv0(
    const float* __restrict__ k2, const float* __restrict__ denw,
    float* __restrict__ out) {
  int b = blockIdx.z;
  int bi = blockIdx.y * 32, bj = blockIdx.x * 32;
  __shared__ float As[32][260];
  __shared__ float Bs[256][36];
  int t = threadIdx.x;
  const float* Ab = k2 + (size_t)b * NM * NM;
  float dval = 1.0f / fmaxf(denw[0], denw[1]);
  #pragma unroll
  for (int q = 0; q < 8; ++q) {
    int s = q * 256 + t;
    int ar = s >> 6, ac = (s & 63) * 4;
    *(float4*)&As[ar][ac] = *(const float4*)(Ab + (size_t)(bi + ar) * NM + ac);
    // B = V0: Bs[k][c] = k2[bj+c][k]*dval  (read k2 rows bj..bj+31, k-contig float4)
    int br = s >> 6, bk4 = (s & 63) * 4;   // br: row offset 0..31, bk4: k
    float4 vv = *(const float4*)(Ab + (size_t)(bj + br) * NM + bk4);
    Bs[bk4 + 0][br] = vv.x * dval; Bs[bk4 + 1][br] = vv.y * dval;
    Bs[bk4 + 2][br] = vv.z * dval; Bs[bk4 + 3][br] = vv.w * dval;
  }
  __syncthreads();
  int tx = t & 15, ty = t >> 4;
  float acc[2][2] = {};
  #pragma unroll 8
  for (int kk = 0; kk < NM; ++kk) {
    float a0 = As[ty * 2][kk], a1 = As[ty * 2 + 1][kk];
    float b0 = Bs[kk][tx * 2], b1 = Bs[kk][tx * 2 + 1];
    acc[0][0] += a0 * b0; acc[0][1] += a0 * b1;
    acc[1][0] += a1 * b0; acc[1][1] += a1 * b1;
  }
  #pragma unroll
  for (int i = 0; i < 2; ++i)
    #pragma unroll
    for (int j = 0; j < 2; ++j)
      out[((size_t)b * NM + bi + ty * 2 + i) * NM + bj + tx * 2 + j] = acc[i][j];
}

// ---- NS launch 4 of iter 0: V' = 3.25*V0 - 0.25*V0@T2, V0 virtual (A-side)
__global__ __launch_bounds__(256) void gemm_rk32_av0(
    const float* __restrict__ k2, const float* __restrict__ T2,
    const float* __restrict__ denw, float* __restrict__ out) {
  int b = blockIdx.z;
  int bi = blockIdx.y * 32, bj = blockIdx.x * 32;
  __shared__ float As[32][260];
  __shared__ float Bs[256][36];
  int t = threadIdx.x;
  const float* k2b = k2 + (size_t)b * NM * NM;
  const float* Bb = T2 + (size_t)b * NM * NM;
  float dval = 1.0f / fmaxf(denw[0], denw[1]);
  #pragma unroll
  for (int q = 0; q < 8; ++q) {
    int s = q * 256 + t;
    // A = V0: As[r][k] = k2[k][bi+r]*dval  (read k2 row k, cols bi..bi+31)
    int kr = s >> 3, c4 = (s & 7) * 4;
    float4 vv = *(const float4*)(k2b + (size_t)kr * NM + bi + c4);
    As[c4 + 0][kr] = vv.x * dval; As[c4 + 1][kr] = vv.y * dval;
    As[c4 + 2][kr] = vv.z * dval; As[c4 + 3][kr] = vv.w * dval;
    int br = s >> 3, bc = (s & 7) * 4;
    *(float4*)&Bs[br][bc] = *(const float4*)(Bb + (size_t)br * NM + bj + bc);
  }
  __syncthreads();
  int tx = t & 15, ty = t >> 4;
  float acc[2][2] = {};
  #pragma unroll 8
  for (int kk = 0; kk < NM; ++kk) {
    float a0 = As[ty * 2][kk], a1 = As[ty * 2 + 1][kk];
    float b0 = Bs[kk][tx * 2], b1 = Bs[kk][tx * 2 + 1];
    acc[0][0] += a0 * b0; acc[0][1] += a0 * b1;
    acc[1][0] += a1 * b0; acc[1][1] += a1 * b1;
  }
  #pragma unroll
  for (int i = 0; i < 2; ++i)
    #pragma unroll
    for (int j = 0; j < 2; ++j) {
      int R = bi + ty * 2 + i, C = bj + tx * 2 + j;
      float a0v = k2b[(size_t)C * NM + R] * dval;   // V0[R][C]
      out[((size_t)b * NM + R) * NM + C] = 3.25f * a0v - 0.25f * acc[i][j];
    }
}

// ---- NS last launch: V' = 3.25*V - 0.25*V@T2, written bf16 TRANSPOSED (fold of cvt_vinv)
__global__ __launch_bounds__(256) void gemm_rk32_wt(
    const float* __restrict__ A, const float* __restrict__ Bm,
    ushort* __restrict__ Vt) {
  int b = blockIdx.z;
  int bi = blockIdx.y * 32, bj = blockIdx.x * 32;
  __shared__ float As[32][260];
  __shared__ float Bs[256][36];
  int t = threadIdx.x;
  const float* Ab = A + (size_t)b * NM * NM;
  const float* Bb = Bm + (size_t)b * NM * NM;
  #pragma unroll
  for (int q = 0; q < 8; ++q) {
    int s = q * 256 + t;
    int ar = s >> 6, ac = (s & 63) * 4;
    *(float4*)&As[ar][ac] = *(const float4*)(Ab + (size_t)(bi + ar) * NM + ac);
    int br = s >> 3, bc = (s & 7) * 4;
    *(float4*)&Bs[br][bc] = *(const float4*)(Bb + (size_t)br * NM + bj + bc);
  }
  __syncthreads();
  int tx = t & 15, ty = t >> 4;
  float acc[2][2] = {};
  #pragma unroll 8
  for (int kk = 0; kk < NM; ++kk) {
    float a0 = As[ty * 2][kk], a1 = As[ty * 2 + 1][kk];
    float b0 = Bs[kk][tx * 2], b1 = Bs[kk][tx * 2 + 1];
    acc[0][0] += a0 * b0; acc[0][1] += a0 * b1;
    acc[1][0] += a1 * b0; acc[1][1] += a1 * b1;
  }
  __syncthreads();
  // stash V' tile (row-major) in As head, then coalesced transposed bf16 write
  float (*tile)[33] = (float (*)[33])&As[0][0];
  #pragma unroll
  for (int i = 0; i < 2; ++i)
    #pragma unroll
    for (int j = 0; j < 2; ++j) {
      int R = ty * 2 + i, C = tx * 2 + j;
      float a0v = Ab[(size_t)(bi + R) * NM + bj + C];
      tile[R][C] = 3.25f * a0v - 0.25f * acc[i][j];
    }
  __syncthreads();
  int rr = t >> 3, m4 = (t & 7) * 4;   // rr: n_local, m4: m_local
  ushort4 u;
  u.x = f2bf(tile[m4 + 0][rr]); u.y = f2bf(tile[m4 + 1][rr]);
  u.z = f2bf(tile[m4 + 2][rr]); u.w = f2bf(tile[m4 + 3][rr]);
  *(ushort4*)(Vt + ((size_t)b * NM + bj + rr) * NM + bi + m4) = u;
}

// ---------------- k3: [B][NM][NN] fp32 -> k3t: [B][NN][NM] bf16 (R5) ----------------
__global__ __launch_bounds__(256) void cvt_t_kernel(const float* __restrict__ k3,
                                                    ushort* __restrict__ k3t) {
  int b = blockIdx.z;
  int n0 = blockIdx.x * 32, m0 = blockIdx.y * 32;
  __shared__ float tile[32][33];
  int t = threadIdx.x;
  int r = t >> 3, c4 = (t & 7) * 4;
  float4 v = *(const float4*)(k3 + ((size_t)b * NM + m0 + r) * NN + n0 + c4);
  tile[c4][r] = v.x; tile[c4 + 1][r] = v.y; tile[c4 + 2][r] = v.z; tile[c4 + 3][r] = v.w;
  __syncthreads();
  ushort4 u;
  u.x = f2bf(tile[r][c4]);     u.y = f2bf(tile[r][c4 + 1]);
  u.z = f2bf(tile[r][c4 + 2]); u.w = f2bf(tile[r][c4 + 3]);
  *(ushort4*)(k3t + ((size_t)b * NN + n0 + r) * NM + m0 + c4) = u;
}

// ---------------- A = k1 @ Vinv via bf16 MFMA (R5) ----------------
__global__ __launch_bounds__(256) void gemm_a_mfma(
    const ushort* __restrict__ k1bf, const ushort* __restrict__ Vt,
    ushort* __restrict__ Abf) {
  int b = blockIdx.z;
  int bi = blockIdx.y * 128, bj = blockIdx.x * 128;
  __shared__ ushort As[128 * 64];
  __shared__ ushort Bs[128 * 64];
  int t = threadIdx.x;
  int wave = t >> 6, lane = t & 63;
  int wr = wave >> 1, wc = wave & 1;
  const ushort* Ab = k1bf + (size_t)b * NN * NM;
  const ushort* Bb = Vt + (size_t)b * NM * NM;
  f32x4 acc[4][4] = {};
  for (int k0 = 0; k0 < NM; k0 += 64) {
    #pragma unroll
    for (int q = 0; q < 4; ++q) {
      int s = q * 256 + t;
      int r = s >> 3, c = s & 7;
      int cs = (c ^ (r & 7)) << 3;
      gl_lds16(Ab + (size_t)(bi + r) * NM + k0 + cs, As + (size_t)s * 8);
      gl_lds16(Bb + (size_t)(bj + r) * NM + k0 + cs, Bs + (size_t)s * 8);
    }
    __syncthreads();
    #pragma unroll
    for (int kk = 0; kk < 2; ++kk) {
      int koff = kk * 64 + (lane >> 4) * 16;
      bf16x8 af[4], bfv[4];
      #pragma unroll
      for (int mi = 0; mi < 4; ++mi) {
        int row = wr * 64 + mi * 16 + (lane & 15);
        af[mi] = *(const bf16x8*)((const char*)As + row * 128 + (koff ^ ((row & 7) << 4)));
      }
      #pragma unroll
      for (int nj = 0; nj < 4; ++nj) {
        int row = wc * 64 + nj * 16 + (lane & 15);
        bfv[nj] = *(const bf16x8*)((const char*)Bs + row * 128 + (koff ^ ((row & 7) << 4)));
      }
      #pragma unroll
      for (int mi = 0; mi < 4; ++mi)
        #pragma unroll
        for (int nj = 0; nj < 4; ++nj)
          acc[mi][nj] = __builtin_amdgcn_mfma_f32_16x16x32_bf16(af[mi], bfv[nj], acc[mi][nj], 0, 0, 0);
    }
    __syncthreads();
  }
  int col = lane & 15, rbase = (lane >> 4) * 4;
  #pragma unroll
  for (int mi = 0; mi < 4; ++mi)
    #pragma unroll
    for (int nj = 0; nj < 4; ++nj)
      #pragma unroll
      for (int r = 0; r < 4; ++r)
        Abf[((size_t)b * NN + bi + wr * 64 + mi * 16 + rbase + r) * NM
            + bj + wc * 64 + nj * 16 + col] = f2bf(acc[mi][nj][r]);
}

// ---------------- attn = A @ k3 via bf16 MFMA, 128x128 tile, XCD swizzle, nt stores ----------------
__global__ __launch_bounds__(256) void gemm_attn_mfma(
    const ushort* __restrict__ Abf, const ushort* __restrict__ K3T,
    float* __restrict__ attn) {
  int lin = blockIdx.z * 1024 + blockIdx.y * 32 + blockIdx.x;
  int swz = (lin & 7) * 256 + (lin >> 3);
  int b = swz >> 10;
  int rem = swz & 1023;
  int bi = (rem >> 5) * 128, bj = (rem & 31) * 128;
  __shared__ ushort As[128 * 64];
  __shared__ ushort Bs[128 * 64];
  int t = threadIdx.x;
  int wave = t >> 6, lane = t & 63;
  int wr = wave >> 1, wc = wave & 1;
  const ushort* Ab = Abf + (size_t)b * NN * NM;
  const ushort* Bb = K3T + (size_t)b * NN * NM;
  f32x4 acc[4][4] = {};
  for (int k0 = 0; k0 < NM; k0 += 64) {
    #pragma unroll
    for (int q = 0; q < 4; ++q) {
      int s = q * 256 + t;
      int r = s >> 3, c = s & 7;
      int cs = (c ^ (r & 7)) << 3;
      gl_lds16(Ab + (size_t)(bi + r) * NM + k0 + cs, As + (size_t)s * 8);
      gl_lds16(Bb + (size_t)(bj + r) * NM + k0 + cs, Bs + (size_t)s * 8);
    }
    __syncthreads();
    #pragma unroll
    for (int kk = 0; kk < 2; ++kk) {
      int koff = kk * 64 + (lane >> 4) * 16;
      bf16x8 af[4], bfv[4];
      #pragma unroll
      for (int mi = 0; mi < 4; ++mi) {
        int row = wr * 64 + mi * 16 + (lane & 15);
        af[mi] = *(const bf16x8*)((const char*)As + row * 128 + (koff ^ ((row & 7) << 4)));
      }
      #pragma unroll
      for (int nj = 0; nj < 4; ++nj) {
        int row = wc * 64 + nj * 16 + (lane & 15);
        bfv[nj] = *(const bf16x8*)((const char*)Bs + row * 128 + (koff ^ ((row & 7) << 4)));
      }
      #pragma unroll
      for (int mi = 0; mi < 4; ++mi)
        #pragma unroll
        for (int nj = 0; nj < 4; ++nj)
          acc[mi][nj] = __builtin_amdgcn_mfma_f32_16x16x32_bf16(af[mi], bfv[nj], acc[mi][nj], 0, 0, 0);
    }
    __syncthreads();
  }
  int col = lane & 15, rbase = (lane >> 4) * 4;
  #pragma unroll
  for (int mi = 0; mi < 4; ++mi)
    #pragma unroll
    for (int nj = 0; nj < 4; ++nj)
      #pragma unroll
      for (int r = 0; r < 4; ++r)
        __builtin_nontemporal_store(
            acc[mi][nj][r],
            &attn[((size_t)b * NN + bi + wr * 64 + mi * 16 + rbase + r) * NN
                  + bj + wc * 64 + nj * 16 + col]);
}

// ---------------- split-K kv (atomicAdd into zeroed buffer, R5) ----------------
__global__ __launch_bounds__(256) void kv_kernel(
    const float* __restrict__ K3, const float* __restrict__ Vv,
    float* __restrict__ kvout) {
  int b = blockIdx.z, bp = blockIdx.x * 64;
  int j0base = blockIdx.y * (NN / 32);
  __shared__ float Ks[64][33], Vs[64][33];
  int t = threadIdx.x, tx = t & 15, ty = t >> 4;
  int lrow = t >> 2, ljc = (t & 3) * 8;
  float acc[4][4] = {};
  for (int j0 = j0base; j0 < j0base + NN / 32; j0 += 32) {
    float4 a0 = *(const float4*)(K3 + ((size_t)b * NM + bp + lrow) * NN + j0 + ljc);
    float4 a1 = *(const float4*)(K3 + ((size_t)b * NM + bp + lrow) * NN + j0 + ljc + 4);
    float4 v0 = *(const float4*)(Vv + ((size_t)b * NC + lrow) * NN + j0 + ljc);
    float4 v1 = *(const float4*)(Vv + ((size_t)b * NC + lrow) * NN + j0 + ljc + 4);
    Ks[lrow][ljc + 0] = a0.x; Ks[lrow][ljc + 1] = a0.y; Ks[lrow][ljc + 2] = a0.z; Ks[lrow][ljc + 3] = a0.w;
    Ks[lrow][ljc + 4] = a1.x; Ks[lrow][ljc + 5] = a1.y; Ks[lrow][ljc + 6] = a1.z; Ks[lrow][ljc + 7] = a1.w;
    Vs[lrow][ljc + 0] = v0.x; Vs[lrow][ljc + 1] = v0.y; Vs[lrow][ljc + 2] = v0.z; Vs[lrow][ljc + 3] = v0.w;
    Vs[lrow][ljc + 4] = v1.x; Vs[lrow][ljc + 5] = v1.y; Vs[lrow][ljc + 6] = v1.z; Vs[lrow][ljc + 7] = v1.w;
    __syncthreads();
    #pragma unroll
    for (int kk = 0; kk < 32; ++kk) {
      float av_[4], bv_[4];
      #pragma unroll
      for (int i = 0; i < 4; ++i) av_[i] = Ks[(ty << 2) + i][kk];
      #pragma unroll
      for (int j = 0; j < 4; ++j) bv_[j] = Vs[(tx << 2) + j][kk];
      #pragma unroll
      for (int i = 0; i < 4; ++i)
        #pragma unroll
        for (int j = 0; j < 4; ++j) acc[i][j] += av_[i] * bv_[j];
    }
    __syncthreads();
  }
  #pragma unroll
  for (int i = 0; i < 4; ++i)
    #pragma unroll
    for (int j = 0; j < 4; ++j)
      atomicAdd(&kvout[((size_t)b * NM + bp + (ty << 2) + i) * NC + (tx << 2) + j], acc[i][j]);
}

// ---------------- out = gamma*(A@kv) + x  (A in bf16, nt stores) ----------------
__global__ __launch_bounds__(256) void out_kernel(
    const ushort* __restrict__ Abf, const float* __restrict__ kvm,
    const float* __restrict__ x, const float* __restrict__ gamma,
    float* __restrict__ outp) {
  __shared__ float As[32 * 256];
  int blk = blockIdx.x;
  int b = blk / (NN / 32), n0 = (blk % (NN / 32)) * 32;
  int t = threadIdx.x;
  for (int it = 0; it < 32; ++it)
    As[it * 256 + (t ^ (it & 31))] = bf2f(Abf[((size_t)b * NN + n0 + it) * NM + t]);
  __syncthreads();
  int tn = t & 31, cg0 = (t >> 5) * 8;
  float g = gamma[0];
  float acc[8] = {};
  for (int p = 0; p < NM; ++p) {
    float a = As[tn * 256 + (p ^ (tn & 31))];
    float4 kv0 = *(const float4*)(kvm + ((size_t)b * NM + p) * NC + cg0);
    float4 kv1 = *(const float4*)(kvm + ((size_t)b * NM + p) * NC + cg0 + 4);
    acc[0] += a * kv0.x; acc[1] += a * kv0.y; acc[2] += a * kv0.z; acc[3] += a * kv0.w;
    acc[4] += a * kv1.x; acc[5] += a * kv1.y; acc[6] += a * kv1.z; acc[7] += a * kv1.w;
  }
  #pragma unroll
  for (int qd = 0; qd < 8; ++qd) {
    int c = cg0 + qd;
    size_t idx = ((size_t)b * NC + c) * NN + n0 + tn;
    __builtin_nontemporal_store(g * acc[qd] + x[idx], &outp[idx]);
  }
}

extern "C" void kernel_launch(void* const* d_in, const int* in_sizes, int n_in,
                              void* d_out, int out_size, void* d_ws, size_t ws_size,
                              hipStream_t stream) {
  const float* x     = (const float*)d_in[0];
  const float* wq    = (const float*)d_in[1];
  const float* bq    = (const float*)d_in[2];
  const float* wk    = (const float*)d_in[3];
  const float* bk    = (const float*)d_in[4];
  const float* wv    = (const float*)d_in[5];
  const float* bv    = (const float*)d_in[6];
  const float* gamma = (const float*)d_in[7];
  float* outp = (float*)d_out;                       // [B][C][N]
  float* attn = outp + (size_t)NB * NC * NN;         // [B][N][N]
  float* w = (float*)d_ws;

  float* qw   = w;                 // [B][N][D]    65536
  float* kw   = qw + 65536;        // [B][N][D]    65536
  float* vw   = kw + 65536;        // [B][C][N]    524288
  float* qlw  = vw + 524288;       // [B][M][D]    4096
  float* klw  = qlw + 4096;        // [B][M][D]    4096
  float* k1w  = klw + 4096;        // 8 MB region: k1bf (4MB) + k3T (4MB)
  float* k2w  = k1w + 2097152;     // [B][M][M]    131072
  float* k3w  = k2w + 131072;      // [B][M][N]    2097152
  float* Abuf = k3w + 2097152;     // 4 MB region: Abf bf16
  float* Va   = Abuf + 1048576;    // [B][M][M]    131072
  float* Vb   = Va + 131072;       // [B][M][M]    131072
  float* Zb   = Vb + 131072;       // [B][M][M]    131072
  float* T1   = Zb + 131072;       // [B][M][M]    131072
  float* T2   = T1 + 131072;       // [B][M][M]    131072
  float* Vtw  = T2 + 131072;       // Vinvt bf16   65536 floats
  float* kvw  = Vtw + 65536;       // [B][M][C]    32768
  float* denw = kvw + 32768;       // [2]
  ushort* k1bf  = (ushort*)k1w;                 // [B][N][M] bf16
  ushort* k3T   = (ushort*)k1w + 2097152;       // [B][N][M] bf16 (k3^T)
  ushort* Abf   = (ushort*)Abuf;                // [B][N][M] bf16
  ushort* Vinvt = (ushort*)Vtw;                 // [B][M][M] bf16 (Vinv^T)

  hipMemsetAsync(kvw, 0, (size_t)NB * NM * NC * sizeof(float), stream);
  qkv4_kernel<<<dim3(20, NN / 1024, NB), dim3(256), 0, stream>>>(
      x, wq, bq, wk, bk, wv, bv, qw, kw, vw, qlw, klw);
  scores_all_kernel<<<dim3(2048 + 128 + 512), dim3(256), 0, stream>>>(
      qw, qlw, kw, klw, k1bf, k2w, k3w);
  denom_kernel<<<dim3(NB), dim3(256), 0, stream>>>(k2w, denw);

  // Newton-Schulz: R5's 24-launch chain; V0 virtualized in iter-0 (fold of vinit),
  // last launch writes Vinv^T bf16 directly (fold of cvt_vinv).
  // iter 0:
  gemm_rk32_zv0<<<dim3(8, 8, NB), dim3(256), 0, stream>>>(k2w, denw, Zb);
  gemm_rk32<<<dim3(8, 8, NB), dim3(256), 0, stream>>>(Zb, Zb, T1, 7.f, -1.f);
  gemm_rk32<<<dim3(8, 8, NB), dim3(256), 0, stream>>>(Zb, T1, T2, 15.f, -1.f);
  gemm_rk32_av0<<<dim3(8, 8, NB), dim3(256), 0, stream>>>(k2w, T2, denw, Va);
  // iters 1..4:
  float* Vc = Va; float* Vn = Vb;
  for (int it = 1; it < 5; ++it) {
    gemm_rk32<<<dim3(8, 8, NB), dim3(256), 0, stream>>>(k2w, Vc, Zb, 0.f, 1.f);
    gemm_rk32<<<dim3(8, 8, NB), dim3(256), 0, stream>>>(Zb, Zb, T1, 7.f, -1.f);
    gemm_rk32<<<dim3(8, 8, NB), dim3(256), 0, stream>>>(Zb, T1, T2, 15.f, -1.f);
    gemm_rk32<<<dim3(8, 8, NB), dim3(256), 0, stream>>>(Vc, T2, Vn, 3.25f, -0.25f);
    float* tmp = Vc; Vc = Vn; Vn = tmp;
  }
  // iter 5 (final): V' -> Vinvt bf16 transposed
  gemm_rk32<<<dim3(8, 8, NB), dim3(256), 0, stream>>>(k2w, Vc, Zb, 0.f, 1.f);
  gemm_rk32<<<dim3(8, 8, NB), dim3(256), 0, stream>>>(Zb, Zb, T1, 7.f, -1.f);
  gemm_rk32<<<dim3(8, 8, NB), dim3(256), 0, stream>>>(Zb, T1, T2, 15.f, -1.f);
  gemm_rk32_wt<<<dim3(8, 8, NB), dim3(256), 0, stream>>>(Vc, T2, Vinvt);

  cvt_t_kernel<<<dim3(NN / 32, NM / 32, NB), dim3(256), 0, stream>>>(k3w, k3T);
  gemm_a_mfma<<<dim3(NM / 128, NN / 128, NB), dim3(256), 0, stream>>>(k1bf, Vinvt, Abf);
  gemm_attn_mfma<<<dim3(NN / 128, NN / 128, NB), dim3(256), 0, stream>>>(Abf, k3T, attn);
  kv_kernel<<<dim3(NM / 64, 32, NB), dim3(256), 0, stream>>>(k3w, vw, kvw);
  out_kernel<<<dim3(NB * NN / 32), dim3(256), 0, stream>>>(Abf, kvw, x, gamma, outp);
}

// Round 14
// 298.761 us; speedup vs baseline: 1.0678x; 1.0012x over previous
//
#include <hip/hip_runtime.h>
#include <hip/hip_bf16.h>
#include <math.h>

#define NB 2        // batch
#define NC 64       // channels
#define ND 8        // head dim (C/8)
#define NN 4096     // tokens (T*W*H)
#define NM 256      // landmarks
#define NL 16       // N/M
#define SCALE 0.35355339059327373f  // 1/sqrt(8)

typedef __attribute__((ext_vector_type(4))) float f32x4;
typedef __attribute__((ext_vector_type(8))) short bf16x8;

__device__ inline ushort f2bf(float f) {
  __hip_bfloat16 h = __float2bfloat16(f);
  return *reinterpret_cast<ushort*>(&h);
}
__device__ inline float bf2f(ushort u) {
  return __uint_as_float(((unsigned int)u) << 16);
}

// async global->LDS, 16B per lane; LDS dest must be wave-linear (base + lane*16)
__device__ inline void gl_lds16(const void* g, void* l) {
  __builtin_amdgcn_global_load_lds(
      (const __attribute__((address_space(1))) unsigned int*)g,
      (__attribute__((address_space(3))) unsigned int*)l, 16, 0, 0);
}

// ---------------- qkv projection, 4 output rows per block + fused landmarks (R12) ----------------
__global__ __launch_bounds__(256) void qkv4_kernel(
    const float* __restrict__ x,
    const float* __restrict__ wq, const float* __restrict__ bq,
    const float* __restrict__ wk, const float* __restrict__ bk,
    const float* __restrict__ wv, const float* __restrict__ bv,
    float* __restrict__ q, float* __restrict__ k, float* __restrict__ v,
    float* __restrict__ ql, float* __restrict__ kl) {
  __shared__ float ws[4][NC];
  int o0 = blockIdx.x * 4;
  int b = blockIdx.z;
  int n0 = blockIdx.y * 1024;
  int t = threadIdx.x;
  {
    int j = t >> 6, c = t & 63;
    int o = o0 + j;
    const float* wrow;
    if (o < ND)          wrow = wq + (size_t)o * NC;
    else if (o < 2 * ND) wrow = wk + (size_t)(o - ND) * NC;
    else                 wrow = wv + (size_t)(o - 2 * ND) * NC;
    ws[j][c] = wrow[c];
  }
  __syncthreads();
  int n = n0 + t * 4;
  float4 acc[4];
  #pragma unroll
  for (int j = 0; j < 4; ++j) {
    int o = o0 + j;
    float bias = (o < ND) ? bq[o] : (o < 2 * ND ? bk[o - ND] : bv[o - 2 * ND]);
    acc[j].x = bias; acc[j].y = bias; acc[j].z = bias; acc[j].w = bias;
  }
  for (int c = 0; c < NC; ++c) {
    float4 xv = *(const float4*)(x + ((size_t)b * NC + c) * NN + n);
    #pragma unroll
    for (int j = 0; j < 4; ++j) {
      float wc = ws[j][c];
      acc[j].x += wc * xv.x; acc[j].y += wc * xv.y;
      acc[j].z += wc * xv.z; acc[j].w += wc * xv.w;
    }
  }
  #pragma unroll
  for (int j = 0; j < 4; ++j) {
    int o = o0 + j;
    if (o < ND) {
      float* qp = q + ((size_t)b * NN + n) * ND + o;
      qp[0] = acc[j].x; qp[8] = acc[j].y; qp[16] = acc[j].z; qp[24] = acc[j].w;
    } else if (o < 2 * ND) {
      float* kp = k + ((size_t)b * NN + n) * ND + (o - ND);
      kp[0] = acc[j].x; kp[8] = acc[j].y; kp[16] = acc[j].z; kp[24] = acc[j].w;
    } else {
      *(float4*)(v + ((size_t)b * NC + (o - 2 * ND)) * NN + n) = acc[j];
    }
    if (o < 2 * ND) {
      float s4 = acc[j].x + acc[j].y + acc[j].z + acc[j].w;
      s4 += __shfl_xor(s4, 1);
      s4 += __shfl_xor(s4, 2);
      if ((t & 3) == 0) {
        int g = n0 / 16 + (t >> 2);
        float* dst = (o < ND) ? ql : kl;
        dst[((size_t)b * NM + g) * ND + (o & 7)] = s4 * (1.0f / 16.0f);
      }
    }
  }
}

// ---------------- merged softmaxes: k1 bf16 / k2 f32 / k3 bf16 row-major ----------------
__global__ __launch_bounds__(256) void scores_all_kernel(
    const float* __restrict__ q, const float* __restrict__ ql,
    const float* __restrict__ kw, const float* __restrict__ kl,
    ushort* __restrict__ k1bf, float* __restrict__ k2w,
    ushort* __restrict__ k3bf) {
  __shared__ float skl[NM][9];
  __shared__ float wred[4], wsum[4];
  int blk = blockIdx.x;
  int t = threadIdx.x;
  if (blk < 2048 + 128) {
    const float* Q; int R, b, xrow;
    bool isbf;
    if (blk < 2048) { b = blk >> 10; xrow = blk & 1023; Q = q;  R = NN; isbf = true; }
    else { int r = blk - 2048; b = r >> 6; xrow = r & 63; Q = ql; R = NM; isbf = false; }
    for (int i = t; i < NM * ND; i += 256) skl[i >> 3][i & 7] = kl[(size_t)b * NM * ND + i];
    __syncthreads();
    int wave = t >> 6, lane = t & 63;
    int r = xrow * 4 + wave;
    const float* qrow = Q + ((size_t)b * R + r) * ND;
    float qr[ND];
    #pragma unroll
    for (int dd = 0; dd < ND; ++dd) qr[dd] = qrow[dd];
    float sc[4];
    float lmax = -1e30f;
    #pragma unroll
    for (int s = 0; s < 4; ++s) {
      int j = lane + 64 * s;
      float a = 0.f;
      #pragma unroll
      for (int dd = 0; dd < ND; ++dd) a += qr[dd] * skl[j][dd];
      sc[s] = a * SCALE;
      lmax = fmaxf(lmax, sc[s]);
    }
    for (int off = 32; off; off >>= 1) lmax = fmaxf(lmax, __shfl_xor(lmax, off));
    float lsum = 0.f;
    #pragma unroll
    for (int s = 0; s < 4; ++s) { sc[s] = expf(sc[s] - lmax); lsum += sc[s]; }
    for (int off = 32; off; off >>= 1) lsum += __shfl_xor(lsum, off);
    float inv = 1.0f / lsum;
    if (isbf) {
      #pragma unroll
      for (int s = 0; s < 4; ++s)
        k1bf[((size_t)b * R + r) * NM + lane + 64 * s] = f2bf(sc[s] * inv);
    } else {
      #pragma unroll
      for (int s = 0; s < 4; ++s)
        k2w[((size_t)b * R + r) * NM + lane + 64 * s] = sc[s] * inv;
    }
  } else {
    // k3 softmax -> bf16 row-major [M][N]
    int r = blk - 2176;
    int b = r >> 8, i = r & 255;
    float qr[ND];
    #pragma unroll
    for (int dd = 0; dd < ND; ++dd) qr[dd] = ql[((size_t)b * NM + i) * ND + dd];
    float sc[16];
    float lmax = -1e30f;
    #pragma unroll
    for (int s = 0; s < 16; ++s) {
      int n = t + 256 * s;
      const float* kp = kw + ((size_t)b * NN + n) * ND;
      float a = 0.f;
      #pragma unroll
      for (int dd = 0; dd < ND; ++dd) a += qr[dd] * kp[dd];
      sc[s] = a * SCALE;
      lmax = fmaxf(lmax, sc[s]);
    }
    for (int off = 32; off; off >>= 1) lmax = fmaxf(lmax, __shfl_xor(lmax, off));
    if ((t & 63) == 0) wred[t >> 6] = lmax;
    __syncthreads();
    lmax = fmaxf(fmaxf(wred[0], wred[1]), fmaxf(wred[2], wred[3]));
    float lsum = 0.f;
    #pragma unroll
    for (int s = 0; s < 16; ++s) { sc[s] = expf(sc[s] - lmax); lsum += sc[s]; }
    for (int off = 32; off; off >>= 1) lsum += __shfl_xor(lsum, off);
    if ((t & 63) == 0) wsum[t >> 6] = lsum;
    __syncthreads();
    lsum = wsum[0] + wsum[1] + wsum[2] + wsum[3];
    float inv = 1.0f / lsum;
    #pragma unroll
    for (int s = 0; s < 16; ++s)
      k3bf[((size_t)b * NM + i) * NN + t + 256 * s] = f2bf(sc[s] * inv);
  }
}

// ---------------- denom: max column-sum per batch (R5) ----------------
__global__ __launch_bounds__(256) void denom_kernel(const float* __restrict__ k2,
                                                    float* __restrict__ denw) {
  __shared__ float red[256];
  int b = blockIdx.x;
  int t = threadIdx.x;
  float cs = 0.f;
  for (int i = 0; i < NM; ++i) cs += k2[((size_t)b * NM + i) * NM + t];
  red[t] = cs;
  __syncthreads();
  for (int off = 128; off; off >>= 1) {
    if (t < off) red[t] = fmaxf(red[t], red[t + off]);
    __syncthreads();
  }
  if (t == 0) denw[b] = red[0];
}

// ---------------- 32x32-tile batched GEMM (R5 core, 303-verified) ----------------
__global__ __launch_bounds__(256) void gemm_rk32(
    const float* __restrict__ A, const float* __restrict__ Bm,
    float* __restrict__ out, float s_a, float s_ab) {
  int b = blockIdx.z;
  int bi = blockIdx.y * 32, bj = blockIdx.x * 32;
  __shared__ float As[32][260];
  __shared__ float Bs[256][36];
  int t = threadIdx.x;
  const float* Ab = A + (size_t)b * NM * NM;
  const float* Bb = Bm + (size_t)b * NM * NM;
  #pragma unroll
  for (int q = 0; q < 8; ++q) {
    int s = q * 256 + t;
    int ar = s >> 6, ac = (s & 63) * 4;
    *(float4*)&As[ar][ac] = *(const float4*)(Ab + (size_t)(bi + ar) * NM + ac);
    int br = s >> 3, bc = (s & 7) * 4;
    *(float4*)&Bs[br][bc] = *(const float4*)(Bb + (size_t)br * NM + bj + bc);
  }
  __syncthreads();
  int tx = t & 15, ty = t >> 4;
  float acc[2][2] = {};
  #pragma unroll 8
  for (int kk = 0; kk < NM; ++kk) {
    float a0 = As[ty * 2][kk], a1 = As[ty * 2 + 1][kk];
    float b0 = Bs[kk][tx * 2], b1 = Bs[kk][tx * 2 + 1];
    acc[0][0] += a0 * b0; acc[0][1] += a0 * b1;
    acc[1][0] += a1 * b0; acc[1][1] += a1 * b1;
  }
  #pragma unroll
  for (int i = 0; i < 2; ++i)
    #pragma unroll
    for (int j = 0; j < 2; ++j) {
      size_t o = ((size_t)b * NM + bi + ty * 2 + i) * NM + bj + tx * 2 + j;
      float r = s_ab * acc[i][j];
      if (s_a != 0.0f) r += s_a * A[o];
      out[o] = r;
    }
}

// ---- NS launch 1 of iter 0: Z = k2 @ V0, V0 virtual (fold of vinit) ----
__global__ __launch_bounds__(256) void gemm_rk32_zv0(
    const float* __restrict__ k2, const float* __restrict__ denw,
    float* __restrict__ out) {
  int b = blockIdx.z;
  int bi = blockIdx.y * 32, bj = blockIdx.x * 32;
  __shared__ float As[32][260];
  __shared__ float Bs[256][36];
  int t = threadIdx.x;
  const float* Ab = k2 + (size_t)b * NM * NM;
  float dval = 1.0f / fmaxf(denw[0], denw[1]);
  #pragma unroll
  for (int q = 0; q < 8; ++q) {
    int s = q * 256 + t;
    int ar = s >> 6, ac = (s & 63) * 4;
    *(float4*)&As[ar][ac] = *(const float4*)(Ab + (size_t)(bi + ar) * NM + ac);
    int br = s >> 6, bk4 = (s & 63) * 4;
    float4 vv = *(const float4*)(Ab + (size_t)(bj + br) * NM + bk4);
    Bs[bk4 + 0][br] = vv.x * dval; Bs[bk4 + 1][br] = vv.y * dval;
    Bs[bk4 + 2][br] = vv.z * dval; Bs[bk4 + 3][br] = vv.w * dval;
  }
  __syncthreads();
  int tx = t & 15, ty = t >> 4;
  float acc[2][2] = {};
  #pragma unroll 8
  for (int kk = 0; kk < NM; ++kk) {
    float a0 = As[ty * 2][kk], a1 = As[ty * 2 + 1][kk];
    float b0 = Bs[kk][tx * 2], b1 = Bs[kk][tx * 2 + 1];
    acc[0][0] += a0 * b0; acc[0][1] += a0 * b1;
    acc[1][0] += a1 * b0; acc[1][1] += a1 * b1;
  }
  #pragma unroll
  for (int i = 0; i < 2; ++i)
    #pragma unroll
    for (int j = 0; j < 2; ++j)
      out[((size_t)b * NM + bi + ty * 2 + i) * NM + bj + tx * 2 + j] = acc[i][j];
}

// ---- NS launch 4 of iter 0: V' = 3.25*V0 - 0.25*V0@T2, V0 virtual (A-side) ----
__global__ __launch_bounds__(256) void gemm_rk32_av0(
    const float* __restrict__ k2, const float* __restrict__ T2,
    const float* __restrict__ denw, float* __restrict__ out) {
  int b = blockIdx.z;
  int bi = blockIdx.y * 32, bj = blockIdx.x * 32;
  __shared__ float As[32][260];
  __shared__ float Bs[256][36];
  int t = threadIdx.x;
  const float* k2b = k2 + (size_t)b * NM * NM;
  const float* Bb = T2 + (size_t)b * NM * NM;
  float dval = 1.0f / fmaxf(denw[0], denw[1]);
  #pragma unroll
  for (int q = 0; q < 8; ++q) {
    int s = q * 256 + t;
    int kr = s >> 3, c4 = (s & 7) * 4;
    float4 vv = *(const float4*)(k2b + (size_t)kr * NM + bi + c4);
    As[c4 + 0][kr] = vv.x * dval; As[c4 + 1][kr] = vv.y * dval;
    As[c4 + 2][kr] = vv.z * dval; As[c4 + 3][kr] = vv.w * dval;
    int br = s >> 3, bc = (s & 7) * 4;
    *(float4*)&Bs[br][bc] = *(const float4*)(Bb + (size_t)br * NM + bj + bc);
  }
  __syncthreads();
  int tx = t & 15, ty = t >> 4;
  float acc[2][2] = {};
  #pragma unroll 8
  for (int kk = 0; kk < NM; ++kk) {
    float a0 = As[ty * 2][kk], a1 = As[ty * 2 + 1][kk];
    float b0 = Bs[kk][tx * 2], b1 = Bs[kk][tx * 2 + 1];
    acc[0][0] += a0 * b0; acc[0][1] += a0 * b1;
    acc[1][0] += a1 * b0; acc[1][1] += a1 * b1;
  }
  #pragma unroll
  for (int i = 0; i < 2; ++i)
    #pragma unroll
    for (int j = 0; j < 2; ++j) {
      int R = bi + ty * 2 + i, C = bj + tx * 2 + j;
      float a0v = k2b[(size_t)C * NM + R] * dval;
      out[((size_t)b * NM + R) * NM + C] = 3.25f * a0v - 0.25f * acc[i][j];
    }
}

// ---- NS last launch: V' written bf16 TRANSPOSED (fold of cvt_vinv) ----
__global__ __launch_bounds__(256) void gemm_rk32_wt(
    const float* __restrict__ A, const float* __restrict__ Bm,
    ushort* __restrict__ Vt) {
  int b = blockIdx.z;
  int bi = blockIdx.y * 32, bj = blockIdx.x * 32;
  __shared__ float As[32][260];
  __shared__ float Bs[256][36];
  int t = threadIdx.x;
  const float* Ab = A + (size_t)b * NM * NM;
  const float* Bb = Bm + (size_t)b * NM * NM;
  #pragma unroll
  for (int q = 0; q < 8; ++q) {
    int s = q * 256 + t;
    int ar = s >> 6, ac = (s & 63) * 4;
    *(float4*)&As[ar][ac] = *(const float4*)(Ab + (size_t)(bi + ar) * NM + ac);
    int br = s >> 3, bc = (s & 7) * 4;
    *(float4*)&Bs[br][bc] = *(const float4*)(Bb + (size_t)br * NM + bj + bc);
  }
  __syncthreads();
  int tx = t & 15, ty = t >> 4;
  float acc[2][2] = {};
  #pragma unroll 8
  for (int kk = 0; kk < NM; ++kk) {
    float a0 = As[ty * 2][kk], a1 = As[ty * 2 + 1][kk];
    float b0 = Bs[kk][tx * 2], b1 = Bs[kk][tx * 2 + 1];
    acc[0][0] += a0 * b0; acc[0][1] += a0 * b1;
    acc[1][0] += a1 * b0; acc[1][1] += a1 * b1;
  }
  __syncthreads();
  float (*tile)[33] = (float (*)[33])&As[0][0];
  #pragma unroll
  for (int i = 0; i < 2; ++i)
    #pragma unroll
    for (int j = 0; j < 2; ++j) {
      int R = ty * 2 + i, C = tx * 2 + j;
      float a0v = Ab[(size_t)(bi + R) * NM + bj + C];
      tile[R][C] = 3.25f * a0v - 0.25f * acc[i][j];
    }
  __syncthreads();
  int rr = t >> 3, m4 = (t & 7) * 4;
  ushort4 u;
  u.x = f2bf(tile[m4 + 0][rr]); u.y = f2bf(tile[m4 + 1][rr]);
  u.z = f2bf(tile[m4 + 2][rr]); u.w = f2bf(tile[m4 + 3][rr]);
  *(ushort4*)(Vt + ((size_t)b * NM + bj + rr) * NM + bi + m4) = u;
}

// ---------------- k3bf [B][NM][NN] bf16 -> k3t [B][NN][NM] bf16 (transpose) ----------------
__global__ __launch_bounds__(256) void cvt_t_kernel(const ushort* __restrict__ k3,
                                                    ushort* __restrict__ k3t) {
  int b = blockIdx.z;
  int n0 = blockIdx.x * 32, m0 = blockIdx.y * 32;
  __shared__ ushort tile[32][33];
  int t = threadIdx.x;
  int r = t >> 3, c4 = (t & 7) * 4;
  ushort4 v = *(const ushort4*)(k3 + ((size_t)b * NM + m0 + r) * NN + n0 + c4);
  tile[c4][r] = v.x; tile[c4 + 1][r] = v.y; tile[c4 + 2][r] = v.z; tile[c4 + 3][r] = v.w;
  __syncthreads();
  ushort4 u;
  u.x = tile[r][c4];     u.y = tile[r][c4 + 1];
  u.z = tile[r][c4 + 2]; u.w = tile[r][c4 + 3];
  *(ushort4*)(k3t + ((size_t)b * NN + n0 + r) * NM + m0 + c4) = u;
}

// ---------------- A = k1 @ Vinv via bf16 MFMA (R5) ----------------
__global__ __launch_bounds__(256) void gemm_a_mfma(
    const ushort* __restrict__ k1bf, const ushort* __restrict__ Vt,
    ushort* __restrict__ Abf) {
  int b = blockIdx.z;
  int bi = blockIdx.y * 128, bj = blockIdx.x * 128;
  __shared__ ushort As[128 * 64];
  __shared__ ushort Bs[128 * 64];
  int t = threadIdx.x;
  int wave = t >> 6, lane = t & 63;
  int wr = wave >> 1, wc = wave & 1;
  const ushort* Ab = k1bf + (size_t)b * NN * NM;
  const ushort* Bb = Vt + (size_t)b * NM * NM;
  f32x4 acc[4][4] = {};
  for (int k0 = 0; k0 < NM; k0 += 64) {
    #pragma unroll
    for (int q = 0; q < 4; ++q) {
      int s = q * 256 + t;
      int r = s >> 3, c = s & 7;
      int cs = (c ^ (r & 7)) << 3;
      gl_lds16(Ab + (size_t)(bi + r) * NM + k0 + cs, As + (size_t)s * 8);
      gl_lds16(Bb + (size_t)(bj + r) * NM + k0 + cs, Bs + (size_t)s * 8);
    }
    __syncthreads();
    #pragma unroll
    for (int kk = 0; kk < 2; ++kk) {
      int koff = kk * 64 + (lane >> 4) * 16;
      bf16x8 af[4], bfv[4];
      #pragma unroll
      for (int mi = 0; mi < 4; ++mi) {
        int row = wr * 64 + mi * 16 + (lane & 15);
        af[mi] = *(const bf16x8*)((const char*)As + row * 128 + (koff ^ ((row & 7) << 4)));
      }
      #pragma unroll
      for (int nj = 0; nj < 4; ++nj) {
        int row = wc * 64 + nj * 16 + (lane & 15);
        bfv[nj] = *(const bf16x8*)((const char*)Bs + row * 128 + (koff ^ ((row & 7) << 4)));
      }
      #pragma unroll
      for (int mi = 0; mi < 4; ++mi)
        #pragma unroll
        for (int nj = 0; nj < 4; ++nj)
          acc[mi][nj] = __builtin_amdgcn_mfma_f32_16x16x32_bf16(af[mi], bfv[nj], acc[mi][nj], 0, 0, 0);
    }
    __syncthreads();
  }
  int col = lane & 15, rbase = (lane >> 4) * 4;
  #pragma unroll
  for (int mi = 0; mi < 4; ++mi)
    #pragma unroll
    for (int nj = 0; nj < 4; ++nj)
      #pragma unroll
      for (int r = 0; r < 4; ++r)
        Abf[((size_t)b * NN + bi + wr * 64 + mi * 16 + rbase + r) * NM
            + bj + wc * 64 + nj * 16 + col] = f2bf(acc[mi][nj][r]);
}

// ---------------- attn = A @ k3 via bf16 MFMA, 128x128 tile, XCD swizzle, nt stores ----------------
__global__ __launch_bounds__(256) void gemm_attn_mfma(
    const ushort* __restrict__ Abf, const ushort* __restrict__ K3T,
    float* __restrict__ attn) {
  int lin = blockIdx.z * 1024 + blockIdx.y * 32 + blockIdx.x;
  int swz = (lin & 7) * 256 + (lin >> 3);
  int b = swz >> 10;
  int rem = swz & 1023;
  int bi = (rem >> 5) * 128, bj = (rem & 31) * 128;
  __shared__ ushort As[128 * 64];
  __shared__ ushort Bs[128 * 64];
  int t = threadIdx.x;
  int wave = t >> 6, lane = t & 63;
  int wr = wave >> 1, wc = wave & 1;
  const ushort* Ab = Abf + (size_t)b * NN * NM;
  const ushort* Bb = K3T + (size_t)b * NN * NM;
  f32x4 acc[4][4] = {};
  for (int k0 = 0; k0 < NM; k0 += 64) {
    #pragma unroll
    for (int q = 0; q < 4; ++q) {
      int s = q * 256 + t;
      int r = s >> 3, c = s & 7;
      int cs = (c ^ (r & 7)) << 3;
      gl_lds16(Ab + (size_t)(bi + r) * NM + k0 + cs, As + (size_t)s * 8);
      gl_lds16(Bb + (size_t)(bj + r) * NM + k0 + cs, Bs + (size_t)s * 8);
    }
    __syncthreads();
    #pragma unroll
    for (int kk = 0; kk < 2; ++kk) {
      int koff = kk * 64 + (lane >> 4) * 16;
      bf16x8 af[4], bfv[4];
      #pragma unroll
      for (int mi = 0; mi < 4; ++mi) {
        int row = wr * 64 + mi * 16 + (lane & 15);
        af[mi] = *(const bf16x8*)((const char*)As + row * 128 + (koff ^ ((row & 7) << 4)));
      }
      #pragma unroll
      for (int nj = 0; nj < 4; ++nj) {
        int row = wc * 64 + nj * 16 + (lane & 15);
        bfv[nj] = *(const bf16x8*)((const char*)Bs + row * 128 + (koff ^ ((row & 7) << 4)));
      }
      #pragma unroll
      for (int mi = 0; mi < 4; ++mi)
        #pragma unroll
        for (int nj = 0; nj < 4; ++nj)
          acc[mi][nj] = __builtin_amdgcn_mfma_f32_16x16x32_bf16(af[mi], bfv[nj], acc[mi][nj], 0, 0, 0);
    }
    __syncthreads();
  }
  int col = lane & 15, rbase = (lane >> 4) * 4;
  #pragma unroll
  for (int mi = 0; mi < 4; ++mi)
    #pragma unroll
    for (int nj = 0; nj < 4; ++nj)
      #pragma unroll
      for (int r = 0; r < 4; ++r)
        __builtin_nontemporal_store(
            acc[mi][nj][r],
            &attn[((size_t)b * NN + bi + wr * 64 + mi * 16 + rbase + r) * NN
                  + bj + wc * 64 + nj * 16 + col]);
}

// ---------------- split-K kv (k3 bf16, atomicAdd into zeroed buffer) ----------------
__global__ __launch_bounds__(256) void kv_kernel(
    const ushort* __restrict__ K3, const float* __restrict__ Vv,
    float* __restrict__ kvout) {
  int b = blockIdx.z, bp = blockIdx.x * 64;
  int j0base = blockIdx.y * (NN / 32);
  __shared__ float Ks[64][33], Vs[64][33];
  int t = threadIdx.x, tx = t & 15, ty = t >> 4;
  int lrow = t >> 2, ljc = (t & 3) * 8;
  float acc[4][4] = {};
  for (int j0 = j0base; j0 < j0base + NN / 32; j0 += 32) {
    bf16x8 a0 = *(const bf16x8*)(K3 + ((size_t)b * NM + bp + lrow) * NN + j0 + ljc);
    float4 v0 = *(const float4*)(Vv + ((size_t)b * NC + lrow) * NN + j0 + ljc);
    float4 v1 = *(const float4*)(Vv + ((size_t)b * NC + lrow) * NN + j0 + ljc + 4);
    #pragma unroll
    for (int e = 0; e < 8; ++e) Ks[lrow][ljc + e] = bf2f((ushort)a0[e]);
    Vs[lrow][ljc + 0] = v0.x; Vs[lrow][ljc + 1] = v0.y; Vs[lrow][ljc + 2] = v0.z; Vs[lrow][ljc + 3] = v0.w;
    Vs[lrow][ljc + 4] = v1.x; Vs[lrow][ljc + 5] = v1.y; Vs[lrow][ljc + 6] = v1.z; Vs[lrow][ljc + 7] = v1.w;
    __syncthreads();
    #pragma unroll
    for (int kk = 0; kk < 32; ++kk) {
      float av_[4], bv_[4];
      #pragma unroll
      for (int i = 0; i < 4; ++i) av_[i] = Ks[(ty << 2) + i][kk];
      #pragma unroll
      for (int j = 0; j < 4; ++j) bv_[j] = Vs[(tx << 2) + j][kk];
      #pragma unroll
      for (int i = 0; i < 4; ++i)
        #pragma unroll
        for (int j = 0; j < 4; ++j) acc[i][j] += av_[i] * bv_[j];
    }
    __syncthreads();
  }
  #pragma unroll
  for (int i = 0; i < 4; ++i)
    #pragma unroll
    for (int j = 0; j < 4; ++j)
      atomicAdd(&kvout[((size_t)b * NM + bp + (ty << 2) + i) * NC + (tx << 2) + j], acc[i][j]);
}

// ---------------- out = gamma*(A@kv) + x  (A in bf16, nt stores) ----------------
__global__ __launch_bounds__(256) void out_kernel(
    const ushort* __restrict__ Abf, const float* __restrict__ kvm,
    const float* __restrict__ x, const float* __restrict__ gamma,
    float* __restrict__ outp) {
  __shared__ float As[32 * 256];
  int blk = blockIdx.x;
  int b = blk / (NN / 32), n0 = (blk % (NN / 32)) * 32;
  int t = threadIdx.x;
  for (int it = 0; it < 32; ++it)
    As[it * 256 + (t ^ (it & 31))] = bf2f(Abf[((size_t)b * NN + n0 + it) * NM + t]);
  __syncthreads();
  int tn = t & 31, cg0 = (t >> 5) * 8;
  float g = gamma[0];
  float acc[8] = {};
  for (int p = 0; p < NM; ++p) {
    float a = As[tn * 256 + (p ^ (tn & 31))];
    float4 kv0 = *(const float4*)(kvm + ((size_t)b * NM + p) * NC + cg0);
    float4 kv1 = *(const float4*)(kvm + ((size_t)b * NM + p) * NC + cg0 + 4);
    acc[0] += a * kv0.x; acc[1] += a * kv0.y; acc[2] += a * kv0.z; acc[3] += a * kv0.w;
    acc[4] += a * kv1.x; acc[5] += a * kv1.y; acc[6] += a * kv1.z; acc[7] += a * kv1.w;
  }
  #pragma unroll
  for (int qd = 0; qd < 8; ++qd) {
    int c = cg0 + qd;
    size_t idx = ((size_t)b * NC + c) * NN + n0 + tn;
    __builtin_nontemporal_store(g * acc[qd] + x[idx], &outp[idx]);
  }
}

extern "C" void kernel_launch(void* const* d_in, const int* in_sizes, int n_in,
                              void* d_out, int out_size, void* d_ws, size_t ws_size,
                              hipStream_t stream) {
  const float* x     = (const float*)d_in[0];
  const float* wq    = (const float*)d_in[1];
  const float* bq    = (const float*)d_in[2];
  const float* wk    = (const float*)d_in[3];
  const float* bk    = (const float*)d_in[4];
  const float* wv    = (const float*)d_in[5];
  const float* bv    = (const float*)d_in[6];
  const float* gamma = (const float*)d_in[7];
  float* outp = (float*)d_out;                       // [B][C][N]
  float* attn = outp + (size_t)NB * NC * NN;         // [B][N][N]
  float* w = (float*)d_ws;

  float* qw   = w;                 // [B][N][D]    65536
  float* kw   = qw + 65536;        // [B][N][D]    65536
  float* vw   = kw + 65536;        // [B][C][N]    524288
  float* qlw  = vw + 524288;       // [B][M][D]    4096
  float* klw  = qlw + 4096;        // [B][M][D]    4096
  float* k1w  = klw + 4096;        // 8 MB region: k1bf (4MB) + k3T (4MB)
  float* k2w  = k1w + 2097152;     // [B][M][M]    131072
  float* k3w  = k2w + 131072;      // region: k3bf row-major bf16 (4 MB of 8)
  float* Abuf = k3w + 2097152;     // 4 MB region: Abf bf16
  float* Va   = Abuf + 1048576;    // [B][M][M]    131072
  float* Vb   = Va + 131072;       // [B][M][M]    131072
  float* Zb   = Vb + 131072;       // [B][M][M]    131072
  float* T1   = Zb + 131072;       // [B][M][M]    131072
  float* T2   = T1 + 131072;       // [B][M][M]    131072
  float* Vtw  = T2 + 131072;       // Vinvt bf16   65536 floats
  float* kvw  = Vtw + 65536;       // [B][M][C]    32768
  float* denw = kvw + 32768;       // [2]
  ushort* k1bf  = (ushort*)k1w;                 // [B][N][M] bf16
  ushort* k3T   = (ushort*)k1w + 2097152;       // [B][N][M] bf16 (k3^T)
  ushort* k3bf  = (ushort*)k3w;                 // [B][M][N] bf16 row-major
  ushort* Abf   = (ushort*)Abuf;                // [B][N][M] bf16
  ushort* Vinvt = (ushort*)Vtw;                 // [B][M][M] bf16 (Vinv^T)

  hipMemsetAsync(kvw, 0, (size_t)NB * NM * NC * sizeof(float), stream);
  qkv4_kernel<<<dim3(20, NN / 1024, NB), dim3(256), 0, stream>>>(
      x, wq, bq, wk, bk, wv, bv, qw, kw, vw, qlw, klw);
  scores_all_kernel<<<dim3(2048 + 128 + 512), dim3(256), 0, stream>>>(
      qw, qlw, kw, klw, k1bf, k2w, k3bf);
  denom_kernel<<<dim3(NB), dim3(256), 0, stream>>>(k2w, denw);

  // Newton-Schulz: R12 structure (fp32; V0 virtualized iter-0; last writes Vinvt)
  gemm_rk32_zv0<<<dim3(8, 8, NB), dim3(256), 0, stream>>>(k2w, denw, Zb);
  gemm_rk32<<<dim3(8, 8, NB), dim3(256), 0, stream>>>(Zb, Zb, T1, 7.f, -1.f);
  gemm_rk32<<<dim3(8, 8, NB), dim3(256), 0, stream>>>(Zb, T1, T2, 15.f, -1.f);
  gemm_rk32_av0<<<dim3(8, 8, NB), dim3(256), 0, stream>>>(k2w, T2, denw, Va);
  float* Vc = Va; float* Vn = Vb;
  for (int it = 1; it < 5; ++it) {
    gemm_rk32<<<dim3(8, 8, NB), dim3(256), 0, stream>>>(k2w, Vc, Zb, 0.f, 1.f);
    gemm_rk32<<<dim3(8, 8, NB), dim3(256), 0, stream>>>(Zb, Zb, T1, 7.f, -1.f);
    gemm_rk32<<<dim3(8, 8, NB), dim3(256), 0, stream>>>(Zb, T1, T2, 15.f, -1.f);
    gemm_rk32<<<dim3(8, 8, NB), dim3(256), 0, stream>>>(Vc, T2, Vn, 3.25f, -0.25f);
    float* tmp = Vc; Vc = Vn; Vn = tmp;
  }
  gemm_rk32<<<dim3(8, 8, NB), dim3(256), 0, stream>>>(k2w, Vc, Zb, 0.f, 1.f);
  gemm_rk32<<<dim3(8, 8, NB), dim3(256), 0, stream>>>(Zb, Zb, T1, 7.f, -1.f);
  gemm_rk32<<<dim3(8, 8, NB), dim3(256), 0, stream>>>(Zb, T1, T2, 15.f, -1.f);
  gemm_rk32_wt<<<dim3(8, 8, NB), dim3(256), 0, stream>>>(Vc, T2, Vinvt);

  cvt_t_kernel<<<dim3(NN / 32, NM / 32, NB), dim3(256), 0, stream>>>(k3bf, k3T);
  gemm_a_mfma<<<dim3(NM / 128, NN / 128, NB), dim3(256), 0, stream>>>(k1bf, Vinvt, Abf);
  gemm_attn_mfma<<<dim3(NN / 128, NN / 128, NB), dim3(256), 0, stream>>>(Abf, k3T, attn);
  kv_kernel<<<dim3(NM / 64, 32, NB), dim3(256), 0, stream>>>(k3bf, vw, kvw);
  out_kernel<<<dim3(NB * NN / 32), dim3(256), 0, stream>>>(Abf, kvw, x, gamma, outp);
}

// Round 15
// 285.483 us; speedup vs baseline: 1.1175x; 1.0465x over previous
//
#include <hip/hip_runtime.h>
#include <hip/hip_bf16.h>
#include <math.h>

#define NB 2        // batch
#define NC 64       // channels
#define ND 8        // head dim (C/8)
#define NN 4096     // tokens (T*W*H)
#define NM 256      // landmarks
#define NL 16       // N/M
#define SCALE 0.35355339059327373f  // 1/sqrt(8)
#define SLICE (NB * NM * NM)        // floats between split-K pair slices

typedef __attribute__((ext_vector_type(4))) float f32x4;
typedef __attribute__((ext_vector_type(8))) short bf16x8;

__device__ inline ushort f2bf(float f) {
  __hip_bfloat16 h = __float2bfloat16(f);
  return *reinterpret_cast<ushort*>(&h);
}
__device__ inline float bf2f(ushort u) {
  return __uint_as_float(((unsigned int)u) << 16);
}

// async global->LDS, 16B per lane; LDS dest must be wave-linear (base + lane*16)
__device__ inline void gl_lds16(const void* g, void* l) {
  __builtin_amdgcn_global_load_lds(
      (const __attribute__((address_space(1))) unsigned int*)g,
      (__attribute__((address_space(3))) unsigned int*)l, 16, 0, 0);
}

// ---------------- qkv projection, 4 output rows per block + fused landmarks (R12) ----------------
__global__ __launch_bounds__(256) void qkv4_kernel(
    const float* __restrict__ x,
    const float* __restrict__ wq, const float* __restrict__ bq,
    const float* __restrict__ wk, const float* __restrict__ bk,
    const float* __restrict__ wv, const float* __restrict__ bv,
    float* __restrict__ q, float* __restrict__ k, float* __restrict__ v,
    float* __restrict__ ql, float* __restrict__ kl) {
  __shared__ float ws[4][NC];
  int o0 = blockIdx.x * 4;
  int b = blockIdx.z;
  int n0 = blockIdx.y * 1024;
  int t = threadIdx.x;
  {
    int j = t >> 6, c = t & 63;
    int o = o0 + j;
    const float* wrow;
    if (o < ND)          wrow = wq + (size_t)o * NC;
    else if (o < 2 * ND) wrow = wk + (size_t)(o - ND) * NC;
    else                 wrow = wv + (size_t)(o - 2 * ND) * NC;
    ws[j][c] = wrow[c];
  }
  __syncthreads();
  int n = n0 + t * 4;
  float4 acc[4];
  #pragma unroll
  for (int j = 0; j < 4; ++j) {
    int o = o0 + j;
    float bias = (o < ND) ? bq[o] : (o < 2 * ND ? bk[o - ND] : bv[o - 2 * ND]);
    acc[j].x = bias; acc[j].y = bias; acc[j].z = bias; acc[j].w = bias;
  }
  for (int c = 0; c < NC; ++c) {
    float4 xv = *(const float4*)(x + ((size_t)b * NC + c) * NN + n);
    #pragma unroll
    for (int j = 0; j < 4; ++j) {
      float wc = ws[j][c];
      acc[j].x += wc * xv.x; acc[j].y += wc * xv.y;
      acc[j].z += wc * xv.z; acc[j].w += wc * xv.w;
    }
  }
  #pragma unroll
  for (int j = 0; j < 4; ++j) {
    int o = o0 + j;
    if (o < ND) {
      float* qp = q + ((size_t)b * NN + n) * ND + o;
      qp[0] = acc[j].x; qp[8] = acc[j].y; qp[16] = acc[j].z; qp[24] = acc[j].w;
    } else if (o < 2 * ND) {
      float* kp = k + ((size_t)b * NN + n) * ND + (o - ND);
      kp[0] = acc[j].x; kp[8] = acc[j].y; kp[16] = acc[j].z; kp[24] = acc[j].w;
    } else {
      *(float4*)(v + ((size_t)b * NC + (o - 2 * ND)) * NN + n) = acc[j];
    }
    if (o < 2 * ND) {
      float s4 = acc[j].x + acc[j].y + acc[j].z + acc[j].w;
      s4 += __shfl_xor(s4, 1);
      s4 += __shfl_xor(s4, 2);
      if ((t & 3) == 0) {
        int g = n0 / 16 + (t >> 2);
        float* dst = (o < ND) ? ql : kl;
        dst[((size_t)b * NM + g) * ND + (o & 7)] = s4 * (1.0f / 16.0f);
      }
    }
  }
}

// ---------------- merged softmaxes: k1 bf16 / k2 f32 / k3 bf16 row-major (R14) ----------------
__global__ __launch_bounds__(256) void scores_all_kernel(
    const float* __restrict__ q, const float* __restrict__ ql,
    const float* __restrict__ kw, const float* __restrict__ kl,
    ushort* __restrict__ k1bf, float* __restrict__ k2w,
    ushort* __restrict__ k3bf) {
  __shared__ float skl[NM][9];
  __shared__ float wred[4], wsum[4];
  int blk = blockIdx.x;
  int t = threadIdx.x;
  if (blk < 2048 + 128) {
    const float* Q; int R, b, xrow;
    bool isbf;
    if (blk < 2048) { b = blk >> 10; xrow = blk & 1023; Q = q;  R = NN; isbf = true; }
    else { int r = blk - 2048; b = r >> 6; xrow = r & 63; Q = ql; R = NM; isbf = false; }
    for (int i = t; i < NM * ND; i += 256) skl[i >> 3][i & 7] = kl[(size_t)b * NM * ND + i];
    __syncthreads();
    int wave = t >> 6, lane = t & 63;
    int r = xrow * 4 + wave;
    const float* qrow = Q + ((size_t)b * R + r) * ND;
    float qr[ND];
    #pragma unroll
    for (int dd = 0; dd < ND; ++dd) qr[dd] = qrow[dd];
    float sc[4];
    float lmax = -1e30f;
    #pragma unroll
    for (int s = 0; s < 4; ++s) {
      int j = lane + 64 * s;
      float a = 0.f;
      #pragma unroll
      for (int dd = 0; dd < ND; ++dd) a += qr[dd] * skl[j][dd];
      sc[s] = a * SCALE;
      lmax = fmaxf(lmax, sc[s]);
    }
    for (int off = 32; off; off >>= 1) lmax = fmaxf(lmax, __shfl_xor(lmax, off));
    float lsum = 0.f;
    #pragma unroll
    for (int s = 0; s < 4; ++s) { sc[s] = expf(sc[s] - lmax); lsum += sc[s]; }
    for (int off = 32; off; off >>= 1) lsum += __shfl_xor(lsum, off);
    float inv = 1.0f / lsum;
    if (isbf) {
      #pragma unroll
      for (int s = 0; s < 4; ++s)
        k1bf[((size_t)b * R + r) * NM + lane + 64 * s] = f2bf(sc[s] * inv);
    } else {
      #pragma unroll
      for (int s = 0; s < 4; ++s)
        k2w[((size_t)b * R + r) * NM + lane + 64 * s] = sc[s] * inv;
    }
  } else {
    // k3 softmax -> bf16 row-major [M][N]
    int r = blk - 2176;
    int b = r >> 8, i = r & 255;
    float qr[ND];
    #pragma unroll
    for (int dd = 0; dd < ND; ++dd) qr[dd] = ql[((size_t)b * NM + i) * ND + dd];
    float sc[16];
    float lmax = -1e30f;
    #pragma unroll
    for (int s = 0; s < 16; ++s) {
      int n = t + 256 * s;
      const float* kp = kw + ((size_t)b * NN + n) * ND;
      float a = 0.f;
      #pragma unroll
      for (int dd = 0; dd < ND; ++dd) a += qr[dd] * kp[dd];
      sc[s] = a * SCALE;
      lmax = fmaxf(lmax, sc[s]);
    }
    for (int off = 32; off; off >>= 1) lmax = fmaxf(lmax, __shfl_xor(lmax, off));
    if ((t & 63) == 0) wred[t >> 6] = lmax;
    __syncthreads();
    lmax = fmaxf(fmaxf(wred[0], wred[1]), fmaxf(wred[2], wred[3]));
    float lsum = 0.f;
    #pragma unroll
    for (int s = 0; s < 16; ++s) { sc[s] = expf(sc[s] - lmax); lsum += sc[s]; }
    for (int off = 32; off; off >>= 1) lsum += __shfl_xor(lsum, off);
    if ((t & 63) == 0) wsum[t >> 6] = lsum;
    __syncthreads();
    lsum = wsum[0] + wsum[1] + wsum[2] + wsum[3];
    float inv = 1.0f / lsum;
    #pragma unroll
    for (int s = 0; s < 16; ++s)
      k3bf[((size_t)b * NM + i) * NN + t + 256 * s] = f2bf(sc[s] * inv);
  }
}

// ---------------- denom: max column-sum per batch (R5) ----------------
__global__ __launch_bounds__(256) void denom_kernel(const float* __restrict__ k2,
                                                    float* __restrict__ denw) {
  __shared__ float red[256];
  int b = blockIdx.x;
  int t = threadIdx.x;
  float cs = 0.f;
  for (int i = 0; i < NM; ++i) cs += k2[((size_t)b * NM + i) * NM + t];
  red[t] = cs;
  __syncthreads();
  for (int off = 128; off; off >>= 1) {
    if (t < off) red[t] = fmaxf(red[t], red[t + off]);
    __syncthreads();
  }
  if (t == 0) denw[b] = red[0];
}

// ============ NS split-K x2: 256 blocks/launch (one per CU), R5 internals ============
// O_slice = s_ab * (A @ B)[K-half slice] ; slice 0 additionally += s_a * A_total
// amode: 0 = plain fp32 matrix; 1 = pair (sum slices); 2 = virtual V0 = k2^T * dval
// bmode: 1 = pair; 2 = virtual V0
__global__ __launch_bounds__(256) void ns2_kernel(
    const float* __restrict__ A, int amode,
    const float* __restrict__ B, int bmode,
    const float* __restrict__ denw, float* __restrict__ O,
    float s_a, float s_ab) {
  __shared__ float As[32][132];   // [row][k-half], pitch 132 (same mod-32 residue as 260)
  __shared__ float Bs[128][36];   // [k-half][col]
  int t = threadIdx.x;
  int bi = blockIdx.y * 32, bj = blockIdx.x * 32;
  int b = blockIdx.z >> 1, slice = blockIdx.z & 1;
  int k0 = slice * 128;
  size_t bo = (size_t)b * NM * NM;
  float dval = (amode == 2 || bmode == 2) ? 1.0f / fmaxf(denw[0], denw[1]) : 0.f;
  // ---- stage A half-panel ----
  if (amode == 2) {
    // As[r][k] = k2[k0+k][bi+r] * dval   (coalesced float4 along r)
    #pragma unroll
    for (int q = 0; q < 4; ++q) {
      int s = q * 256 + t;
      int k = s >> 3, rc = (s & 7) * 4;
      float4 v = *(const float4*)(A + bo + (size_t)(k0 + k) * NM + bi + rc);
      As[rc + 0][k] = v.x * dval; As[rc + 1][k] = v.y * dval;
      As[rc + 2][k] = v.z * dval; As[rc + 3][k] = v.w * dval;
    }
  } else {
    #pragma unroll
    for (int q = 0; q < 4; ++q) {
      int s = q * 256 + t;
      int ar = s >> 5, ac = (s & 31) * 4;
      const float* p = A + bo + (size_t)(bi + ar) * NM + k0 + ac;
      float4 v = *(const float4*)p;
      if (amode == 1) {
        float4 v1 = *(const float4*)(p + SLICE);
        v.x += v1.x; v.y += v1.y; v.z += v1.z; v.w += v1.w;
      }
      *(float4*)&As[ar][ac] = v;
    }
  }
  // ---- stage B half-panel ----
  if (bmode == 2) {
    // Bs[k][c] = k2[bj+c][k0+k] * dval   (coalesced float4 along k)
    #pragma unroll
    for (int q = 0; q < 4; ++q) {
      int s = q * 256 + t;
      int c = s >> 5, kc = (s & 31) * 4;
      float4 v = *(const float4*)(B + bo + (size_t)(bj + c) * NM + k0 + kc);
      Bs[kc + 0][c] = v.x * dval; Bs[kc + 1][c] = v.y * dval;
      Bs[kc + 2][c] = v.z * dval; Bs[kc + 3][c] = v.w * dval;
    }
  } else {
    #pragma unroll
    for (int q = 0; q < 4; ++q) {
      int s = q * 256 + t;
      int bk = s >> 3, bc = (s & 7) * 4;
      const float* p = B + bo + (size_t)(k0 + bk) * NM + bj + bc;
      float4 v = *(const float4*)p;
      if (bmode == 1) {
        float4 v1 = *(const float4*)(p + SLICE);
        v.x += v1.x; v.y += v1.y; v.z += v1.z; v.w += v1.w;
      }
      *(float4*)&Bs[bk][bc] = v;
    }
  }
  __syncthreads();
  int tx = t & 15, ty = t >> 4;
  float acc[2][2] = {};
  #pragma unroll 8
  for (int kk = 0; kk < 128; ++kk) {
    float a0 = As[ty * 2][kk], a1 = As[ty * 2 + 1][kk];
    float b0 = Bs[kk][tx * 2], b1 = Bs[kk][tx * 2 + 1];
    acc[0][0] += a0 * b0; acc[0][1] += a0 * b1;
    acc[1][0] += a1 * b0; acc[1][1] += a1 * b1;
  }
  float* Op = O + (size_t)slice * SLICE + bo;
  bool addA = (slice == 0) && (s_a != 0.0f);
  #pragma unroll
  for (int i = 0; i < 2; ++i)
    #pragma unroll
    for (int j = 0; j < 2; ++j) {
      int R = bi + ty * 2 + i, C = bj + tx * 2 + j;
      float r = s_ab * acc[i][j];
      if (addA) {
        float av;
        if (amode == 2)      av = A[bo + (size_t)C * NM + R] * dval;
        else if (amode == 1) av = A[bo + (size_t)R * NM + C] + A[bo + SLICE + (size_t)R * NM + C];
        else                 av = A[bo + (size_t)R * NM + C];
        r += s_a * av;
      }
      Op[(size_t)R * NM + C] = r;
    }
}

// ---- NS final launch: V' = 3.25*V - 0.25*V@T2 (A,B pairs), full K, bf16^T out ----
__global__ __launch_bounds__(256) void gemm_rk32_wt_pair(
    const float* __restrict__ A, const float* __restrict__ Bm,
    ushort* __restrict__ Vt) {
  int b = blockIdx.z;
  int bi = blockIdx.y * 32, bj = blockIdx.x * 32;
  __shared__ float As[32][260];
  __shared__ float Bs[256][36];
  int t = threadIdx.x;
  const float* Ab = A + (size_t)b * NM * NM;
  const float* Bb = Bm + (size_t)b * NM * NM;
  #pragma unroll
  for (int q = 0; q < 8; ++q) {
    int s = q * 256 + t;
    int ar = s >> 6, ac = (s & 63) * 4;
    const float* pa = Ab + (size_t)(bi + ar) * NM + ac;
    float4 va = *(const float4*)pa;
    float4 va1 = *(const float4*)(pa + SLICE);
    va.x += va1.x; va.y += va1.y; va.z += va1.z; va.w += va1.w;
    *(float4*)&As[ar][ac] = va;
    int br = s >> 3, bc = (s & 7) * 4;
    const float* pb = Bb + (size_t)br * NM + bj + bc;
    float4 vb = *(const float4*)pb;
    float4 vb1 = *(const float4*)(pb + SLICE);
    vb.x += vb1.x; vb.y += vb1.y; vb.z += vb1.z; vb.w += vb1.w;
    *(float4*)&Bs[br][bc] = vb;
  }
  __syncthreads();
  int tx = t & 15, ty = t >> 4;
  float acc[2][2] = {};
  #pragma unroll 8
  for (int kk = 0; kk < NM; ++kk) {
    float a0 = As[ty * 2][kk], a1 = As[ty * 2 + 1][kk];
    float b0 = Bs[kk][tx * 2], b1 = Bs[kk][tx * 2 + 1];
    acc[0][0] += a0 * b0; acc[0][1] += a0 * b1;
    acc[1][0] += a1 * b0; acc[1][1] += a1 * b1;
  }
  __syncthreads();
  float (*tile)[33] = (float (*)[33])&As[0][0];
  #pragma unroll
  for (int i = 0; i < 2; ++i)
    #pragma unroll
    for (int j = 0; j < 2; ++j) {
      int R = ty * 2 + i, C = tx * 2 + j;
      size_t o = (size_t)(bi + R) * NM + bj + C;
      float a0v = Ab[o] + Ab[o + SLICE];
      tile[R][C] = 3.25f * a0v - 0.25f * acc[i][j];
    }
  __syncthreads();
  int rr = t >> 3, m4 = (t & 7) * 4;
  ushort4 u;
  u.x = f2bf(tile[m4 + 0][rr]); u.y = f2bf(tile[m4 + 1][rr]);
  u.z = f2bf(tile[m4 + 2][rr]); u.w = f2bf(tile[m4 + 3][rr]);
  *(ushort4*)(Vt + ((size_t)b * NM + bj + rr) * NM + bi + m4) = u;
}

// ---------------- k3bf [B][NM][NN] bf16 -> k3t [B][NN][NM] bf16 (transpose) ----------------
__global__ __launch_bounds__(256) void cvt_t_kernel(const ushort* __restrict__ k3,
                                                    ushort* __restrict__ k3t) {
  int b = blockIdx.z;
  int n0 = blockIdx.x * 32, m0 = blockIdx.y * 32;
  __shared__ ushort tile[32][33];
  int t = threadIdx.x;
  int r = t >> 3, c4 = (t & 7) * 4;
  ushort4 v = *(const ushort4*)(k3 + ((size_t)b * NM + m0 + r) * NN + n0 + c4);
  tile[c4][r] = v.x; tile[c4 + 1][r] = v.y; tile[c4 + 2][r] = v.z; tile[c4 + 3][r] = v.w;
  __syncthreads();
  ushort4 u;
  u.x = tile[r][c4];     u.y = tile[r][c4 + 1];
  u.z = tile[r][c4 + 2]; u.w = tile[r][c4 + 3];
  *(ushort4*)(k3t + ((size_t)b * NN + n0 + r) * NM + m0 + c4) = u;
}

// ---------------- A = k1 @ Vinv via bf16 MFMA (R5) ----------------
__global__ __launch_bounds__(256) void gemm_a_mfma(
    const ushort* __restrict__ k1bf, const ushort* __restrict__ Vt,
    ushort* __restrict__ Abf) {
  int b = blockIdx.z;
  int bi = blockIdx.y * 128, bj = blockIdx.x * 128;
  __shared__ ushort As[128 * 64];
  __shared__ ushort Bs[128 * 64];
  int t = threadIdx.x;
  int wave = t >> 6, lane = t & 63;
  int wr = wave >> 1, wc = wave & 1;
  const ushort* Ab = k1bf + (size_t)b * NN * NM;
  const ushort* Bb = Vt + (size_t)b * NM * NM;
  f32x4 acc[4][4] = {};
  for (int k0 = 0; k0 < NM; k0 += 64) {
    #pragma unroll
    for (int q = 0; q < 4; ++q) {
      int s = q * 256 + t;
      int r = s >> 3, c = s & 7;
      int cs = (c ^ (r & 7)) << 3;
      gl_lds16(Ab + (size_t)(bi + r) * NM + k0 + cs, As + (size_t)s * 8);
      gl_lds16(Bb + (size_t)(bj + r) * NM + k0 + cs, Bs + (size_t)s * 8);
    }
    __syncthreads();
    #pragma unroll
    for (int kk = 0; kk < 2; ++kk) {
      int koff = kk * 64 + (lane >> 4) * 16;
      bf16x8 af[4], bfv[4];
      #pragma unroll
      for (int mi = 0; mi < 4; ++mi) {
        int row = wr * 64 + mi * 16 + (lane & 15);
        af[mi] = *(const bf16x8*)((const char*)As + row * 128 + (koff ^ ((row & 7) << 4)));
      }
      #pragma unroll
      for (int nj = 0; nj < 4; ++nj) {
        int row = wc * 64 + nj * 16 + (lane & 15);
        bfv[nj] = *(const bf16x8*)((const char*)Bs + row * 128 + (koff ^ ((row & 7) << 4)));
      }
      #pragma unroll
      for (int mi = 0; mi < 4; ++mi)
        #pragma unroll
        for (int nj = 0; nj < 4; ++nj)
          acc[mi][nj] = __builtin_amdgcn_mfma_f32_16x16x32_bf16(af[mi], bfv[nj], acc[mi][nj], 0, 0, 0);
    }
    __syncthreads();
  }
  int col = lane & 15, rbase = (lane >> 4) * 4;
  #pragma unroll
  for (int mi = 0; mi < 4; ++mi)
    #pragma unroll
    for (int nj = 0; nj < 4; ++nj)
      #pragma unroll
      for (int r = 0; r < 4; ++r)
        Abf[((size_t)b * NN + bi + wr * 64 + mi * 16 + rbase + r) * NM
            + bj + wc * 64 + nj * 16 + col] = f2bf(acc[mi][nj][r]);
}

// ---------------- attn = A @ k3 via bf16 MFMA, 128x128 tile, XCD swizzle, nt stores ----------------
__global__ __launch_bounds__(256) void gemm_attn_mfma(
    const ushort* __restrict__ Abf, const ushort* __restrict__ K3T,
    float* __restrict__ attn) {
  int lin = blockIdx.z * 1024 + blockIdx.y * 32 + blockIdx.x;
  int swz = (lin & 7) * 256 + (lin >> 3);
  int b = swz >> 10;
  int rem = swz & 1023;
  int bi = (rem >> 5) * 128, bj = (rem & 31) * 128;
  __shared__ ushort As[128 * 64];
  __shared__ ushort Bs[128 * 64];
  int t = threadIdx.x;
  int wave = t >> 6, lane = t & 63;
  int wr = wave >> 1, wc = wave & 1;
  const ushort* Ab = Abf + (size_t)b * NN * NM;
  const ushort* Bb = K3T + (size_t)b * NN * NM;
  f32x4 acc[4][4] = {};
  for (int k0 = 0; k0 < NM; k0 += 64) {
    #pragma unroll
    for (int q = 0; q < 4; ++q) {
      int s = q * 256 + t;
      int r = s >> 3, c = s & 7;
      int cs = (c ^ (r & 7)) << 3;
      gl_lds16(Ab + (size_t)(bi + r) * NM + k0 + cs, As + (size_t)s * 8);
      gl_lds16(Bb + (size_t)(bj + r) * NM + k0 + cs, Bs + (size_t)s * 8);
    }
    __syncthreads();
    #pragma unroll
    for (int kk = 0; kk < 2; ++kk) {
      int koff = kk * 64 + (lane >> 4) * 16;
      bf16x8 af[4], bfv[4];
      #pragma unroll
      for (int mi = 0; mi < 4; ++mi) {
        int row = wr * 64 + mi * 16 + (lane & 15);
        af[mi] = *(const bf16x8*)((const char*)As + row * 128 + (koff ^ ((row & 7) << 4)));
      }
      #pragma unroll
      for (int nj = 0; nj < 4; ++nj) {
        int row = wc * 64 + nj * 16 + (lane & 15);
        bfv[nj] = *(const bf16x8*)((const char*)Bs + row * 128 + (koff ^ ((row & 7) << 4)));
      }
      #pragma unroll
      for (int mi = 0; mi < 4; ++mi)
        #pragma unroll
        for (int nj = 0; nj < 4; ++nj)
          acc[mi][nj] = __builtin_amdgcn_mfma_f32_16x16x32_bf16(af[mi], bfv[nj], acc[mi][nj], 0, 0, 0);
    }
    __syncthreads();
  }
  int col = lane & 15, rbase = (lane >> 4) * 4;
  #pragma unroll
  for (int mi = 0; mi < 4; ++mi)
    #pragma unroll
    for (int nj = 0; nj < 4; ++nj)
      #pragma unroll
      for (int r = 0; r < 4; ++r)
        __builtin_nontemporal_store(
            acc[mi][nj][r],
            &attn[((size_t)b * NN + bi + wr * 64 + mi * 16 + rbase + r) * NN
                  + bj + wc * 64 + nj * 16 + col]);
}

// ---------------- split-K kv (k3 bf16, atomicAdd into zeroed buffer) ----------------
__global__ __launch_bounds__(256) void kv_kernel(
    const ushort* __restrict__ K3, const float* __restrict__ Vv,
    float* __restrict__ kvout) {
  int b = blockIdx.z, bp = blockIdx.x * 64;
  int j0base = blockIdx.y * (NN / 32);
  __shared__ float Ks[64][33], Vs[64][33];
  int t = threadIdx.x, tx = t & 15, ty = t >> 4;
  int lrow = t >> 2, ljc = (t & 3) * 8;
  float acc[4][4] = {};
  for (int j0 = j0base; j0 < j0base + NN / 32; j0 += 32) {
    bf16x8 a0 = *(const bf16x8*)(K3 + ((size_t)b * NM + bp + lrow) * NN + j0 + ljc);
    float4 v0 = *(const float4*)(Vv + ((size_t)b * NC + lrow) * NN + j0 + ljc);
    float4 v1 = *(const float4*)(Vv + ((size_t)b * NC + lrow) * NN + j0 + ljc + 4);
    #pragma unroll
    for (int e = 0; e < 8; ++e) Ks[lrow][ljc + e] = bf2f((ushort)a0[e]);
    Vs[lrow][ljc + 0] = v0.x; Vs[lrow][ljc + 1] = v0.y; Vs[lrow][ljc + 2] = v0.z; Vs[lrow][ljc + 3] = v0.w;
    Vs[lrow][ljc + 4] = v1.x; Vs[lrow][ljc + 5] = v1.y; Vs[lrow][ljc + 6] = v1.z; Vs[lrow][ljc + 7] = v1.w;
    __syncthreads();
    #pragma unroll
    for (int kk = 0; kk < 32; ++kk) {
      float av_[4], bv_[4];
      #pragma unroll
      for (int i = 0; i < 4; ++i) av_[i] = Ks[(ty << 2) + i][kk];
      #pragma unroll
      for (int j = 0; j < 4; ++j) bv_[j] = Vs[(tx << 2) + j][kk];
      #pragma unroll
      for (int i = 0; i < 4; ++i)
        #pragma unroll
        for (int j = 0; j < 4; ++j) acc[i][j] += av_[i] * bv_[j];
    }
    __syncthreads();
  }
  #pragma unroll
  for (int i = 0; i < 4; ++i)
    #pragma unroll
    for (int j = 0; j < 4; ++j)
      atomicAdd(&kvout[((size_t)b * NM + bp + (ty << 2) + i) * NC + (tx << 2) + j], acc[i][j]);
}

// ---------------- out = gamma*(A@kv) + x  (A in bf16, nt stores) ----------------
__global__ __launch_bounds__(256) void out_kernel(
    const ushort* __restrict__ Abf, const float* __restrict__ kvm,
    const float* __restrict__ x, const float* __restrict__ gamma,
    float* __restrict__ outp) {
  __shared__ float As[32 * 256];
  int blk = blockIdx.x;
  int b = blk / (NN / 32), n0 = (blk % (NN / 32)) * 32;
  int t = threadIdx.x;
  for (int it = 0; it < 32; ++it)
    As[it * 256 + (t ^ (it & 31))] = bf2f(Abf[((size_t)b * NN + n0 + it) * NM + t]);
  __syncthreads();
  int tn = t & 31, cg0 = (t >> 5) * 8;
  float g = gamma[0];
  float acc[8] = {};
  for (int p = 0; p < NM; ++p) {
    float a = As[tn * 256 + (p ^ (tn & 31))];
    float4 kv0 = *(const float4*)(kvm + ((size_t)b * NM + p) * NC + cg0);
    float4 kv1 = *(const float4*)(kvm + ((size_t)b * NM + p) * NC + cg0 + 4);
    acc[0] += a * kv0.x; acc[1] += a * kv0.y; acc[2] += a * kv0.z; acc[3] += a * kv0.w;
    acc[4] += a * kv1.x; acc[5] += a * kv1.y; acc[6] += a * kv1.z; acc[7] += a * kv1.w;
  }
  #pragma unroll
  for (int qd = 0; qd < 8; ++qd) {
    int c = cg0 + qd;
    size_t idx = ((size_t)b * NC + c) * NN + n0 + tn;
    __builtin_nontemporal_store(g * acc[qd] + x[idx], &outp[idx]);
  }
}

extern "C" void kernel_launch(void* const* d_in, const int* in_sizes, int n_in,
                              void* d_out, int out_size, void* d_ws, size_t ws_size,
                              hipStream_t stream) {
  const float* x     = (const float*)d_in[0];
  const float* wq    = (const float*)d_in[1];
  const float* bq    = (const float*)d_in[2];
  const float* wk    = (const float*)d_in[3];
  const float* bk    = (const float*)d_in[4];
  const float* wv    = (const float*)d_in[5];
  const float* bv    = (const float*)d_in[6];
  const float* gamma = (const float*)d_in[7];
  float* outp = (float*)d_out;                       // [B][C][N]
  float* attn = outp + (size_t)NB * NC * NN;         // [B][N][N]
  float* w = (float*)d_ws;

  float* qw   = w;                 // [B][N][D]    65536
  float* kw   = qw + 65536;        // [B][N][D]    65536
  float* vw   = kw + 65536;        // [B][C][N]    524288
  float* qlw  = vw + 524288;       // [B][M][D]    4096
  float* klw  = qlw + 4096;        // [B][M][D]    4096
  float* k1w  = klw + 4096;        // 8 MB region: k1bf (4MB) + k3T (4MB)
  float* k2w  = k1w + 2097152;     // [B][M][M]    131072
  float* k3w  = k2w + 131072;      // region: k3bf row-major bf16 (4 MB of 8)
  float* Abuf = k3w + 2097152;     // 4 MB region: Abf bf16
  float* Zp   = Abuf + 1048576;    // pair 262144
  float* T1p  = Zp + 2 * SLICE;    // pair 262144
  float* T2p  = T1p + 2 * SLICE;   // pair 262144
  float* Vap  = T2p + 2 * SLICE;   // pair 262144
  float* Vbp  = Vap + 2 * SLICE;   // pair 262144
  float* Vtw  = Vbp + 2 * SLICE;   // Vinvt bf16   65536 floats
  float* kvw  = Vtw + 65536;       // [B][M][C]    32768
  float* denw = kvw + 32768;       // [2]
  ushort* k1bf  = (ushort*)k1w;                 // [B][N][M] bf16
  ushort* k3T   = (ushort*)k1w + 2097152;       // [B][N][M] bf16 (k3^T)
  ushort* k3bf  = (ushort*)k3w;                 // [B][M][N] bf16 row-major
  ushort* Abf   = (ushort*)Abuf;                // [B][N][M] bf16
  ushort* Vinvt = (ushort*)Vtw;                 // [B][M][M] bf16 (Vinv^T)

  hipMemsetAsync(kvw, 0, (size_t)NB * NM * NC * sizeof(float), stream);
  qkv4_kernel<<<dim3(20, NN / 1024, NB), dim3(256), 0, stream>>>(
      x, wq, bq, wk, bk, wv, bv, qw, kw, vw, qlw, klw);
  scores_all_kernel<<<dim3(2048 + 128 + 512), dim3(256), 0, stream>>>(
      qw, qlw, kw, klw, k1bf, k2w, k3bf);
  denom_kernel<<<dim3(NB), dim3(256), 0, stream>>>(k2w, denw);

  // Newton-Schulz: split-K x2 pairs, 256 blocks/launch (1 per CU).
  // iter 0 (V0 virtual):
  ns2_kernel<<<dim3(8, 8, 2 * NB), dim3(256), 0, stream>>>(k2w, 0, k2w, 2, denw, Zp, 0.f, 1.f);
  ns2_kernel<<<dim3(8, 8, 2 * NB), dim3(256), 0, stream>>>(Zp, 1, Zp, 1, denw, T1p, 7.f, -1.f);
  ns2_kernel<<<dim3(8, 8, 2 * NB), dim3(256), 0, stream>>>(Zp, 1, T1p, 1, denw, T2p, 15.f, -1.f);
  ns2_kernel<<<dim3(8, 8, 2 * NB), dim3(256), 0, stream>>>(k2w, 2, T2p, 1, denw, Vap, 3.25f, -0.25f);
  // iters 1..4:
  float* Vcp = Vap; float* Vnp = Vbp;
  for (int it = 1; it < 5; ++it) {
    ns2_kernel<<<dim3(8, 8, 2 * NB), dim3(256), 0, stream>>>(k2w, 0, Vcp, 1, denw, Zp, 0.f, 1.f);
    ns2_kernel<<<dim3(8, 8, 2 * NB), dim3(256), 0, stream>>>(Zp, 1, Zp, 1, denw, T1p, 7.f, -1.f);
    ns2_kernel<<<dim3(8, 8, 2 * NB), dim3(256), 0, stream>>>(Zp, 1, T1p, 1, denw, T2p, 15.f, -1.f);
    ns2_kernel<<<dim3(8, 8, 2 * NB), dim3(256), 0, stream>>>(Vcp, 1, T2p, 1, denw, Vnp, 3.25f, -0.25f);
    float* tmp = Vcp; Vcp = Vnp; Vnp = tmp;
  }
  // iter 5: final V' -> Vinvt bf16 transposed (full-K pair kernel)
  ns2_kernel<<<dim3(8, 8, 2 * NB), dim3(256), 0, stream>>>(k2w, 0, Vcp, 1, denw, Zp, 0.f, 1.f);
  ns2_kernel<<<dim3(8, 8, 2 * NB), dim3(256), 0, stream>>>(Zp, 1, Zp, 1, denw, T1p, 7.f, -1.f);
  ns2_kernel<<<dim3(8, 8, 2 * NB), dim3(256), 0, stream>>>(Zp, 1, T1p, 1, denw, T2p, 15.f, -1.f);
  gemm_rk32_wt_pair<<<dim3(8, 8, NB), dim3(256), 0, stream>>>(Vcp, T2p, Vinvt);

  cvt_t_kernel<<<dim3(NN / 32, NM / 32, NB), dim3(256), 0, stream>>>(k3bf, k3T);
  gemm_a_mfma<<<dim3(NM / 128, NN / 128, NB), dim3(256), 0, stream>>>(k1bf, Vinvt, Abf);
  gemm_attn_mfma<<<dim3(NN / 128, NN / 128, NB), dim3(256), 0, stream>>>(Abf, k3T, attn);
  kv_kernel<<<dim3(NM / 64, 32, NB), dim3(256), 0, stream>>>(k3bf, vw, kvw);
  out_kernel<<<dim3(NB * NN / 32), dim3(256), 0, stream>>>(Abf, kvw, x, gamma, outp);
}

// Round 16
// 280.544 us; speedup vs baseline: 1.1371x; 1.0176x over previous
//
#include <hip/hip_runtime.h>
#include <hip/hip_bf16.h>
#include <math.h>

#define NB 2        // batch
#define NC 64       // channels
#define ND 8        // head dim (C/8)
#define NN 4096     // tokens (T*W*H)
#define NM 256      // landmarks
#define NL 16       // N/M
#define SCALE 0.35355339059327373f  // 1/sqrt(8)
#define SLICE (NB * NM * NM)        // floats between split-K slices

typedef __attribute__((ext_vector_type(4))) float f32x4;
typedef __attribute__((ext_vector_type(8))) short bf16x8;

__device__ inline ushort f2bf(float f) {
  __hip_bfloat16 h = __float2bfloat16(f);
  return *reinterpret_cast<ushort*>(&h);
}
__device__ inline float bf2f(ushort u) {
  return __uint_as_float(((unsigned int)u) << 16);
}

// async global->LDS, 16B per lane; LDS dest must be wave-linear (base + lane*16)
__device__ inline void gl_lds16(const void* g, void* l) {
  __builtin_amdgcn_global_load_lds(
      (const __attribute__((address_space(1))) unsigned int*)g,
      (__attribute__((address_space(3))) unsigned int*)l, 16, 0, 0);
}

// ---------------- qkv projection, 4 output rows per block + fused landmarks (R12) ----------------
__global__ __launch_bounds__(256) void qkv4_kernel(
    const float* __restrict__ x,
    const float* __restrict__ wq, const float* __restrict__ bq,
    const float* __restrict__ wk, const float* __restrict__ bk,
    const float* __restrict__ wv, const float* __restrict__ bv,
    float* __restrict__ q, float* __restrict__ k, float* __restrict__ v,
    float* __restrict__ ql, float* __restrict__ kl) {
  __shared__ float ws[4][NC];
  int o0 = blockIdx.x * 4;
  int b = blockIdx.z;
  int n0 = blockIdx.y * 1024;
  int t = threadIdx.x;
  {
    int j = t >> 6, c = t & 63;
    int o = o0 + j;
    const float* wrow;
    if (o < ND)          wrow = wq + (size_t)o * NC;
    else if (o < 2 * ND) wrow = wk + (size_t)(o - ND) * NC;
    else                 wrow = wv + (size_t)(o - 2 * ND) * NC;
    ws[j][c] = wrow[c];
  }
  __syncthreads();
  int n = n0 + t * 4;
  float4 acc[4];
  #pragma unroll
  for (int j = 0; j < 4; ++j) {
    int o = o0 + j;
    float bias = (o < ND) ? bq[o] : (o < 2 * ND ? bk[o - ND] : bv[o - 2 * ND]);
    acc[j].x = bias; acc[j].y = bias; acc[j].z = bias; acc[j].w = bias;
  }
  for (int c = 0; c < NC; ++c) {
    float4 xv = *(const float4*)(x + ((size_t)b * NC + c) * NN + n);
    #pragma unroll
    for (int j = 0; j < 4; ++j) {
      float wc = ws[j][c];
      acc[j].x += wc * xv.x; acc[j].y += wc * xv.y;
      acc[j].z += wc * xv.z; acc[j].w += wc * xv.w;
    }
  }
  #pragma unroll
  for (int j = 0; j < 4; ++j) {
    int o = o0 + j;
    if (o < ND) {
      float* qp = q + ((size_t)b * NN + n) * ND + o;
      qp[0] = acc[j].x; qp[8] = acc[j].y; qp[16] = acc[j].z; qp[24] = acc[j].w;
    } else if (o < 2 * ND) {
      float* kp = k + ((size_t)b * NN + n) * ND + (o - ND);
      kp[0] = acc[j].x; kp[8] = acc[j].y; kp[16] = acc[j].z; kp[24] = acc[j].w;
    } else {
      *(float4*)(v + ((size_t)b * NC + (o - 2 * ND)) * NN + n) = acc[j];
    }
    if (o < 2 * ND) {
      float s4 = acc[j].x + acc[j].y + acc[j].z + acc[j].w;
      s4 += __shfl_xor(s4, 1);
      s4 += __shfl_xor(s4, 2);
      if ((t & 3) == 0) {
        int g = n0 / 16 + (t >> 2);
        float* dst = (o < ND) ? ql : kl;
        dst[((size_t)b * NM + g) * ND + (o & 7)] = s4 * (1.0f / 16.0f);
      }
    }
  }
}

// ---------------- merged softmaxes: k1 bf16 / k2 f32 / k3 bf16 row-major (R14) ----------------
__global__ __launch_bounds__(256) void scores_all_kernel(
    const float* __restrict__ q, const float* __restrict__ ql,
    const float* __restrict__ kw, const float* __restrict__ kl,
    ushort* __restrict__ k1bf, float* __restrict__ k2w,
    ushort* __restrict__ k3bf) {
  __shared__ float skl[NM][9];
  __shared__ float wred[4], wsum[4];
  int blk = blockIdx.x;
  int t = threadIdx.x;
  if (blk < 2048 + 128) {
    const float* Q; int R, b, xrow;
    bool isbf;
    if (blk < 2048) { b = blk >> 10; xrow = blk & 1023; Q = q;  R = NN; isbf = true; }
    else { int r = blk - 2048; b = r >> 6; xrow = r & 63; Q = ql; R = NM; isbf = false; }
    for (int i = t; i < NM * ND; i += 256) skl[i >> 3][i & 7] = kl[(size_t)b * NM * ND + i];
    __syncthreads();
    int wave = t >> 6, lane = t & 63;
    int r = xrow * 4 + wave;
    const float* qrow = Q + ((size_t)b * R + r) * ND;
    float qr[ND];
    #pragma unroll
    for (int dd = 0; dd < ND; ++dd) qr[dd] = qrow[dd];
    float sc[4];
    float lmax = -1e30f;
    #pragma unroll
    for (int s = 0; s < 4; ++s) {
      int j = lane + 64 * s;
      float a = 0.f;
      #pragma unroll
      for (int dd = 0; dd < ND; ++dd) a += qr[dd] * skl[j][dd];
      sc[s] = a * SCALE;
      lmax = fmaxf(lmax, sc[s]);
    }
    for (int off = 32; off; off >>= 1) lmax = fmaxf(lmax, __shfl_xor(lmax, off));
    float lsum = 0.f;
    #pragma unroll
    for (int s = 0; s < 4; ++s) { sc[s] = expf(sc[s] - lmax); lsum += sc[s]; }
    for (int off = 32; off; off >>= 1) lsum += __shfl_xor(lsum, off);
    float inv = 1.0f / lsum;
    if (isbf) {
      #pragma unroll
      for (int s = 0; s < 4; ++s)
        k1bf[((size_t)b * R + r) * NM + lane + 64 * s] = f2bf(sc[s] * inv);
    } else {
      #pragma unroll
      for (int s = 0; s < 4; ++s)
        k2w[((size_t)b * R + r) * NM + lane + 64 * s] = sc[s] * inv;
    }
  } else {
    // k3 softmax -> bf16 row-major [M][N]
    int r = blk - 2176;
    int b = r >> 8, i = r & 255;
    float qr[ND];
    #pragma unroll
    for (int dd = 0; dd < ND; ++dd) qr[dd] = ql[((size_t)b * NM + i) * ND + dd];
    float sc[16];
    float lmax = -1e30f;
    #pragma unroll
    for (int s = 0; s < 16; ++s) {
      int n = t + 256 * s;
      const float* kp = kw + ((size_t)b * NN + n) * ND;
      float a = 0.f;
      #pragma unroll
      for (int dd = 0; dd < ND; ++dd) a += qr[dd] * kp[dd];
      sc[s] = a * SCALE;
      lmax = fmaxf(lmax, sc[s]);
    }
    for (int off = 32; off; off >>= 1) lmax = fmaxf(lmax, __shfl_xor(lmax, off));
    if ((t & 63) == 0) wred[t >> 6] = lmax;
    __syncthreads();
    lmax = fmaxf(fmaxf(wred[0], wred[1]), fmaxf(wred[2], wred[3]));
    float lsum = 0.f;
    #pragma unroll
    for (int s = 0; s < 16; ++s) { sc[s] = expf(sc[s] - lmax); lsum += sc[s]; }
    for (int off = 32; off; off >>= 1) lsum += __shfl_xor(lsum, off);
    if ((t & 63) == 0) wsum[t >> 6] = lsum;
    __syncthreads();
    lsum = wsum[0] + wsum[1] + wsum[2] + wsum[3];
    float inv = 1.0f / lsum;
    #pragma unroll
    for (int s = 0; s < 16; ++s)
      k3bf[((size_t)b * NM + i) * NN + t + 256 * s] = f2bf(sc[s] * inv);
  }
}

// ---------------- denom: max column-sum per batch (R5) ----------------
__global__ __launch_bounds__(256) void denom_kernel(const float* __restrict__ k2,
                                                    float* __restrict__ denw) {
  __shared__ float red[256];
  int b = blockIdx.x;
  int t = threadIdx.x;
  float cs = 0.f;
  for (int i = 0; i < NM; ++i) cs += k2[((size_t)b * NM + i) * NM + t];
  red[t] = cs;
  __syncthreads();
  for (int off = 128; off; off >>= 1) {
    if (t < off) red[t] = fmaxf(red[t], red[t + off]);
    __syncthreads();
  }
  if (t == 0) denw[b] = red[0];
}

// ============ NS split-K x4: 1024 blocks/launch (2 per CU), R5 internals ============
// O_slice = s_ab * (A @ B)[K-quarter slice] ; slice 0 additionally += s_a * A_total
// amode: 0 = plain fp32; 1 = quad (sum 4 slices); 2 = virtual V0 = k2^T * dval
// bmode: 1 = quad; 2 = virtual V0
__global__ __launch_bounds__(256) void ns4_kernel(
    const float* __restrict__ A, int amode,
    const float* __restrict__ B, int bmode,
    const float* __restrict__ denw, float* __restrict__ O,
    float s_a, float s_ab) {
  __shared__ float As[32][68];    // [row][k-quarter], pitch 68 (mod-32 = 4, conflict-free)
  __shared__ float Bs[64][36];    // [k-quarter][col]
  int t = threadIdx.x;
  int bi = blockIdx.y * 32, bj = blockIdx.x * 32;
  int b = blockIdx.z >> 2, slice = blockIdx.z & 3;
  int k0 = slice * 64;
  size_t bo = (size_t)b * NM * NM;
  float dval = (amode == 2 || bmode == 2) ? 1.0f / fmaxf(denw[0], denw[1]) : 0.f;
  // ---- stage A quarter-panel (32 x 64) ----
  if (amode == 2) {
    // As[r][k] = k2[k0+k][bi+r] * dval  (coalesced float4 along r)
    #pragma unroll
    for (int q = 0; q < 2; ++q) {
      int s = q * 256 + t;
      int k = s >> 3, rc = (s & 7) * 4;
      float4 v = *(const float4*)(A + bo + (size_t)(k0 + k) * NM + bi + rc);
      As[rc + 0][k] = v.x * dval; As[rc + 1][k] = v.y * dval;
      As[rc + 2][k] = v.z * dval; As[rc + 3][k] = v.w * dval;
    }
  } else {
    #pragma unroll
    for (int q = 0; q < 2; ++q) {
      int s = q * 256 + t;
      int ar = s >> 4, ac = (s & 15) * 4;
      const float* p = A + bo + (size_t)(bi + ar) * NM + k0 + ac;
      float4 v = *(const float4*)p;
      if (amode == 1) {
        float4 v1 = *(const float4*)(p + SLICE);
        float4 v2 = *(const float4*)(p + 2 * SLICE);
        float4 v3 = *(const float4*)(p + 3 * SLICE);
        v.x += v1.x + v2.x + v3.x; v.y += v1.y + v2.y + v3.y;
        v.z += v1.z + v2.z + v3.z; v.w += v1.w + v2.w + v3.w;
      }
      *(float4*)&As[ar][ac] = v;
    }
  }
  // ---- stage B quarter-panel (64 x 32) ----
  if (bmode == 2) {
    // Bs[k][c] = k2[bj+c][k0+k] * dval  (coalesced float4 along k)
    #pragma unroll
    for (int q = 0; q < 2; ++q) {
      int s = q * 256 + t;
      int c = s >> 4, kc = (s & 15) * 4;
      float4 v = *(const float4*)(B + bo + (size_t)(bj + c) * NM + k0 + kc);
      Bs[kc + 0][c] = v.x * dval; Bs[kc + 1][c] = v.y * dval;
      Bs[kc + 2][c] = v.z * dval; Bs[kc + 3][c] = v.w * dval;
    }
  } else {
    #pragma unroll
    for (int q = 0; q < 2; ++q) {
      int s = q * 256 + t;
      int bk = s >> 3, bc = (s & 7) * 4;
      const float* p = B + bo + (size_t)(k0 + bk) * NM + bj + bc;
      float4 v = *(const float4*)p;
      if (bmode == 1) {
        float4 v1 = *(const float4*)(p + SLICE);
        float4 v2 = *(const float4*)(p + 2 * SLICE);
        float4 v3 = *(const float4*)(p + 3 * SLICE);
        v.x += v1.x + v2.x + v3.x; v.y += v1.y + v2.y + v3.y;
        v.z += v1.z + v2.z + v3.z; v.w += v1.w + v2.w + v3.w;
      }
      *(float4*)&Bs[bk][bc] = v;
    }
  }
  __syncthreads();
  int tx = t & 15, ty = t >> 4;
  float acc[2][2] = {};
  #pragma unroll 8
  for (int kk = 0; kk < 64; ++kk) {
    float a0 = As[ty * 2][kk], a1 = As[ty * 2 + 1][kk];
    float b0 = Bs[kk][tx * 2], b1 = Bs[kk][tx * 2 + 1];
    acc[0][0] += a0 * b0; acc[0][1] += a0 * b1;
    acc[1][0] += a1 * b0; acc[1][1] += a1 * b1;
  }
  float* Op = O + (size_t)slice * SLICE + bo;
  bool addA = (slice == 0) && (s_a != 0.0f);
  #pragma unroll
  for (int i = 0; i < 2; ++i)
    #pragma unroll
    for (int j = 0; j < 2; ++j) {
      int R = bi + ty * 2 + i, C = bj + tx * 2 + j;
      float r = s_ab * acc[i][j];
      if (addA) {
        float av;
        if (amode == 2) {
          av = A[bo + (size_t)C * NM + R] * dval;
        } else if (amode == 1) {
          size_t o = bo + (size_t)R * NM + C;
          av = A[o] + A[o + SLICE] + A[o + 2 * SLICE] + A[o + 3 * SLICE];
        } else {
          av = A[bo + (size_t)R * NM + C];
        }
        r += s_a * av;
      }
      Op[(size_t)R * NM + C] = r;
    }
}

// ---- NS final launch: V' = 3.25*V - 0.25*V@T2 (A,B quads), full K, bf16^T out ----
__global__ __launch_bounds__(256) void gemm_rk32_wt_quad(
    const float* __restrict__ A, const float* __restrict__ Bm,
    ushort* __restrict__ Vt) {
  int b = blockIdx.z;
  int bi = blockIdx.y * 32, bj = blockIdx.x * 32;
  __shared__ float As[32][260];
  __shared__ float Bs[256][36];
  int t = threadIdx.x;
  const float* Ab = A + (size_t)b * NM * NM;
  const float* Bb = Bm + (size_t)b * NM * NM;
  #pragma unroll
  for (int q = 0; q < 8; ++q) {
    int s = q * 256 + t;
    int ar = s >> 6, ac = (s & 63) * 4;
    const float* pa = Ab + (size_t)(bi + ar) * NM + ac;
    float4 va = *(const float4*)pa;
    float4 va1 = *(const float4*)(pa + SLICE);
    float4 va2 = *(const float4*)(pa + 2 * SLICE);
    float4 va3 = *(const float4*)(pa + 3 * SLICE);
    va.x += va1.x + va2.x + va3.x; va.y += va1.y + va2.y + va3.y;
    va.z += va1.z + va2.z + va3.z; va.w += va1.w + va2.w + va3.w;
    *(float4*)&As[ar][ac] = va;
    int br = s >> 3, bc = (s & 7) * 4;
    const float* pb = Bb + (size_t)br * NM + bj + bc;
    float4 vb = *(const float4*)pb;
    float4 vb1 = *(const float4*)(pb + SLICE);
    float4 vb2 = *(const float4*)(pb + 2 * SLICE);
    float4 vb3 = *(const float4*)(pb + 3 * SLICE);
    vb.x += vb1.x + vb2.x + vb3.x; vb.y += vb1.y + vb2.y + vb3.y;
    vb.z += vb1.z + vb2.z + vb3.z; vb.w += vb1.w + vb2.w + vb3.w;
    *(float4*)&Bs[br][bc] = vb;
  }
  __syncthreads();
  int tx = t & 15, ty = t >> 4;
  float acc[2][2] = {};
  #pragma unroll 8
  for (int kk = 0; kk < NM; ++kk) {
    float a0 = As[ty * 2][kk], a1 = As[ty * 2 + 1][kk];
    float b0 = Bs[kk][tx * 2], b1 = Bs[kk][tx * 2 + 1];
    acc[0][0] += a0 * b0; acc[0][1] += a0 * b1;
    acc[1][0] += a1 * b0; acc[1][1] += a1 * b1;
  }
  __syncthreads();
  float (*tile)[33] = (float (*)[33])&As[0][0];
  #pragma unroll
  for (int i = 0; i < 2; ++i)
    #pragma unroll
    for (int j = 0; j < 2; ++j) {
      int R = ty * 2 + i, C = tx * 2 + j;
      size_t o = (size_t)(bi + R) * NM + bj + C;
      float a0v = Ab[o] + Ab[o + SLICE] + Ab[o + 2 * SLICE] + Ab[o + 3 * SLICE];
      tile[R][C] = 3.25f * a0v - 0.25f * acc[i][j];
    }
  __syncthreads();
  int rr = t >> 3, m4 = (t & 7) * 4;
  ushort4 u;
  u.x = f2bf(tile[m4 + 0][rr]); u.y = f2bf(tile[m4 + 1][rr]);
  u.z = f2bf(tile[m4 + 2][rr]); u.w = f2bf(tile[m4 + 3][rr]);
  *(ushort4*)(Vt + ((size_t)b * NM + bj + rr) * NM + bi + m4) = u;
}

// ---------------- k3bf [B][NM][NN] bf16 -> k3t [B][NN][NM] bf16 (transpose) ----------------
__global__ __launch_bounds__(256) void cvt_t_kernel(const ushort* __restrict__ k3,
                                                    ushort* __restrict__ k3t) {
  int b = blockIdx.z;
  int n0 = blockIdx.x * 32, m0 = blockIdx.y * 32;
  __shared__ ushort tile[32][33];
  int t = threadIdx.x;
  int r = t >> 3, c4 = (t & 7) * 4;
  ushort4 v = *(const ushort4*)(k3 + ((size_t)b * NM + m0 + r) * NN + n0 + c4);
  tile[c4][r] = v.x; tile[c4 + 1][r] = v.y; tile[c4 + 2][r] = v.z; tile[c4 + 3][r] = v.w;
  __syncthreads();
  ushort4 u;
  u.x = tile[r][c4];     u.y = tile[r][c4 + 1];
  u.z = tile[r][c4 + 2]; u.w = tile[r][c4 + 3];
  *(ushort4*)(k3t + ((size_t)b * NN + n0 + r) * NM + m0 + c4) = u;
}

// ---------------- A = k1 @ Vinv via bf16 MFMA (R5) ----------------
__global__ __launch_bounds__(256) void gemm_a_mfma(
    const ushort* __restrict__ k1bf, const ushort* __restrict__ Vt,
    ushort* __restrict__ Abf) {
  int b = blockIdx.z;
  int bi = blockIdx.y * 128, bj = blockIdx.x * 128;
  __shared__ ushort As[128 * 64];
  __shared__ ushort Bs[128 * 64];
  int t = threadIdx.x;
  int wave = t >> 6, lane = t & 63;
  int wr = wave >> 1, wc = wave & 1;
  const ushort* Ab = k1bf + (size_t)b * NN * NM;
  const ushort* Bb = Vt + (size_t)b * NM * NM;
  f32x4 acc[4][4] = {};
  for (int k0 = 0; k0 < NM; k0 += 64) {
    #pragma unroll
    for (int q = 0; q < 4; ++q) {
      int s = q * 256 + t;
      int r = s >> 3, c = s & 7;
      int cs = (c ^ (r & 7)) << 3;
      gl_lds16(Ab + (size_t)(bi + r) * NM + k0 + cs, As + (size_t)s * 8);
      gl_lds16(Bb + (size_t)(bj + r) * NM + k0 + cs, Bs + (size_t)s * 8);
    }
    __syncthreads();
    #pragma unroll
    for (int kk = 0; kk < 2; ++kk) {
      int koff = kk * 64 + (lane >> 4) * 16;
      bf16x8 af[4], bfv[4];
      #pragma unroll
      for (int mi = 0; mi < 4; ++mi) {
        int row = wr * 64 + mi * 16 + (lane & 15);
        af[mi] = *(const bf16x8*)((const char*)As + row * 128 + (koff ^ ((row & 7) << 4)));
      }
      #pragma unroll
      for (int nj = 0; nj < 4; ++nj) {
        int row = wc * 64 + nj * 16 + (lane & 15);
        bfv[nj] = *(const bf16x8*)((const char*)Bs + row * 128 + (koff ^ ((row & 7) << 4)));
      }
      #pragma unroll
      for (int mi = 0; mi < 4; ++mi)
        #pragma unroll
        for (int nj = 0; nj < 4; ++nj)
          acc[mi][nj] = __builtin_amdgcn_mfma_f32_16x16x32_bf16(af[mi], bfv[nj], acc[mi][nj], 0, 0, 0);
    }
    __syncthreads();
  }
  int col = lane & 15, rbase = (lane >> 4) * 4;
  #pragma unroll
  for (int mi = 0; mi < 4; ++mi)
    #pragma unroll
    for (int nj = 0; nj < 4; ++nj)
      #pragma unroll
      for (int r = 0; r < 4; ++r)
        Abf[((size_t)b * NN + bi + wr * 64 + mi * 16 + rbase + r) * NM
            + bj + wc * 64 + nj * 16 + col] = f2bf(acc[mi][nj][r]);
}

// ---------------- attn = A @ k3 via bf16 MFMA, 128x128 tile, XCD swizzle, nt stores ----------------
__global__ __launch_bounds__(256) void gemm_attn_mfma(
    const ushort* __restrict__ Abf, const ushort* __restrict__ K3T,
    float* __restrict__ attn) {
  int lin = blockIdx.z * 1024 + blockIdx.y * 32 + blockIdx.x;
  int swz = (lin & 7) * 256 + (lin >> 3);
  int b = swz >> 10;
  int rem = swz & 1023;
  int bi = (rem >> 5) * 128, bj = (rem & 31) * 128;
  __shared__ ushort As[128 * 64];
  __shared__ ushort Bs[128 * 64];
  int t = threadIdx.x;
  int wave = t >> 6, lane = t & 63;
  int wr = wave >> 1, wc = wave & 1;
  const ushort* Ab = Abf + (size_t)b * NN * NM;
  const ushort* Bb = K3T + (size_t)b * NN * NM;
  f32x4 acc[4][4] = {};
  for (int k0 = 0; k0 < NM; k0 += 64) {
    #pragma unroll
    for (int q = 0; q < 4; ++q) {
      int s = q * 256 + t;
      int r = s >> 3, c = s & 7;
      int cs = (c ^ (r & 7)) << 3;
      gl_lds16(Ab + (size_t)(bi + r) * NM + k0 + cs, As + (size_t)s * 8);
      gl_lds16(Bb + (size_t)(bj + r) * NM + k0 + cs, Bs + (size_t)s * 8);
    }
    __syncthreads();
    #pragma unroll
    for (int kk = 0; kk < 2; ++kk) {
      int koff = kk * 64 + (lane >> 4) * 16;
      bf16x8 af[4], bfv[4];
      #pragma unroll
      for (int mi = 0; mi < 4; ++mi) {
        int row = wr * 64 + mi * 16 + (lane & 15);
        af[mi] = *(const bf16x8*)((const char*)As + row * 128 + (koff ^ ((row & 7) << 4)));
      }
      #pragma unroll
      for (int nj = 0; nj < 4; ++nj) {
        int row = wc * 64 + nj * 16 + (lane & 15);
        bfv[nj] = *(const bf16x8*)((const char*)Bs + row * 128 + (koff ^ ((row & 7) << 4)));
      }
      #pragma unroll
      for (int mi = 0; mi < 4; ++mi)
        #pragma unroll
        for (int nj = 0; nj < 4; ++nj)
          acc[mi][nj] = __builtin_amdgcn_mfma_f32_16x16x32_bf16(af[mi], bfv[nj], acc[mi][nj], 0, 0, 0);
    }
    __syncthreads();
  }
  int col = lane & 15, rbase = (lane >> 4) * 4;
  #pragma unroll
  for (int mi = 0; mi < 4; ++mi)
    #pragma unroll
    for (int nj = 0; nj < 4; ++nj)
      #pragma unroll
      for (int r = 0; r < 4; ++r)
        __builtin_nontemporal_store(
            acc[mi][nj][r],
            &attn[((size_t)b * NN + bi + wr * 64 + mi * 16 + rbase + r) * NN
                  + bj + wc * 64 + nj * 16 + col]);
}

// ---------------- split-K kv (k3 bf16, atomicAdd into zeroed buffer) ----------------
__global__ __launch_bounds__(256) void kv_kernel(
    const ushort* __restrict__ K3, const float* __restrict__ Vv,
    float* __restrict__ kvout) {
  int b = blockIdx.z, bp = blockIdx.x * 64;
  int j0base = blockIdx.y * (NN / 32);
  __shared__ float Ks[64][33], Vs[64][33];
  int t = threadIdx.x, tx = t & 15, ty = t >> 4;
  int lrow = t >> 2, ljc = (t & 3) * 8;
  float acc[4][4] = {};
  for (int j0 = j0base; j0 < j0base + NN / 32; j0 += 32) {
    bf16x8 a0 = *(const bf16x8*)(K3 + ((size_t)b * NM + bp + lrow) * NN + j0 + ljc);
    float4 v0 = *(const float4*)(Vv + ((size_t)b * NC + lrow) * NN + j0 + ljc);
    float4 v1 = *(const float4*)(Vv + ((size_t)b * NC + lrow) * NN + j0 + ljc + 4);
    #pragma unroll
    for (int e = 0; e < 8; ++e) Ks[lrow][ljc + e] = bf2f((ushort)a0[e]);
    Vs[lrow][ljc + 0] = v0.x; Vs[lrow][ljc + 1] = v0.y; Vs[lrow][ljc + 2] = v0.z; Vs[lrow][ljc + 3] = v0.w;
    Vs[lrow][ljc + 4] = v1.x; Vs[lrow][ljc + 5] = v1.y; Vs[lrow][ljc + 6] = v1.z; Vs[lrow][ljc + 7] = v1.w;
    __syncthreads();
    #pragma unroll
    for (int kk = 0; kk < 32; ++kk) {
      float av_[4], bv_[4];
      #pragma unroll
      for (int i = 0; i < 4; ++i) av_[i] = Ks[(ty << 2) + i][kk];
      #pragma unroll
      for (int j = 0; j < 4; ++j) bv_[j] = Vs[(tx << 2) + j][kk];
      #pragma unroll
      for (int i = 0; i < 4; ++i)
        #pragma unroll
        for (int j = 0; j < 4; ++j) acc[i][j] += av_[i] * bv_[j];
    }
    __syncthreads();
  }
  #pragma unroll
  for (int i = 0; i < 4; ++i)
    #pragma unroll
    for (int j = 0; j < 4; ++j)
      atomicAdd(&kvout[((size_t)b * NM + bp + (ty << 2) + i) * NC + (tx << 2) + j], acc[i][j]);
}

// ---------------- out = gamma*(A@kv) + x  (A in bf16, nt stores) ----------------
__global__ __launch_bounds__(256) void out_kernel(
    const ushort* __restrict__ Abf, const float* __restrict__ kvm,
    const float* __restrict__ x, const float* __restrict__ gamma,
    float* __restrict__ outp) {
  __shared__ float As[32 * 256];
  int blk = blockIdx.x;
  int b = blk / (NN / 32), n0 = (blk % (NN / 32)) * 32;
  int t = threadIdx.x;
  for (int it = 0; it < 32; ++it)
    As[it * 256 + (t ^ (it & 31))] = bf2f(Abf[((size_t)b * NN + n0 + it) * NM + t]);
  __syncthreads();
  int tn = t & 31, cg0 = (t >> 5) * 8;
  float g = gamma[0];
  float acc[8] = {};
  for (int p = 0; p < NM; ++p) {
    float a = As[tn * 256 + (p ^ (tn & 31))];
    float4 kv0 = *(const float4*)(kvm + ((size_t)b * NM + p) * NC + cg0);
    float4 kv1 = *(const float4*)(kvm + ((size_t)b * NM + p) * NC + cg0 + 4);
    acc[0] += a * kv0.x; acc[1] += a * kv0.y; acc[2] += a * kv0.z; acc[3] += a * kv0.w;
    acc[4] += a * kv1.x; acc[5] += a * kv1.y; acc[6] += a * kv1.z; acc[7] += a * kv1.w;
  }
  #pragma unroll
  for (int qd = 0; qd < 8; ++qd) {
    int c = cg0 + qd;
    size_t idx = ((size_t)b * NC + c) * NN + n0 + tn;
    __builtin_nontemporal_store(g * acc[qd] + x[idx], &outp[idx]);
  }
}

extern "C" void kernel_launch(void* const* d_in, const int* in_sizes, int n_in,
                              void* d_out, int out_size, void* d_ws, size_t ws_size,
                              hipStream_t stream) {
  const float* x     = (const float*)d_in[0];
  const float* wq    = (const float*)d_in[1];
  const float* bq    = (const float*)d_in[2];
  const float* wk    = (const float*)d_in[3];
  const float* bk    = (const float*)d_in[4];
  const float* wv    = (const float*)d_in[5];
  const float* bv    = (const float*)d_in[6];
  const float* gamma = (const float*)d_in[7];
  float* outp = (float*)d_out;                       // [B][C][N]
  float* attn = outp + (size_t)NB * NC * NN;         // [B][N][N]
  float* w = (float*)d_ws;

  float* qw   = w;                 // [B][N][D]    65536
  float* kw   = qw + 65536;        // [B][N][D]    65536
  float* vw   = kw + 65536;        // [B][C][N]    524288
  float* qlw  = vw + 524288;       // [B][M][D]    4096
  float* klw  = qlw + 4096;        // [B][M][D]    4096
  float* k1w  = klw + 4096;        // 8 MB region: k1bf (4MB) + k3T (4MB)
  float* k2w  = k1w + 2097152;     // [B][M][M]    131072
  float* k3w  = k2w + 131072;      // k3bf bf16 row-major (4 MB)
  float* Abuf = k3w + 1048576;     // 4 MB region: Abf bf16
  float* Zp   = Abuf + 1048576;    // quad 524288
  float* T1p  = Zp + 4 * SLICE;    // quad 524288
  float* T2p  = T1p + 4 * SLICE;   // quad 524288
  float* Vap  = T2p + 4 * SLICE;   // quad 524288
  float* Vbp  = Vap + 4 * SLICE;   // quad 524288
  float* Vtw  = Vbp + 4 * SLICE;   // Vinvt bf16   65536 floats
  float* kvw  = Vtw + 65536;       // [B][M][C]    32768
  float* denw = kvw + 32768;       // [2]
  ushort* k1bf  = (ushort*)k1w;                 // [B][N][M] bf16
  ushort* k3T   = (ushort*)k1w + 2097152;       // [B][N][M] bf16 (k3^T)
  ushort* k3bf  = (ushort*)k3w;                 // [B][M][N] bf16 row-major
  ushort* Abf   = (ushort*)Abuf;                // [B][N][M] bf16
  ushort* Vinvt = (ushort*)Vtw;                 // [B][M][M] bf16 (Vinv^T)

  hipMemsetAsync(kvw, 0, (size_t)NB * NM * NC * sizeof(float), stream);
  qkv4_kernel<<<dim3(20, NN / 1024, NB), dim3(256), 0, stream>>>(
      x, wq, bq, wk, bk, wv, bv, qw, kw, vw, qlw, klw);
  scores_all_kernel<<<dim3(2048 + 128 + 512), dim3(256), 0, stream>>>(
      qw, qlw, kw, klw, k1bf, k2w, k3bf);
  denom_kernel<<<dim3(NB), dim3(256), 0, stream>>>(k2w, denw);

  // Newton-Schulz: split-K x4 quads, 1024 blocks/launch (2 per CU).
  // iter 0 (V0 virtual):
  ns4_kernel<<<dim3(8, 8, 4 * NB), dim3(256), 0, stream>>>(k2w, 0, k2w, 2, denw, Zp, 0.f, 1.f);
  ns4_kernel<<<dim3(8, 8, 4 * NB), dim3(256), 0, stream>>>(Zp, 1, Zp, 1, denw, T1p, 7.f, -1.f);
  ns4_kernel<<<dim3(8, 8, 4 * NB), dim3(256), 0, stream>>>(Zp, 1, T1p, 1, denw, T2p, 15.f, -1.f);
  ns4_kernel<<<dim3(8, 8, 4 * NB), dim3(256), 0, stream>>>(k2w, 2, T2p, 1, denw, Vap, 3.25f, -0.25f);
  // iters 1..4:
  float* Vcp = Vap; float* Vnp = Vbp;
  for (int it = 1; it < 5; ++it) {
    ns4_kernel<<<dim3(8, 8, 4 * NB), dim3(256), 0, stream>>>(k2w, 0, Vcp, 1, denw, Zp, 0.f, 1.f);
    ns4_kernel<<<dim3(8, 8, 4 * NB), dim3(256), 0, stream>>>(Zp, 1, Zp, 1, denw, T1p, 7.f, -1.f);
    ns4_kernel<<<dim3(8, 8, 4 * NB), dim3(256), 0, stream>>>(Zp, 1, T1p, 1, denw, T2p, 15.f, -1.f);
    ns4_kernel<<<dim3(8, 8, 4 * NB), dim3(256), 0, stream>>>(Vcp, 1, T2p, 1, denw, Vnp, 3.25f, -0.25f);
    float* tmp = Vcp; Vcp = Vnp; Vnp = tmp;
  }
  // iter 5: final V' -> Vinvt bf16 transposed (full-K quad kernel)
  ns4_kernel<<<dim3(8, 8, 4 * NB), dim3(256), 0, stream>>>(k2w, 0, Vcp, 1, denw, Zp, 0.f, 1.f);
  ns4_kernel<<<dim3(8, 8, 4 * NB), dim3(256), 0, stream>>>(Zp, 1, Zp, 1, denw, T1p, 7.f, -1.f);
  ns4_kernel<<<dim3(8, 8, 4 * NB), dim3(256), 0, stream>>>(Zp, 1, T1p, 1, denw, T2p, 15.f, -1.f);
  gemm_rk32_wt_quad<<<dim3(8, 8, NB), dim3(256), 0, stream>>>(Vcp, T2p, Vinvt);

  cvt_t_kernel<<<dim3(NN / 32, NM / 32, NB), dim3(256), 0, stream>>>(k3bf, k3T);
  gemm_a_mfma<<<dim3(NM / 128, NN / 128, NB), dim3(256), 0, stream>>>(k1bf, Vinvt, Abf);
  gemm_attn_mfma<<<dim3(NN / 128, NN / 128, NB), dim3(256), 0, stream>>>(Abf, k3T, attn);
  kv_kernel<<<dim3(NM / 64, 32, NB), dim3(256), 0, stream>>>(k3bf, vw, kvw);
  out_kernel<<<dim3(NB * NN / 32), dim3(256), 0, stream>>>(Abf, kvw, x, gamma, outp);
}